// Round 11
// baseline (337.032 us; speedup 1.0000x reference)
//
// R10: asm_kvq v2 — Msm eliminated (phase-1 epilogue writes FV direct to FVb;
// phase 2 re-stages A from FVb via global_load_lds). LDS 74.7->40KB = 4
// blocks/CU (16 waves). All other kernels byte-identical to R9.
#include <hip/hip_runtime.h>
#include <hip/hip_bf16.h>
#include <cstddef>

#define N_NODES 40000
#define N_EDGES 8000
#define DE 32
#define DV 8
#define DIM 256
#define QDIM 256
#define EIGD 64
#define NCLS 40
#define LN_EPS 1e-5f
#define ATT_SCALE 0.0625f   // 1/sqrt(256)

typedef unsigned short u16;
typedef unsigned int u32;
using i16x8 = __attribute__((ext_vector_type(8))) short;
using f32x4 = __attribute__((ext_vector_type(4))) float;

__device__ inline u16 f2b(float f) {   // RNE f32 -> bf16 bits
    union { float f; u32 u; } c; c.f = f;
    u32 u = c.u + 0x7FFF + ((c.u >> 16) & 1);
    return (u16)(u >> 16);
}
__device__ inline float b2f(u16 b) {
    union { u32 u; float f; } c; c.u = (u32)b << 16;
    return c.f;
}

__device__ inline void gload_lds16(const u16* g, u16* l) {
    __builtin_amdgcn_global_load_lds(
        (const __attribute__((address_space(1))) void*)g,
        (__attribute__((address_space(3))) void*)l, 16, 0, 0);
}

#define VMCNT12 asm volatile("s_waitcnt vmcnt(12)" ::: "memory")
#define VMCNT6  asm volatile("s_waitcnt vmcnt(6)" ::: "memory")
#define VMCNT0  asm volatile("s_waitcnt vmcnt(0)" ::: "memory")
#define LGKM0   asm volatile("s_waitcnt lgkmcnt(0)" ::: "memory")
#define SCHED0  __builtin_amdgcn_sched_barrier(0)
#define SBAR    __builtin_amdgcn_s_barrier()

// ---------------------------------------------------------------------------
// Batched transpose-cast. Slots: 0 vtx, 1 pe, 2 kv, 3 vv, 4 qv, 5 qe,
// 6 ke, 7 ve, 8 l1, 9 l2, 10 l3, 11 l4, 12 cls.
// ---------------------------------------------------------------------------
__global__ __launch_bounds__(256) void prep_weights(
    const float* w0, const float* w1, const float* w2, const float* w3,
    const float* w4, const float* w5, const float* w6, const float* w7,
    const float* w8, const float* w9, const float* w10, const float* w11,
    const float* w12, u16* __restrict__ pool)
{
    const float* srcs[13] = {w0,w1,w2,w3,w4,w5,w6,w7,w8,w9,w10,w11,w12};
    const int Ks[13]  = {256,64,256,256,256,256,256,256,256,256,256,256,256};
    const int Nds[13] = {256,256,256,256,256,256,256,256,256,256,256,256,40};
    const int id = blockIdx.z;
    const float* W = srcs[id];
    u16* Wt = pool + (size_t)id * 65536;
    const int K = Ks[id], Nd = Nds[id];
    const int k0 = blockIdx.x * 32, n0 = blockIdx.y * 32;
    if (k0 >= K || n0 >= Nd) return;

    __shared__ float tile[32][33];
    const int x = threadIdx.x & 31, y4 = (threadIdx.x >> 5) * 4;
#pragma unroll
    for (int j = 0; j < 4; j++) {
        int k = k0 + y4 + j;
        tile[y4 + j][x] = (k < K && (n0 + x) < Nd) ? W[(size_t)k * Nd + n0 + x] : 0.f;
    }
    __syncthreads();
#pragma unroll
    for (int j = 0; j < 4; j++) {
        int n = n0 + y4 + j;
        if (n < Nd && (k0 + x) < K)
            Wt[(size_t)n * K + k0 + x] = f2b(tile[x][y4 + j]);
    }
}

// ---------------------------------------------------------------------------
// asm_kvq v2: one block = 64 node rows, LDS 40 KB -> 4 blocks/CU.
// Phase 1: FV = vfeat@Wt_vtx + eign@Wt_pe (dual f32, NT=10, 2-buffer).
// Epilogue: FVb[r][c] = f2b(acc + b_vtx+b_pe + gcn + emb1[i1] + emb2[i2])
//           (direct global write; no Msm).
// Readback safety: no thread loaded FVb earlier -> L1 holds no stale line;
// vmcnt(0)+barrier then global_load_lds readback hits L2 (post-store).
// Phase 2: KVQn[.,c*256+..] = FVb @ Wt_kvq[c] + bias_c, single-barrier steps,
//          A re-staged from FVb (L2-hot), cross-chunk A0/B0 prefetch.
// ---------------------------------------------------------------------------
__global__ __launch_bounds__(256, 4) void asm_kvq(
    const float* __restrict__ vfeat, const float* __restrict__ eign,
    const u16* __restrict__ Wt_vtx, const u16* __restrict__ Wt_pe,
    const float* __restrict__ b_vtx, const float* __restrict__ b_pe,
    const float* __restrict__ gcn, const float* __restrict__ emb1,
    const float* __restrict__ emb2, const int* __restrict__ idx1,
    const int* __restrict__ idx2,
    const u16* __restrict__ Wt_kvq, const float* __restrict__ b_kv,
    const float* __restrict__ b_vv, const float* __restrict__ b_qv,
    u16* __restrict__ FVb, u16* __restrict__ KVQn)
{
    __shared__ __align__(16) u16 Asm[2][64 * 32];   //  8 KB
    __shared__ __align__(16) u16 Bsm[2][256 * 32];  // 32 KB
    const int t = threadIdx.x;
    const int lane = t & 63, w = t >> 6;
    const int row0 = blockIdx.x * 64;

    const int srow = lane >> 2;                          // 0..15
    const int sblk = ((lane & 3) ^ ((lane >> 3) & 3)) * 8;  // swizzled src blk
    const int fr = lane & 15, h = lane >> 4;
    const int rsw = (fr >> 1) & 3;

    f32x4 acc[4][4] = {};
    float4 fA[2][2];                                      // [parity][half]

    auto p1_issueB = [&](int kt) {
        const int buf = kt & 1;
        const int k0 = kt << 5;
        const bool tail = (k0 >= 256);
#pragma unroll
        for (int i = 0; i < 4; i++) {
            const int r = w * 64 + i * 16;
            const u16* gp = tail ? Wt_pe + (size_t)(r + srow) * 64 + (k0 - 256) + sblk
                                 : Wt_vtx + (size_t)(r + srow) * 256 + k0 + sblk;
            gload_lds16(gp, &Bsm[buf][r * 32]);
        }
    };
    auto p1_loadA = [&](int kt) {
        const int k0 = kt << 5;
        const bool tail = (k0 >= 256);
        const float* ap = tail
            ? eign + (size_t)(row0 + w * 16 + srow) * 64 + (k0 - 256) + sblk
            : vfeat + (size_t)(row0 + w * 16 + srow) * 256 + k0 + sblk;
        fA[kt & 1][0] = *(const float4*)ap;
        fA[kt & 1][1] = *(const float4*)(ap + 4);
    };
    auto p1_write = [&](int kt) {                         // cvt + ds_write
        const int buf = kt & 1;
        float4 f0 = fA[buf][0], f1 = fA[buf][1];
        i16x8 v;
        v[0] = (short)f2b(f0.x); v[1] = (short)f2b(f0.y);
        v[2] = (short)f2b(f0.z); v[3] = (short)f2b(f0.w);
        v[4] = (short)f2b(f1.x); v[5] = (short)f2b(f1.y);
        v[6] = (short)f2b(f1.z); v[7] = (short)f2b(f1.w);
        *(i16x8*)&Asm[buf][(w * 16 + srow) * 32 + (lane & 3) * 8] = v;
    };

    // ---- phase 1 main loop (NT=10; R8-proven 2-barrier structure) ----
    p1_loadA(0); p1_issueB(0); p1_loadA(1); p1_write(0);
#pragma unroll
    for (int kt = 0; kt < 10; ++kt) {
        const int buf = kt & 1;
        if (kt + 1 < 10) p1_issueB(kt + 1);
        if (kt + 2 < 10) p1_loadA(kt + 2);
        if (kt + 1 < 10) p1_write(kt + 1);
        else { VMCNT0; }
        LGKM0;
        SBAR;

        i16x8 af[4], bfr[4];
#pragma unroll
        for (int m = 0; m < 4; m++)
            af[m] = *(const i16x8*)&Asm[buf][(m * 16 + fr) * 32 + (h ^ rsw) * 8];
#pragma unroll
        for (int n = 0; n < 4; n++)
            bfr[n] = *(const i16x8*)&Bsm[buf][(w * 64 + n * 16 + fr) * 32 + (h ^ rsw) * 8];
        LGKM0;
        SCHED0;
        SBAR;

#pragma unroll
        for (int m = 0; m < 4; m++)
#pragma unroll
            for (int n = 0; n < 4; n++)
                acc[m][n] = __builtin_amdgcn_mfma_f32_16x16x32_bf16(
                    af[m], bfr[n], acc[m][n], 0, 0, 0);
    }

    // ---- assembly epilogue: direct to FVb (bias + gcn + embeddings) ----
#pragma unroll
    for (int m = 0; m < 4; m++) {
#pragma unroll
        for (int j = 0; j < 4; j++) {
            const int grow = row0 + m * 16 + h * 4 + j;
            const int i1 = idx1[grow], i2 = idx2[grow];
#pragma unroll
            for (int n = 0; n < 4; n++) {
                const int gcol = w * 64 + n * 16 + fr;
                float v = acc[m][n][j] + b_vtx[gcol] + b_pe[gcol];
                v += gcn[(size_t)grow * 256 + gcol];
                v += emb1[(size_t)i1 * 256 + gcol];
                v += emb2[(size_t)i2 * 256 + gcol];
                FVb[(size_t)grow * 256 + gcol] = f2b(v);
                acc[m][n][j] = 0.f;
            }
        }
    }
    VMCNT0;     // all FVb stores complete (to L2)
    SBAR;       // every wave's rows written before any readback

    // ---- phase 2: KVQ = FVb @ Wt_kvq (3 chunks), single-barrier steps ----
    auto p2_stageA = [&](int buf, int kt) {
        gload_lds16(FVb + (size_t)(row0 + w * 16 + srow) * 256 + (kt << 5) + sblk,
                    &Asm[buf][(w * 16) * 32]);
    };
    auto p2_stageB = [&](int buf, int kt, const u16* Wb) {
#pragma unroll
        for (int i = 0; i < 4; i++) {
            const int r = w * 64 + i * 16;
            gload_lds16(Wb + (size_t)(r + srow) * 256 + (kt << 5) + sblk,
                        &Bsm[buf][r * 32]);
        }
    };
    p2_stageA(0, 0); p2_stageB(0, 0, Wt_kvq);
    VMCNT0; SBAR;
#pragma unroll 1
    for (int c = 0; c < 3; ++c) {
        const u16* Wb = Wt_kvq + (size_t)c * 65536;
        const float* bc = (c == 0) ? b_kv : ((c == 1) ? b_vv : b_qv);
#pragma unroll
        for (int kt = 0; kt < 8; ++kt) {
            const int buf = kt & 1;
            if (kt < 7) { p2_stageA(buf ^ 1, kt + 1); p2_stageB(buf ^ 1, kt + 1, Wb); }
            else if (c < 2) { p2_stageA(0, 0); p2_stageB(0, 0, Wb + 65536); }

            i16x8 af[4], bfr[4];
#pragma unroll
            for (int m = 0; m < 4; m++)
                af[m] = *(const i16x8*)&Asm[buf][(m * 16 + fr) * 32 + (h ^ rsw) * 8];
#pragma unroll
            for (int n = 0; n < 4; n++)
                bfr[n] = *(const i16x8*)&Bsm[buf][(w * 64 + n * 16 + fr) * 32 + (h ^ rsw) * 8];
            LGKM0;
            SCHED0;
#pragma unroll
            for (int m = 0; m < 4; m++)
#pragma unroll
                for (int n = 0; n < 4; n++)
                    acc[m][n] = __builtin_amdgcn_mfma_f32_16x16x32_bf16(
                        af[m], bfr[n], acc[m][n], 0, 0, 0);
            if (kt < 7) { VMCNT0; SBAR; }
        }
        // store chunk c (overlaps prefetched next-chunk A0/B0 loads)
#pragma unroll
        for (int m = 0; m < 4; m++)
#pragma unroll
            for (int j = 0; j < 4; j++) {
                const int grow = row0 + m * 16 + h * 4 + j;
#pragma unroll
                for (int n = 0; n < 4; n++) {
                    const int gcol = w * 64 + n * 16 + fr;
                    KVQn[(size_t)grow * 768 + c * 256 + gcol] =
                        f2b(acc[m][n][j] + bc[gcol]);
                    acc[m][n][j] = 0.f;
                }
            }
        if (c < 2) { VMCNT0; SBAR; }    // next chunk's A0/B0 landed
    }
}

// ---------------------------------------------------------------------------
// gemmN: BM=64, BN=128, BK=64 (unchanged; used for q_e only)
// ---------------------------------------------------------------------------
template <int EPI, int AMODE, int NT>
__global__ __launch_bounds__(256, 2) void gemmN(
    const void* __restrict__ Av, const u16* __restrict__ Wt,
    const float* __restrict__ bias0, const float* __restrict__ bias1,
    const float* __restrict__ bias2,
    void* __restrict__ Cv, int Nd)
{
    __shared__ u16 Asm[3][64 * 64];
    __shared__ u16 Bsm[3][128 * 64];
    const int t = threadIdx.x;
    const int lane = t & 63, w = t >> 6;
    const int wr = w >> 1, wc = w & 1;
    const int row0 = blockIdx.y * 64, col0 = blockIdx.x * 128;

    f32x4 acc[2][4] = {};

    const int srow = lane >> 3;
    const int sblk = ((lane & 7) ^ srow) * 8;
    const int fr = lane & 15, h = lane >> 4;
    const int lsw = fr & 7;

    float4 farA[2][2][2];

    auto stage_load = [&](int kt) {
        const int buf = kt % 3;
        const int k0 = kt << 6;
        if constexpr (AMODE == 0) {
#pragma unroll
            for (int i = 0; i < 2; i++) {
                const int r = w * 16 + i * 8;
                gload_lds16((const u16*)Av + (size_t)(row0 + r + srow) * 256 + k0 + sblk,
                            &Asm[buf][r * 64]);
            }
        } else {
#pragma unroll
            for (int i = 0; i < 2; i++) {
                const int r = w * 16 + i * 8;
                const float* ap = (const float*)Av + (size_t)(row0 + r + srow) * 256 + k0 + sblk;
                farA[kt & 1][i][0] = *(const float4*)ap;
                farA[kt & 1][i][1] = *(const float4*)(ap + 4);
            }
        }
#pragma unroll
        for (int i = 0; i < 4; i++) {
            const int r = w * 32 + i * 8;
            int ng = col0 + r + srow; if (ng > Nd - 1) ng = Nd - 1;
            gload_lds16(Wt + (size_t)ng * 256 + k0 + sblk, &Bsm[buf][r * 64]);
        }
    };
    auto stage_write = [&](int kt) {
        const int buf = kt % 3;
#pragma unroll
        for (int i = 0; i < 2; i++) {
            const int r = w * 16 + i * 8;
            float4 f0 = farA[kt & 1][i][0], f1 = farA[kt & 1][i][1];
            i16x8 v;
            v[0] = (short)f2b(f0.x); v[1] = (short)f2b(f0.y);
            v[2] = (short)f2b(f0.z); v[3] = (short)f2b(f0.w);
            v[4] = (short)f2b(f1.x); v[5] = (short)f2b(f1.y);
            v[6] = (short)f2b(f1.z); v[7] = (short)f2b(f1.w);
            *(i16x8*)&Asm[buf][(r + srow) * 64 + (lane & 7) * 8] = v;
        }
    };

    stage_load(0);
    if (NT > 1) stage_load(1);
    if constexpr (AMODE != 0) stage_write(0);

#pragma unroll
    for (int kt = 0; kt < NT; ++kt) {
        const int buf = kt % 3;
        if (kt + 2 < NT) stage_load(kt + 2);
        if constexpr (AMODE != 0) {
            if (kt + 1 < NT) stage_write(kt + 1);
            else { VMCNT0; }
        } else {
            if (kt + 2 < NT) { VMCNT12; }
            else if (kt + 1 < NT) { VMCNT6; }
            else { VMCNT0; }
        }
        LGKM0;
        SBAR;

        i16x8 af[2][2], bfr[2][4];
#pragma unroll
        for (int kk = 0; kk < 2; kk++) {
#pragma unroll
            for (int m = 0; m < 2; m++)
                af[kk][m] = *(const i16x8*)&Asm[buf][(wr * 32 + m * 16 + fr) * 64 +
                                                    ((kk * 4 + h) ^ lsw) * 8];
#pragma unroll
            for (int n = 0; n < 4; n++)
                bfr[kk][n] = *(const i16x8*)&Bsm[buf][(wc * 64 + n * 16 + fr) * 64 +
                                                     ((kk * 4 + h) ^ lsw) * 8];
        }
        LGKM0;
        SCHED0;
        SBAR;

#pragma unroll
        for (int kk = 0; kk < 2; kk++)
#pragma unroll
            for (int m = 0; m < 2; m++)
#pragma unroll
                for (int n = 0; n < 4; n++)
                    acc[m][n] = __builtin_amdgcn_mfma_f32_16x16x32_bf16(
                        af[kk][m], bfr[kk][n], acc[m][n], 0, 0, 0);
    }

    const int seg = (int)(blockIdx.x >> 1);
    const float* bp = (seg == 0) ? bias0 : ((seg == 1) ? bias1 : bias2);
#pragma unroll
    for (int m = 0; m < 2; m++) {
#pragma unroll
        for (int j = 0; j < 4; j++) {
            const int grow = row0 + wr * 32 + m * 16 + h * 4 + j;
#pragma unroll
            for (int n = 0; n < 4; n++) {
                const int gcol = col0 + wc * 64 + n * 16 + fr;
                if (EPI == 4 && gcol >= Nd) continue;
                float v = acc[m][n][j] + bp[gcol & 255];
                if constexpr (EPI == 1) v = fmaxf(v, 0.f);
                if constexpr (EPI == 4)
                    ((float*)Cv)[(size_t)grow * Nd + gcol] = v;
                else
                    ((u16*)Cv)[(size_t)grow * Nd + gcol] = f2b(v);
            }
        }
    }
}

// ---------------------------------------------------------------------------
// ffn_fused (unchanged from R9: single-barrier loops + cross-phase prefetch)
// ---------------------------------------------------------------------------
#define MST 264
template <int TAIL>
__global__ __launch_bounds__(256, 2) void ffn_fused(
    const u16* __restrict__ X, const u16* __restrict__ Wt1,
    const float* __restrict__ b1, const u16* __restrict__ Wt2,
    const float* __restrict__ b2, const float* __restrict__ lng,
    const float* __restrict__ lnb, const u16* __restrict__ WtT,
    const float* __restrict__ bT0, const float* __restrict__ bT1,
    void* __restrict__ outp)
{
    __shared__ __align__(16) u16 Asm[2][64 * 32];
    __shared__ __align__(16) u16 Bsm[2][256 * 32];
    __shared__ __align__(16) u16 Msm[64 * MST];
    const int t = threadIdx.x;
    const int lane = t & 63, w = t >> 6;
    const int row0 = blockIdx.x * 64;

    const int srow = lane >> 2;
    const int sblk = ((lane & 3) ^ ((lane >> 3) & 3)) * 8;
    const int fr = lane & 15, h = lane >> 4;
    const int rsw = (fr >> 1) & 3;

    f32x4 acc[4][4] = {};

    auto stageA = [&](int buf, int kt) {
        gload_lds16(X + (size_t)(row0 + w * 16 + srow) * 256 + (kt << 5) + sblk,
                    &Asm[buf][(w * 16) * 32]);
    };
    auto stageB = [&](int buf, int kt, const u16* W) {
#pragma unroll
        for (int i = 0; i < 4; i++) {
            const int r = w * 64 + i * 16;
            gload_lds16(W + (size_t)(r + srow) * 256 + (kt << 5) + sblk,
                        &Bsm[buf][r * 32]);
        }
    };

    // phase 1: mid = relu(X @ Wt1 + b1)
    stageA(0, 0); stageB(0, 0, Wt1);
    VMCNT0; SBAR;
#pragma unroll
    for (int kt = 0; kt < 8; ++kt) {
        const int buf = kt & 1;
        if (kt < 7) { stageA(buf ^ 1, kt + 1); stageB(buf ^ 1, kt + 1, Wt1); }
        else        { stageB(0, 0, Wt2); }

        i16x8 af[4], bfr[4];
#pragma unroll
        for (int m = 0; m < 4; m++)
            af[m] = *(const i16x8*)&Asm[buf][(m * 16 + fr) * 32 + (h ^ rsw) * 8];
#pragma unroll
        for (int n = 0; n < 4; n++)
            bfr[n] = *(const i16x8*)&Bsm[buf][(w * 64 + n * 16 + fr) * 32 + (h ^ rsw) * 8];
        LGKM0;
        SCHED0;
#pragma unroll
        for (int m = 0; m < 4; m++)
#pragma unroll
            for (int n = 0; n < 4; n++)
                acc[m][n] = __builtin_amdgcn_mfma_f32_16x16x32_bf16(
                    af[m], bfr[n], acc[m][n], 0, 0, 0);
        if (kt < 7) { VMCNT0; SBAR; }
    }
    {
        float b1v[4];
#pragma unroll
        for (int n = 0; n < 4; n++) b1v[n] = b1[w * 64 + n * 16 + fr];
#pragma unroll
        for (int m = 0; m < 4; m++)
#pragma unroll
            for (int j = 0; j < 4; j++) {
                const int row = m * 16 + h * 4 + j;
#pragma unroll
                for (int n = 0; n < 4; n++) {
                    const int col = w * 64 + n * 16 + fr;
                    float v = fmaxf(acc[m][n][j] + b1v[n], 0.f);
                    Msm[row * MST + col] = f2b(v);
                    acc[m][n][j] = 0.f;
                }
            }
    }
    __syncthreads();

    // phase 2: y = LN(mid @ Wt2 + b2 + X)
#pragma unroll
    for (int kt = 0; kt < 8; ++kt) {
        const int buf = kt & 1;
        if (kt < 7) stageB(buf ^ 1, kt + 1, Wt2);
        else if (TAIL == 0) stageB(0, 0, WtT);

        i16x8 af[4], bfr[4];
#pragma unroll
        for (int m = 0; m < 4; m++)
            af[m] = *(const i16x8*)&Msm[(m * 16 + fr) * MST + (kt << 5) + h * 8];
#pragma unroll
        for (int n = 0; n < 4; n++)
            bfr[n] = *(const i16x8*)&Bsm[buf][(w * 64 + n * 16 + fr) * 32 + (h ^ rsw) * 8];
        LGKM0;
        SCHED0;
#pragma unroll
        for (int m = 0; m < 4; m++)
#pragma unroll
            for (int n = 0; n < 4; n++)
                acc[m][n] = __builtin_amdgcn_mfma_f32_16x16x32_bf16(
                    af[m], bfr[n], acc[m][n], 0, 0, 0);
        if (kt < 7) { VMCNT0; SBAR; }
    }
    {
        float* redS = (float*)&Asm[0][0];
        float* redQ = redS + 256;
#pragma unroll
        for (int m = 0; m < 4; m++) {
#pragma unroll
            for (int j = 0; j < 4; j++) {
                const int grow = row0 + m * 16 + h * 4 + j;
                float s = 0.f, q = 0.f;
#pragma unroll
                for (int n = 0; n < 4; n++) {
                    const int gcol = w * 64 + n * 16 + fr;
                    float v = acc[m][n][j] + b2[gcol] +
                              b2f(X[(size_t)grow * 256 + gcol]);
                    acc[m][n][j] = v;
                    s += v; q += v * v;
                }
#pragma unroll
                for (int off = 1; off < 16; off <<= 1) {
                    s += __shfl_xor(s, off, 64);
                    q += __shfl_xor(q, off, 64);
                }
                if (fr == 0) {
                    redS[(m * 16 + h * 4 + j) * 4 + w] = s;
                    redQ[(m * 16 + h * 4 + j) * 4 + w] = q;
                }
            }
        }
        __syncthreads();
#pragma unroll
        for (int m = 0; m < 4; m++) {
#pragma unroll
            for (int j = 0; j < 4; j++) {
                const int r = m * 16 + h * 4 + j;
                float4 s4 = *(const float4*)&redS[r * 4];
                float4 q4 = *(const float4*)&redQ[r * 4];
                float mu = (s4.x + s4.y + s4.z + s4.w) * (1.f / DIM);
                float var = (q4.x + q4.y + q4.z + q4.w) * (1.f / DIM) - mu * mu;
                float rr = rsqrtf(var + LN_EPS);
#pragma unroll
                for (int n = 0; n < 4; n++) {
                    const int gcol = w * 64 + n * 16 + fr;
                    float y = (acc[m][n][j] - mu) * rr * lng[gcol] + lnb[gcol];
                    acc[m][n][j] = y;
                }
            }
        }
        __syncthreads();
#pragma unroll
        for (int m = 0; m < 4; m++)
#pragma unroll
            for (int j = 0; j < 4; j++) {
                const int row = m * 16 + h * 4 + j;
#pragma unroll
                for (int n = 0; n < 4; n++)
                    Msm[row * MST + (w * 64 + n * 16 + fr)] = f2b(acc[m][n][j]);
            }
    }
    __syncthreads();

    if constexpr (TAIL == 0) {
        u16* KVe = (u16*)outp;
#pragma unroll 1
        for (int half = 0; half < 2; half++) {
            const u16* Wb = WtT + (size_t)half * 65536;
            const float* bT = half ? bT1 : bT0;
#pragma unroll
            for (int m = 0; m < 4; m++)
#pragma unroll
                for (int n = 0; n < 4; n++)
                    acc[m][n] = f32x4{0.f, 0.f, 0.f, 0.f};
#pragma unroll
            for (int kt = 0; kt < 8; ++kt) {
                const int buf = kt & 1;
                if (kt < 7) stageB(buf ^ 1, kt + 1, Wb);
                else if (half == 0) stageB(0, 0, WtT + 65536);

                i16x8 af[4], bfr[4];
#pragma unroll
                for (int m = 0; m < 4; m++)
                    af[m] = *(const i16x8*)&Msm[(m * 16 + fr) * MST + (kt << 5) + h * 8];
#pragma unroll
                for (int n = 0; n < 4; n++)
                    bfr[n] = *(const i16x8*)&Bsm[buf][(w * 64 + n * 16 + fr) * 32 + (h ^ rsw) * 8];
                LGKM0;
                SCHED0;
#pragma unroll
                for (int m = 0; m < 4; m++)
#pragma unroll
                    for (int n = 0; n < 4; n++)
                        acc[m][n] = __builtin_amdgcn_mfma_f32_16x16x32_bf16(
                            af[m], bfr[n], acc[m][n], 0, 0, 0);
                if (kt < 7) { VMCNT0; SBAR; }
            }
#pragma unroll
            for (int m = 0; m < 4; m++)
#pragma unroll
                for (int j = 0; j < 4; j++) {
                    const int grow = row0 + m * 16 + h * 4 + j;
#pragma unroll
                    for (int n = 0; n < 4; n++) {
                        const int gcol = w * 64 + n * 16 + fr;
                        KVe[(size_t)grow * 512 + half * 256 + gcol] =
                            f2b(acc[m][n][j] + bT[gcol]);
                    }
                }
            if (half == 0) { VMCNT0; SBAR; }
        }
    } else {
        float* out = (float*)outp;
        f32x4 acc3[3] = {};
#pragma unroll
        for (int kk = 0; kk < 8; kk++) {
            i16x8 af = *(const i16x8*)&Msm[(w * 16 + fr) * MST + kk * 32 + h * 8];
#pragma unroll
            for (int n = 0; n < 3; n++) {
                int br = n * 16 + fr; if (br > NCLS - 1) br = NCLS - 1;
                i16x8 bfr = *(const i16x8*)(WtT + (size_t)br * 256 + kk * 32 + h * 8);
                acc3[n] = __builtin_amdgcn_mfma_f32_16x16x32_bf16(af, bfr, acc3[n], 0, 0, 0);
            }
        }
#pragma unroll
        for (int n = 0; n < 3; n++) {
            const int gcol = n * 16 + fr;
            if (gcol >= NCLS) continue;
#pragma unroll
            for (int j = 0; j < 4; j++) {
                const int grow = row0 + w * 16 + h * 4 + j;
                out[(size_t)grow * NCLS + gcol] = acc3[n][j] + bT0[gcol];
            }
        }
    }
}

// ---------------------------------------------------------------------------
// edge_attn (unchanged from R4-R9)
// ---------------------------------------------------------------------------
__global__ __launch_bounds__(256) void edge_attn(
    const u16* __restrict__ KVQn, const u16* __restrict__ QE,
    const float* __restrict__ efeat,
    const int* __restrict__ e2n, const float* __restrict__ cent1,
    const float* __restrict__ g, const float* __restrict__ bb,
    u16* __restrict__ XE)
{
    const int lane = threadIdx.x & 63, w = threadIdx.x >> 6;
    const int e = blockIdx.x * 4 + w;
    const int c4 = lane * 4;

    ushort4 q4 = *(const ushort4*)&QE[(size_t)e * QDIM + c4];
    const float q0 = b2f(q4.x), q1 = b2f(q4.y), q2 = b2f(q4.z), q3 = b2f(q4.w);

    int4 rv[8];
#pragma unroll
    for (int i = 0; i < 8; i++)
        rv[i] = *(const int4*)&e2n[(size_t)e * DE + i * 4];
    int rows[DE];
#pragma unroll
    for (int i = 0; i < 8; i++) {
        rows[i * 4 + 0] = rv[i].x; rows[i * 4 + 1] = rv[i].y;
        rows[i * 4 + 2] = rv[i].z; rows[i * 4 + 3] = rv[i].w;
    }

    float p[DE];
#pragma unroll
    for (int g0 = 0; g0 < DE; g0 += 16) {
        ushort4 k4[16];
#pragma unroll
        for (int j = 0; j < 16; j++)
            k4[j] = *(const ushort4*)&KVQn[(size_t)rows[g0 + j] * 768 + c4];
#pragma unroll
        for (int j = 0; j < 16; j++)
            p[g0 + j] = q0 * b2f(k4[j].x) + q1 * b2f(k4[j].y)
                      + q2 * b2f(k4[j].z) + q3 * b2f(k4[j].w);
    }
#pragma unroll
    for (int off = 32; off; off >>= 1)
#pragma unroll
        for (int d = 0; d < DE; d++)
            p[d] += __shfl_xor(p[d], off, 64);

    float4 cv[8];
#pragma unroll
    for (int i = 0; i < 8; i++)
        cv[i] = *(const float4*)&cent1[(size_t)e * DE + i * 4];
    float cent[DE];
#pragma unroll
    for (int i = 0; i < 8; i++) {
        cent[i * 4 + 0] = cv[i].x; cent[i * 4 + 1] = cv[i].y;
        cent[i * 4 + 2] = cv[i].z; cent[i * 4 + 3] = cv[i].w;
    }
#pragma unroll
    for (int d = 0; d < DE; d++)
        p[d] = (p[d] > 0.f ? p[d] : 0.01f * p[d]) * ATT_SCALE + cent[d];

    float mx = p[0];
#pragma unroll
    for (int d = 1; d < DE; d++) mx = fmaxf(mx, p[d]);
    float s = 0.f;
#pragma unroll
    for (int d = 0; d < DE; d++) { p[d] = __expf(p[d] - mx); s += p[d]; }
    const float inv = 1.f / s;
#pragma unroll
    for (int d = 0; d < DE; d++) p[d] *= inv;

    float a0 = 0.f, a1 = 0.f, a2 = 0.f, a3 = 0.f;
#pragma unroll
    for (int g0 = 0; g0 < DE; g0 += 16) {
        ushort4 v4[16];
#pragma unroll
        for (int j = 0; j < 16; j++)
            v4[j] = *(const ushort4*)&KVQn[(size_t)rows[g0 + j] * 768 + 256 + c4];
#pragma unroll
        for (int j = 0; j < 16; j++) {
            const float sd = p[g0 + j];
            a0 = fmaf(sd, b2f(v4[j].x), a0); a1 = fmaf(sd, b2f(v4[j].y), a1);
            a2 = fmaf(sd, b2f(v4[j].z), a2); a3 = fmaf(sd, b2f(v4[j].w), a3);
        }
    }
    float4 ef = *(const float4*)&efeat[(size_t)e * DIM + c4];
    float x0 = a0 + ef.x, x1 = a1 + ef.y, x2 = a2 + ef.z, x3 = a3 + ef.w;

    float mu = x0 + x1 + x2 + x3;
#pragma unroll
    for (int off = 32; off; off >>= 1) mu += __shfl_xor(mu, off, 64);
    mu *= (1.f / DIM);
    float d0 = x0 - mu, d1 = x1 - mu, d2 = x2 - mu, d3 = x3 - mu;
    float var = d0 * d0 + d1 * d1 + d2 * d2 + d3 * d3;
#pragma unroll
    for (int off = 32; off; off >>= 1) var += __shfl_xor(var, off, 64);
    var *= (1.f / DIM);
    float r = rsqrtf(var + LN_EPS);
    float4 gv = *(const float4*)&g[c4];
    float4 bv = *(const float4*)&bb[c4];
    ushort4 o;
    o.x = f2b(d0 * r * gv.x + bv.x); o.y = f2b(d1 * r * gv.y + bv.y);
    o.z = f2b(d2 * r * gv.z + bv.z); o.w = f2b(d3 * r * gv.w + bv.w);
    *(ushort4*)&XE[(size_t)e * DIM + c4] = o;
}

// ---------------------------------------------------------------------------
// node_attn (unchanged from R4-R9)
// ---------------------------------------------------------------------------
__global__ __launch_bounds__(256) void node_attn(
    const u16* __restrict__ KVe, const u16* __restrict__ KVQn,
    const u16* __restrict__ FV,
    const int* __restrict__ n2e, const float* __restrict__ cent2,
    const float* __restrict__ g, const float* __restrict__ bb,
    u16* __restrict__ XV)
{
    const int lane = threadIdx.x & 63, w = threadIdx.x >> 6;
    const int na = blockIdx.x * 8 + w * 2, nb = na + 1;
    const int c4 = lane * 4;

    ushort4 qa4 = *(const ushort4*)&KVQn[(size_t)na * 768 + 512 + c4];
    ushort4 qb4 = *(const ushort4*)&KVQn[(size_t)nb * 768 + 512 + c4];
    const float qa0 = b2f(qa4.x), qa1 = b2f(qa4.y), qa2 = b2f(qa4.z), qa3 = b2f(qa4.w);
    const float qb0 = b2f(qb4.x), qb1 = b2f(qb4.y), qb2 = b2f(qb4.z), qb3 = b2f(qb4.w);

    int4 r0 = *(const int4*)&n2e[(size_t)na * DV];
    int4 r1 = *(const int4*)&n2e[(size_t)na * DV + 4];
    int4 r2 = *(const int4*)&n2e[(size_t)nb * DV];
    int4 r3 = *(const int4*)&n2e[(size_t)nb * DV + 4];
    int rA[8] = {r0.x, r0.y, r0.z, r0.w, r1.x, r1.y, r1.z, r1.w};
    int rB[8] = {r2.x, r2.y, r2.z, r2.w, r3.x, r3.y, r3.z, r3.w};

    ushort4 kA[8], vA[8], kB[8], vB[8];
#pragma unroll
    for (int d = 0; d < DV; d++) {
        const u16* b = KVe + (size_t)rA[d] * 512 + c4;
        kA[d] = *(const ushort4*)b; vA[d] = *(const ushort4*)(b + 256);
    }
#pragma unroll
    for (int d = 0; d < DV; d++) {
        const u16* b = KVe + (size_t)rB[d] * 512 + c4;
        kB[d] = *(const ushort4*)b; vB[d] = *(const ushort4*)(b + 256);
    }

    float pA[8], pB[8];
#pragma unroll
    for (int d = 0; d < DV; d++) {
        pA[d] = qa0 * b2f(kA[d].x) + qa1 * b2f(kA[d].y)
              + qa2 * b2f(kA[d].z) + qa3 * b2f(kA[d].w);
        pB[d] = qb0 * b2f(kB[d].x) + qb1 * b2f(kB[d].y)
              + qb2 * b2f(kB[d].z) + qb3 * b2f(kB[d].w);
    }
#pragma unroll
    for (int off = 32; off; off >>= 1) {
#pragma unroll
        for (int d = 0; d < DV; d++) {
            pA[d] += __shfl_xor(pA[d], off, 64);
            pB[d] += __shfl_xor(pB[d], off, 64);
        }
    }
    float4 cA0 = *(const float4*)&cent2[(size_t)na * DV];
    float4 cA1 = *(const float4*)&cent2[(size_t)na * DV + 4];
    float4 cB0 = *(const float4*)&cent2[(size_t)nb * DV];
    float4 cB1 = *(const float4*)&cent2[(size_t)nb * DV + 4];
    float cA[8] = {cA0.x, cA0.y, cA0.z, cA0.w, cA1.x, cA1.y, cA1.z, cA1.w};
    float cB[8] = {cB0.x, cB0.y, cB0.z, cB0.w, cB1.x, cB1.y, cB1.z, cB1.w};
#pragma unroll
    for (int d = 0; d < DV; d++) {
        pA[d] = (pA[d] > 0.f ? pA[d] : 0.01f * pA[d]) * ATT_SCALE + cA[d];
        pB[d] = (pB[d] > 0.f ? pB[d] : 0.01f * pB[d]) * ATT_SCALE + cB[d];
    }
    float mA = pA[0], mB = pB[0];
#pragma unroll
    for (int d = 1; d < DV; d++) { mA = fmaxf(mA, pA[d]); mB = fmaxf(mB, pB[d]); }
    float sA = 0.f, sB = 0.f;
#pragma unroll
    for (int d = 0; d < DV; d++) {
        pA[d] = __expf(pA[d] - mA); sA += pA[d];
        pB[d] = __expf(pB[d] - mB); sB += pB[d];
    }
    const float iA = 1.f / sA, iB = 1.f / sB;

    float a0 = 0.f, a1 = 0.f, a2 = 0.f, a3 = 0.f;
    float b0 = 0.f, b1 = 0.f, b2 = 0.f, b3 = 0.f;
#pragma unroll
    for (int d = 0; d < DV; d++) {
        const float sa = pA[d] * iA, sb = pB[d] * iB;
        a0 = fmaf(sa, b2f(vA[d].x), a0); a1 = fmaf(sa, b2f(vA[d].y), a1);
        a2 = fmaf(sa, b2f(vA[d].z), a2); a3 = fmaf(sa, b2f(vA[d].w), a3);
        b0 = fmaf(sb, b2f(vB[d].x), b0); b1 = fmaf(sb, b2f(vB[d].y), b1);
        b2 = fmaf(sb, b2f(vB[d].z), b2); b3 = fmaf(sb, b2f(vB[d].w), b3);
    }
    ushort4 fa = *(const ushort4*)&FV[(size_t)na * DIM + c4];
    ushort4 fb = *(const ushort4*)&FV[(size_t)nb * DIM + c4];
    float xa0 = a0 + b2f(fa.x), xa1 = a1 + b2f(fa.y);
    float xa2 = a2 + b2f(fa.z), xa3 = a3 + b2f(fa.w);
    float xb0 = b0 + b2f(fb.x), xb1 = b1 + b2f(fb.y);
    float xb2 = b2 + b2f(fb.z), xb3 = b3 + b2f(fb.w);

    float muA = xa0 + xa1 + xa2 + xa3, muB = xb0 + xb1 + xb2 + xb3;
#pragma unroll
    for (int off = 32; off; off >>= 1) {
        muA += __shfl_xor(muA, off, 64);
        muB += __shfl_xor(muB, off, 64);
    }
    muA *= (1.f / DIM); muB *= (1.f / DIM);
    float da0 = xa0 - muA, da1 = xa1 - muA, da2 = xa2 - muA, da3 = xa3 - muA;
    float db0 = xb0 - muB, db1 = xb1 - muB, db2 = xb2 - muB, db3 = xb3 - muB;
    float vA_ = da0 * da0 + da1 * da1 + da2 * da2 + da3 * da3;
    float vB_ = db0 * db0 + db1 * db1 + db2 * db2 + db3 * db3;
#pragma unroll
    for (int off = 32; off; off >>= 1) {
        vA_ += __shfl_xor(vA_, off, 64);
        vB_ += __shfl_xor(vB_, off, 64);
    }
    const float rA_ = rsqrtf(vA_ * (1.f / DIM) + LN_EPS);
    const float rB_ = rsqrtf(vB_ * (1.f / DIM) + LN_EPS);
    float4 gv = *(const float4*)&g[c4];
    float4 bv = *(const float4*)&bb[c4];
    ushort4 oa, ob;
    oa.x = f2b(da0 * rA_ * gv.x + bv.x); oa.y = f2b(da1 * rA_ * gv.y + bv.y);
    oa.z = f2b(da2 * rA_ * gv.z + bv.z); oa.w = f2b(da3 * rA_ * gv.w + bv.w);
    ob.x = f2b(db0 * rB_ * gv.x + bv.x); ob.y = f2b(db1 * rB_ * gv.y + bv.y);
    ob.z = f2b(db2 * rB_ * gv.z + bv.z); ob.w = f2b(db3 * rB_ * gv.w + bv.w);
    *(ushort4*)&XV[(size_t)na * DIM + c4] = oa;
    *(ushort4*)&XV[(size_t)nb * DIM + c4] = ob;
}

extern "C" void kernel_launch(void* const* d_in, const int* in_sizes, int n_in,
                              void* d_out, int out_size, void* d_ws, size_t ws_size,
                              hipStream_t stream)
{
    const float* vfeat  = (const float*)d_in[0];
    const float* efeat  = (const float*)d_in[1];
    const float* eign   = (const float*)d_in[2];
    const float* gcn    = (const float*)d_in[3];
    const float* cent1  = (const float*)d_in[4];
    const float* cent2  = (const float*)d_in[5];
    const int*   cidx   = (const int*)d_in[6];
    const int*   uidx   = (const int*)d_in[7];
    const int*   e2n    = (const int*)d_in[8];
    const int*   n2e    = (const int*)d_in[9];
    const float* W_vtx  = (const float*)d_in[10]; const float* b_vtx = (const float*)d_in[11];
    const float* W_pe   = (const float*)d_in[12]; const float* b_pe  = (const float*)d_in[13];
    const float* cs_emb = (const float*)d_in[14]; const float* un_emb= (const float*)d_in[15];
    const float* W_kv   = (const float*)d_in[16]; const float* b_kv  = (const float*)d_in[17];
    const float* W_vv   = (const float*)d_in[18]; const float* b_vv  = (const float*)d_in[19];
    const float* W_qe   = (const float*)d_in[20]; const float* b_qe  = (const float*)d_in[21];
    const float* W_ke   = (const float*)d_in[22]; const float* b_ke  = (const float*)d_in[23];
    const float* W_ve   = (const float*)d_in[24]; const float* b_ve  = (const float*)d_in[25];
    const float* W_qv   = (const float*)d_in[26]; const float* b_qv  = (const float*)d_in[27];
    const float* W_l1   = (const float*)d_in[28]; const float* b_l1  = (const float*)d_in[29];
    const float* W_l2   = (const float*)d_in[30]; const float* b_l2  = (const float*)d_in[31];
    const float* W_l3   = (const float*)d_in[32]; const float* b_l3  = (const float*)d_in[33];
    const float* W_l4   = (const float*)d_in[34]; const float* b_l4  = (const float*)d_in[35];
    const float* ln1_g  = (const float*)d_in[36]; const float* ln1_b = (const float*)d_in[37];
    const float* ln2_g  = (const float*)d_in[38]; const float* ln2_b = (const float*)d_in[39];
    const float* W_cls  = (const float*)d_in[40]; const float* b_cls = (const float*)d_in[41];
    float* out = (float*)d_out;

    const size_t NE = (size_t)N_NODES * DIM;   // 10,240,000
    const size_t EE = (size_t)N_EDGES * DIM;   //  2,048,000
    u16* ws = (u16*)d_ws;
    u16* FVb  = ws;                 // assembled feat_v (resid for node_attn)
    u16* KVQn = FVb + NE;           // [N][768] k_n|v_n|q_v
    u16* B2   = KVQn + 3 * NE;      // x_v
    u16* QEb  = B2 + NE;
    u16* XE   = QEb + EE;           // x_e
    u16* KVe  = XE + EE;            // [E][512] k_e|v_e
    u16* Wp   = KVe + 2 * EE;       // 13 * 65536
    u16* Wt_vtx = Wp +  0 * 65536;
    u16* Wt_pe  = Wp +  1 * 65536;
    u16* Wt_kvq = Wp +  2 * 65536;  // slots 2,3,4 = [768][256]
    u16* Wt_qe  = Wp +  5 * 65536;
    u16* Wt_kve = Wp +  6 * 65536;  // slots 6,7 = [512][256]
    u16* Wt_l1  = Wp +  8 * 65536;
    u16* Wt_l2  = Wp +  9 * 65536;
    u16* Wt_l3  = Wp + 10 * 65536;
    u16* Wt_l4  = Wp + 11 * 65536;
    u16* Wt_cls = Wp + 12 * 65536;

    const dim3 blk(256);
    const dim3 gW(8, 8, 13);
    const dim3 gQE(2, N_EDGES / 64);     // (2,125)

    prep_weights<<<gW, blk, 0, stream>>>(
        W_vtx, W_pe, W_kv, W_vv, W_qv, W_qe, W_ke, W_ve,
        W_l1, W_l2, W_l3, W_l4, W_cls, Wp);

    // fused assembly + KVQ (40 KB LDS -> 4 blocks/CU)
    asm_kvq<<<N_NODES / 64, blk, 0, stream>>>(
        vfeat, eign, Wt_vtx, Wt_pe, b_vtx, b_pe,
        gcn, cs_emb, un_emb, cidx, uidx,
        Wt_kvq, b_kv, b_vv, b_qv, FVb, KVQn);

    // stage 1
    gemmN<0, 1, 4><<<gQE, blk, 0, stream>>>(efeat, Wt_qe,
        b_qe, b_qe, b_qe, QEb, 256);                                    // q_e
    edge_attn<<<N_EDGES / 4, blk, 0, stream>>>(KVQn, QEb, efeat, e2n, cent1,
        ln1_g, ln1_b, XE);
    ffn_fused<0><<<N_EDGES / 64, blk, 0, stream>>>(XE, Wt_l1, b_l1,
        Wt_l2, b_l2, ln1_g, ln1_b, Wt_kve, b_ke, b_ve, KVe);            // FFN+LN+{k_e|v_e}

    // stage 2
    node_attn<<<N_NODES / 8, blk, 0, stream>>>(KVe, KVQn, FVb, n2e, cent2,
        ln2_g, ln2_b, B2);                                              // x_v
    ffn_fused<1><<<N_NODES / 64, blk, 0, stream>>>(B2, Wt_l3, b_l3,
        Wt_l4, b_l4, ln2_g, ln2_b, Wt_cls, b_cls, nullptr, out);        // FFN+LN+cls
}

// Round 12
// 311.182 us; speedup vs baseline: 1.0831x; 1.0831x over previous
//
// R11: barrier-free weight reads (B direct from L2-resident global, no Bsm).
// asm_kvq: phase-1 A-only LDS staging; phase-2 fully barrier-free. ffn_fused:
// same treatment; LDS 74->42KB => 3 blocks/CU on both. R10's FVb-direct
// epilogue reverted (back to Msm). q_e/attention/prep byte-identical to R9.
#include <hip/hip_runtime.h>
#include <hip/hip_bf16.h>
#include <cstddef>

#define N_NODES 40000
#define N_EDGES 8000
#define DE 32
#define DV 8
#define DIM 256
#define QDIM 256
#define EIGD 64
#define NCLS 40
#define LN_EPS 1e-5f
#define ATT_SCALE 0.0625f   // 1/sqrt(256)

typedef unsigned short u16;
typedef unsigned int u32;
using i16x8 = __attribute__((ext_vector_type(8))) short;
using f32x4 = __attribute__((ext_vector_type(4))) float;

__device__ inline u16 f2b(float f) {   // RNE f32 -> bf16 bits
    union { float f; u32 u; } c; c.f = f;
    u32 u = c.u + 0x7FFF + ((c.u >> 16) & 1);
    return (u16)(u >> 16);
}
__device__ inline float b2f(u16 b) {
    union { u32 u; float f; } c; c.u = (u32)b << 16;
    return c.f;
}

__device__ inline void gload_lds16(const u16* g, u16* l) {
    __builtin_amdgcn_global_load_lds(
        (const __attribute__((address_space(1))) void*)g,
        (__attribute__((address_space(3))) void*)l, 16, 0, 0);
}

#define VMCNT12 asm volatile("s_waitcnt vmcnt(12)" ::: "memory")
#define VMCNT6  asm volatile("s_waitcnt vmcnt(6)" ::: "memory")
#define VMCNT0  asm volatile("s_waitcnt vmcnt(0)" ::: "memory")
#define LGKM0   asm volatile("s_waitcnt lgkmcnt(0)" ::: "memory")
#define SCHED0  __builtin_amdgcn_sched_barrier(0)
#define SBAR    __builtin_amdgcn_s_barrier()

// ---------------------------------------------------------------------------
// Batched transpose-cast. Slots: 0 vtx, 1 pe, 2 kv, 3 vv, 4 qv, 5 qe,
// 6 ke, 7 ve, 8 l1, 9 l2, 10 l3, 11 l4, 12 cls.
// ---------------------------------------------------------------------------
__global__ __launch_bounds__(256) void prep_weights(
    const float* w0, const float* w1, const float* w2, const float* w3,
    const float* w4, const float* w5, const float* w6, const float* w7,
    const float* w8, const float* w9, const float* w10, const float* w11,
    const float* w12, u16* __restrict__ pool)
{
    const float* srcs[13] = {w0,w1,w2,w3,w4,w5,w6,w7,w8,w9,w10,w11,w12};
    const int Ks[13]  = {256,64,256,256,256,256,256,256,256,256,256,256,256};
    const int Nds[13] = {256,256,256,256,256,256,256,256,256,256,256,256,40};
    const int id = blockIdx.z;
    const float* W = srcs[id];
    u16* Wt = pool + (size_t)id * 65536;
    const int K = Ks[id], Nd = Nds[id];
    const int k0 = blockIdx.x * 32, n0 = blockIdx.y * 32;
    if (k0 >= K || n0 >= Nd) return;

    __shared__ float tile[32][33];
    const int x = threadIdx.x & 31, y4 = (threadIdx.x >> 5) * 4;
#pragma unroll
    for (int j = 0; j < 4; j++) {
        int k = k0 + y4 + j;
        tile[y4 + j][x] = (k < K && (n0 + x) < Nd) ? W[(size_t)k * Nd + n0 + x] : 0.f;
    }
    __syncthreads();
#pragma unroll
    for (int j = 0; j < 4; j++) {
        int n = n0 + y4 + j;
        if (n < Nd && (k0 + x) < K)
            Wt[(size_t)n * K + k0 + x] = f2b(tile[x][y4 + j]);
    }
}

// ---------------------------------------------------------------------------
// asm_kvq v3: LDS = Asm(8K) + Msm(33.75K) = 41.75K -> 3 blocks/CU.
// Phase 1: FV = vfeat@Wt_vtx + eign@Wt_pe; A LDS-staged (proven 2-barrier
//          skeleton), B read DIRECT from global (L2-resident weights).
// Add:     coalesced Msm += gcn + embeddings; writes FVb + Msm in place.
// Phase 2: KVQ = Msm @ Wt_kvq, fully barrier-free (A read-only LDS, B direct).
// ---------------------------------------------------------------------------
#define MST 264
__global__ __launch_bounds__(256, 3) void asm_kvq(
    const float* __restrict__ vfeat, const float* __restrict__ eign,
    const u16* __restrict__ Wt_vtx, const u16* __restrict__ Wt_pe,
    const float* __restrict__ b_vtx, const float* __restrict__ b_pe,
    const float* __restrict__ gcn, const float* __restrict__ emb1,
    const float* __restrict__ emb2, const int* __restrict__ idx1,
    const int* __restrict__ idx2,
    const u16* __restrict__ Wt_kvq, const float* __restrict__ b_kv,
    const float* __restrict__ b_vv, const float* __restrict__ b_qv,
    u16* __restrict__ FVb, u16* __restrict__ KVQn)
{
    __shared__ __align__(16) u16 Asm[2][64 * 32];   //  8 KB
    __shared__ __align__(16) u16 Msm[64 * MST];     // 33.75 KB
    const int t = threadIdx.x;
    const int lane = t & 63, w = t >> 6;
    const int row0 = blockIdx.x * 64;

    const int srow = lane >> 2;                          // 0..15
    const int sblk = ((lane & 3) ^ ((lane >> 3) & 3)) * 8;  // swizzled src blk
    const int fr = lane & 15, h = lane >> 4;
    const int rsw = (fr >> 1) & 3;

    f32x4 acc[4][4] = {};
    float4 fA[2][2];                                      // [parity][half]

    auto p1_loadA = [&](int kt) {
        const int k0 = kt << 5;
        const bool tail = (k0 >= 256);
        const float* ap = tail
            ? eign + (size_t)(row0 + w * 16 + srow) * 64 + (k0 - 256) + sblk
            : vfeat + (size_t)(row0 + w * 16 + srow) * 256 + k0 + sblk;
        fA[kt & 1][0] = *(const float4*)ap;
        fA[kt & 1][1] = *(const float4*)(ap + 4);
    };
    auto p1_write = [&](int kt) {                         // cvt + ds_write
        const int buf = kt & 1;
        float4 f0 = fA[buf][0], f1 = fA[buf][1];
        i16x8 v;
        v[0] = (short)f2b(f0.x); v[1] = (short)f2b(f0.y);
        v[2] = (short)f2b(f0.z); v[3] = (short)f2b(f0.w);
        v[4] = (short)f2b(f1.x); v[5] = (short)f2b(f1.y);
        v[6] = (short)f2b(f1.z); v[7] = (short)f2b(f1.w);
        *(i16x8*)&Asm[buf][(w * 16 + srow) * 32 + (lane & 3) * 8] = v;
    };

    // ---- phase 1 (NT=10): A via LDS dbuf, B direct from global ----
    p1_loadA(0); p1_loadA(1); p1_write(0);
#pragma unroll
    for (int kt = 0; kt < 10; ++kt) {
        const int buf = kt & 1;
        if (kt + 2 < 10) p1_loadA(kt + 2);
        if (kt + 1 < 10) p1_write(kt + 1);
        else { VMCNT0; }
        LGKM0;
        SBAR;                                  // Asm[buf] staged

        i16x8 af[4], bfr[4];
#pragma unroll
        for (int m = 0; m < 4; m++)
            af[m] = *(const i16x8*)&Asm[buf][(m * 16 + fr) * 32 + (h ^ rsw) * 8];
        {
            const bool tail = (kt >= 8);
#pragma unroll
            for (int n = 0; n < 4; n++) {
                const int br = w * 64 + n * 16 + fr;
                bfr[n] = tail
                    ? *(const i16x8*)(Wt_pe + (size_t)br * 64 + ((kt - 8) << 5) + h * 8)
                    : *(const i16x8*)(Wt_vtx + (size_t)br * 256 + (kt << 5) + h * 8);
            }
        }
        LGKM0;
        SCHED0;
        SBAR;                                  // Asm reads done

#pragma unroll
        for (int m = 0; m < 4; m++)
#pragma unroll
            for (int n = 0; n < 4; n++)
                acc[m][n] = __builtin_amdgcn_mfma_f32_16x16x32_bf16(
                    af[m], bfr[n], acc[m][n], 0, 0, 0);
    }

    // ---- phase 1 epilogue: acc + biases -> Msm ----
#pragma unroll
    for (int m = 0; m < 4; m++)
#pragma unroll
        for (int j = 0; j < 4; j++) {
            const int row = m * 16 + h * 4 + j;
#pragma unroll
            for (int n = 0; n < 4; n++) {
                const int col = w * 64 + n * 16 + fr;
                float v = acc[m][n][j] + b_vtx[col] + b_pe[col];
                Msm[row * MST + col] = f2b(v);
            }
        }
    __syncthreads();

    // ---- coalesced add pass: Msm += gcn + emb1[idx1] + emb2[idx2] ----
    const float4* gcn4 = (const float4*)gcn;
    const float4* e1_4 = (const float4*)emb1;
    const float4* e2_4 = (const float4*)emb2;
    ushort4* FVb4 = (ushort4*)FVb;
#pragma unroll 4
    for (int it = 0; it < 16; ++it) {
        const int T = t + it * 256;
        const int row = T >> 6, cg = T & 63;
        const int grow = row0 + row;
        const int i1 = idx1[grow], i2 = idx2[grow];
        ushort4 mv = *(const ushort4*)&Msm[row * MST + cg * 4];
        float4 gv = gcn4[(size_t)grow * 64 + cg];
        float4 e1 = e1_4[(size_t)i1 * 64 + cg];
        float4 e2 = e2_4[(size_t)i2 * 64 + cg];
        ushort4 o;
        o.x = f2b(b2f(mv.x) + gv.x + e1.x + e2.x);
        o.y = f2b(b2f(mv.y) + gv.y + e1.y + e2.y);
        o.z = f2b(b2f(mv.z) + gv.z + e1.z + e2.z);
        o.w = f2b(b2f(mv.w) + gv.w + e1.w + e2.w);
        FVb4[(size_t)grow * 64 + cg] = o;
        *(ushort4*)&Msm[row * MST + cg * 4] = o;
    }
    __syncthreads();                 // Msm final; read-only below

    // ---- phase 2: barrier-free. A from Msm, B direct from L2 ----
#pragma unroll 1
    for (int c = 0; c < 3; ++c) {
        const u16* Wb = Wt_kvq + (size_t)c * 65536;
        const float* bc = (c == 0) ? b_kv : ((c == 1) ? b_vv : b_qv);
        f32x4 a2[4][4] = {};
#pragma unroll
        for (int kt = 0; kt < 8; ++kt) {
            i16x8 af[4], bfr[4];
#pragma unroll
            for (int m = 0; m < 4; m++)
                af[m] = *(const i16x8*)&Msm[(m * 16 + fr) * MST + (kt << 5) + h * 8];
#pragma unroll
            for (int n = 0; n < 4; n++)
                bfr[n] = *(const i16x8*)(Wb + (size_t)(w * 64 + n * 16 + fr) * 256 +
                                         (kt << 5) + h * 8);
#pragma unroll
            for (int m = 0; m < 4; m++)
#pragma unroll
                for (int n = 0; n < 4; n++)
                    a2[m][n] = __builtin_amdgcn_mfma_f32_16x16x32_bf16(
                        af[m], bfr[n], a2[m][n], 0, 0, 0);
        }
#pragma unroll
        for (int m = 0; m < 4; m++)
#pragma unroll
            for (int j = 0; j < 4; j++) {
                const int grow = row0 + m * 16 + h * 4 + j;
#pragma unroll
                for (int n = 0; n < 4; n++) {
                    const int gcol = w * 64 + n * 16 + fr;
                    KVQn[(size_t)grow * 768 + c * 256 + gcol] =
                        f2b(a2[m][n][j] + bc[gcol]);
                }
            }
    }
}

// ---------------------------------------------------------------------------
// gemmN: BM=64, BN=128, BK=64 (unchanged; used for q_e only)
// ---------------------------------------------------------------------------
template <int EPI, int AMODE, int NT>
__global__ __launch_bounds__(256, 2) void gemmN(
    const void* __restrict__ Av, const u16* __restrict__ Wt,
    const float* __restrict__ bias0, const float* __restrict__ bias1,
    const float* __restrict__ bias2,
    void* __restrict__ Cv, int Nd)
{
    __shared__ u16 Asm[3][64 * 64];
    __shared__ u16 Bsm[3][128 * 64];
    const int t = threadIdx.x;
    const int lane = t & 63, w = t >> 6;
    const int wr = w >> 1, wc = w & 1;
    const int row0 = blockIdx.y * 64, col0 = blockIdx.x * 128;

    f32x4 acc[2][4] = {};

    const int srow = lane >> 3;
    const int sblk = ((lane & 7) ^ srow) * 8;
    const int fr = lane & 15, h = lane >> 4;
    const int lsw = fr & 7;

    float4 farA[2][2][2];

    auto stage_load = [&](int kt) {
        const int buf = kt % 3;
        const int k0 = kt << 6;
        if constexpr (AMODE == 0) {
#pragma unroll
            for (int i = 0; i < 2; i++) {
                const int r = w * 16 + i * 8;
                gload_lds16((const u16*)Av + (size_t)(row0 + r + srow) * 256 + k0 + sblk,
                            &Asm[buf][r * 64]);
            }
        } else {
#pragma unroll
            for (int i = 0; i < 2; i++) {
                const int r = w * 16 + i * 8;
                const float* ap = (const float*)Av + (size_t)(row0 + r + srow) * 256 + k0 + sblk;
                farA[kt & 1][i][0] = *(const float4*)ap;
                farA[kt & 1][i][1] = *(const float4*)(ap + 4);
            }
        }
#pragma unroll
        for (int i = 0; i < 4; i++) {
            const int r = w * 32 + i * 8;
            int ng = col0 + r + srow; if (ng > Nd - 1) ng = Nd - 1;
            gload_lds16(Wt + (size_t)ng * 256 + k0 + sblk, &Bsm[buf][r * 64]);
        }
    };
    auto stage_write = [&](int kt) {
        const int buf = kt % 3;
#pragma unroll
        for (int i = 0; i < 2; i++) {
            const int r = w * 16 + i * 8;
            float4 f0 = farA[kt & 1][i][0], f1 = farA[kt & 1][i][1];
            i16x8 v;
            v[0] = (short)f2b(f0.x); v[1] = (short)f2b(f0.y);
            v[2] = (short)f2b(f0.z); v[3] = (short)f2b(f0.w);
            v[4] = (short)f2b(f1.x); v[5] = (short)f2b(f1.y);
            v[6] = (short)f2b(f1.z); v[7] = (short)f2b(f1.w);
            *(i16x8*)&Asm[buf][(r + srow) * 64 + (lane & 7) * 8] = v;
        }
    };

    stage_load(0);
    if (NT > 1) stage_load(1);
    if constexpr (AMODE != 0) stage_write(0);

#pragma unroll
    for (int kt = 0; kt < NT; ++kt) {
        const int buf = kt % 3;
        if (kt + 2 < NT) stage_load(kt + 2);
        if constexpr (AMODE != 0) {
            if (kt + 1 < NT) stage_write(kt + 1);
            else { VMCNT0; }
        } else {
            if (kt + 2 < NT) { VMCNT12; }
            else if (kt + 1 < NT) { VMCNT6; }
            else { VMCNT0; }
        }
        LGKM0;
        SBAR;

        i16x8 af[2][2], bfr[2][4];
#pragma unroll
        for (int kk = 0; kk < 2; kk++) {
#pragma unroll
            for (int m = 0; m < 2; m++)
                af[kk][m] = *(const i16x8*)&Asm[buf][(wr * 32 + m * 16 + fr) * 64 +
                                                    ((kk * 4 + h) ^ lsw) * 8];
#pragma unroll
            for (int n = 0; n < 4; n++)
                bfr[kk][n] = *(const i16x8*)&Bsm[buf][(wc * 64 + n * 16 + fr) * 64 +
                                                     ((kk * 4 + h) ^ lsw) * 8];
        }
        LGKM0;
        SCHED0;
        SBAR;

#pragma unroll
        for (int kk = 0; kk < 2; kk++)
#pragma unroll
            for (int m = 0; m < 2; m++)
#pragma unroll
                for (int n = 0; n < 4; n++)
                    acc[m][n] = __builtin_amdgcn_mfma_f32_16x16x32_bf16(
                        af[kk][m], bfr[kk][n], acc[m][n], 0, 0, 0);
    }

    const int seg = (int)(blockIdx.x >> 1);
    const float* bp = (seg == 0) ? bias0 : ((seg == 1) ? bias1 : bias2);
#pragma unroll
    for (int m = 0; m < 2; m++) {
#pragma unroll
        for (int j = 0; j < 4; j++) {
            const int grow = row0 + wr * 32 + m * 16 + h * 4 + j;
#pragma unroll
            for (int n = 0; n < 4; n++) {
                const int gcol = col0 + wc * 64 + n * 16 + fr;
                if (EPI == 4 && gcol >= Nd) continue;
                float v = acc[m][n][j] + bp[gcol & 255];
                if constexpr (EPI == 1) v = fmaxf(v, 0.f);
                if constexpr (EPI == 4)
                    ((float*)Cv)[(size_t)grow * Nd + gcol] = v;
                else
                    ((u16*)Cv)[(size_t)grow * Nd + gcol] = f2b(v);
            }
        }
    }
}

// ---------------------------------------------------------------------------
// ffn_fused v2: LDS = Asm(8K) + Msm(33.75K) -> 3 blocks/CU.
// Phase 1: A via LDS dbuf (1 gload/wave/step), B direct from global.
// Phase 2 + KV tail: barrier-free (A from Msm read-only, B direct).
// ---------------------------------------------------------------------------
template <int TAIL>
__global__ __launch_bounds__(256, 3) void ffn_fused(
    const u16* __restrict__ X, const u16* __restrict__ Wt1,
    const float* __restrict__ b1, const u16* __restrict__ Wt2,
    const float* __restrict__ b2, const float* __restrict__ lng,
    const float* __restrict__ lnb, const u16* __restrict__ WtT,
    const float* __restrict__ bT0, const float* __restrict__ bT1,
    void* __restrict__ outp)
{
    __shared__ __align__(16) u16 Asm[2][64 * 32];
    __shared__ __align__(16) u16 Msm[64 * MST];
    const int t = threadIdx.x;
    const int lane = t & 63, w = t >> 6;
    const int row0 = blockIdx.x * 64;

    const int srow = lane >> 2;
    const int sblk = ((lane & 3) ^ ((lane >> 3) & 3)) * 8;
    const int fr = lane & 15, h = lane >> 4;
    const int rsw = (fr >> 1) & 3;

    f32x4 acc[4][4] = {};

    auto stageA = [&](int buf, int kt) {
        gload_lds16(X + (size_t)(row0 + w * 16 + srow) * 256 + (kt << 5) + sblk,
                    &Asm[buf][(w * 16) * 32]);
    };

    // ---- phase 1: mid = relu(X @ Wt1 + b1); A LDS dbuf, B direct ----
    stageA(0, 0);
    VMCNT0; SBAR;
#pragma unroll
    for (int kt = 0; kt < 8; ++kt) {
        const int buf = kt & 1;
        if (kt < 7) stageA(buf ^ 1, kt + 1);

        i16x8 af[4], bfr[4];
#pragma unroll
        for (int m = 0; m < 4; m++)
            af[m] = *(const i16x8*)&Asm[buf][(m * 16 + fr) * 32 + (h ^ rsw) * 8];
#pragma unroll
        for (int n = 0; n < 4; n++)
            bfr[n] = *(const i16x8*)(Wt1 + (size_t)(w * 64 + n * 16 + fr) * 256 +
                                     (kt << 5) + h * 8);
        LGKM0;
        SCHED0;
#pragma unroll
        for (int m = 0; m < 4; m++)
#pragma unroll
            for (int n = 0; n < 4; n++)
                acc[m][n] = __builtin_amdgcn_mfma_f32_16x16x32_bf16(
                    af[m], bfr[n], acc[m][n], 0, 0, 0);
        if (kt < 7) { VMCNT0; SBAR; }
    }
    {   // mid -> Msm (relu + bias)
        float b1v[4];
#pragma unroll
        for (int n = 0; n < 4; n++) b1v[n] = b1[w * 64 + n * 16 + fr];
#pragma unroll
        for (int m = 0; m < 4; m++)
#pragma unroll
            for (int j = 0; j < 4; j++) {
                const int row = m * 16 + h * 4 + j;
#pragma unroll
                for (int n = 0; n < 4; n++) {
                    const int col = w * 64 + n * 16 + fr;
                    float v = fmaxf(acc[m][n][j] + b1v[n], 0.f);
                    Msm[row * MST + col] = f2b(v);
                    acc[m][n][j] = 0.f;
                }
            }
    }
    __syncthreads();

    // ---- phase 2: y = LN(mid @ Wt2 + b2 + X); barrier-free ----
#pragma unroll
    for (int kt = 0; kt < 8; ++kt) {
        i16x8 af[4], bfr[4];
#pragma unroll
        for (int m = 0; m < 4; m++)
            af[m] = *(const i16x8*)&Msm[(m * 16 + fr) * MST + (kt << 5) + h * 8];
#pragma unroll
        for (int n = 0; n < 4; n++)
            bfr[n] = *(const i16x8*)(Wt2 + (size_t)(w * 64 + n * 16 + fr) * 256 +
                                     (kt << 5) + h * 8);
#pragma unroll
        for (int m = 0; m < 4; m++)
#pragma unroll
            for (int n = 0; n < 4; n++)
                acc[m][n] = __builtin_amdgcn_mfma_f32_16x16x32_bf16(
                    af[m], bfr[n], acc[m][n], 0, 0, 0);
    }
    {   // LN epilogue (resid = X re-read from global)
        float* redS = (float*)&Asm[0][0];
        float* redQ = redS + 256;
#pragma unroll
        for (int m = 0; m < 4; m++) {
#pragma unroll
            for (int j = 0; j < 4; j++) {
                const int grow = row0 + m * 16 + h * 4 + j;
                float s = 0.f, q = 0.f;
#pragma unroll
                for (int n = 0; n < 4; n++) {
                    const int gcol = w * 64 + n * 16 + fr;
                    float v = acc[m][n][j] + b2[gcol] +
                              b2f(X[(size_t)grow * 256 + gcol]);
                    acc[m][n][j] = v;
                    s += v; q += v * v;
                }
#pragma unroll
                for (int off = 1; off < 16; off <<= 1) {
                    s += __shfl_xor(s, off, 64);
                    q += __shfl_xor(q, off, 64);
                }
                if (fr == 0) {
                    redS[(m * 16 + h * 4 + j) * 4 + w] = s;
                    redQ[(m * 16 + h * 4 + j) * 4 + w] = q;
                }
            }
        }
        __syncthreads();
#pragma unroll
        for (int m = 0; m < 4; m++) {
#pragma unroll
            for (int j = 0; j < 4; j++) {
                const int r = m * 16 + h * 4 + j;
                float4 s4 = *(const float4*)&redS[r * 4];
                float4 q4 = *(const float4*)&redQ[r * 4];
                float mu = (s4.x + s4.y + s4.z + s4.w) * (1.f / DIM);
                float var = (q4.x + q4.y + q4.z + q4.w) * (1.f / DIM) - mu * mu;
                float rr = rsqrtf(var + LN_EPS);
#pragma unroll
                for (int n = 0; n < 4; n++) {
                    const int gcol = w * 64 + n * 16 + fr;
                    float y = (acc[m][n][j] - mu) * rr * lng[gcol] + lnb[gcol];
                    acc[m][n][j] = y;
                }
            }
        }
        __syncthreads();
#pragma unroll
        for (int m = 0; m < 4; m++)
#pragma unroll
            for (int j = 0; j < 4; j++) {
                const int row = m * 16 + h * 4 + j;
#pragma unroll
                for (int n = 0; n < 4; n++)
                    Msm[row * MST + (w * 64 + n * 16 + fr)] = f2b(acc[m][n][j]);
            }
    }
    __syncthreads();

    // ---- tail ----
    if constexpr (TAIL == 0) {
        u16* KVe = (u16*)outp;
#pragma unroll 1
        for (int half = 0; half < 2; half++) {
            const u16* Wb = WtT + (size_t)half * 65536;
            const float* bT = half ? bT1 : bT0;
            f32x4 a2[4][4] = {};
#pragma unroll
            for (int kt = 0; kt < 8; ++kt) {
                i16x8 af[4], bfr[4];
#pragma unroll
                for (int m = 0; m < 4; m++)
                    af[m] = *(const i16x8*)&Msm[(m * 16 + fr) * MST + (kt << 5) + h * 8];
#pragma unroll
                for (int n = 0; n < 4; n++)
                    bfr[n] = *(const i16x8*)(Wb + (size_t)(w * 64 + n * 16 + fr) * 256 +
                                             (kt << 5) + h * 8);
#pragma unroll
                for (int m = 0; m < 4; m++)
#pragma unroll
                    for (int n = 0; n < 4; n++)
                        a2[m][n] = __builtin_amdgcn_mfma_f32_16x16x32_bf16(
                            af[m], bfr[n], a2[m][n], 0, 0, 0);
            }
#pragma unroll
            for (int m = 0; m < 4; m++)
#pragma unroll
                for (int j = 0; j < 4; j++) {
                    const int grow = row0 + m * 16 + h * 4 + j;
#pragma unroll
                    for (int n = 0; n < 4; n++) {
                        const int gcol = w * 64 + n * 16 + fr;
                        KVe[(size_t)grow * 512 + half * 256 + gcol] =
                            f2b(a2[m][n][j] + bT[gcol]);
                    }
                }
        }
    } else {
        float* out = (float*)outp;
        f32x4 acc3[3] = {};
#pragma unroll
        for (int kk = 0; kk < 8; kk++) {
            i16x8 af = *(const i16x8*)&Msm[(w * 16 + fr) * MST + kk * 32 + h * 8];
#pragma unroll
            for (int n = 0; n < 3; n++) {
                int br = n * 16 + fr; if (br > NCLS - 1) br = NCLS - 1;
                i16x8 bfr = *(const i16x8*)(WtT + (size_t)br * 256 + kk * 32 + h * 8);
                acc3[n] = __builtin_amdgcn_mfma_f32_16x16x32_bf16(af, bfr, acc3[n], 0, 0, 0);
            }
        }
#pragma unroll
        for (int n = 0; n < 3; n++) {
            const int gcol = n * 16 + fr;
            if (gcol >= NCLS) continue;
#pragma unroll
            for (int j = 0; j < 4; j++) {
                const int grow = row0 + w * 16 + h * 4 + j;
                out[(size_t)grow * NCLS + gcol] = acc3[n][j] + bT0[gcol];
            }
        }
    }
}

// ---------------------------------------------------------------------------
// edge_attn (unchanged from R4-R9)
// ---------------------------------------------------------------------------
__global__ __launch_bounds__(256) void edge_attn(
    const u16* __restrict__ KVQn, const u16* __restrict__ QE,
    const float* __restrict__ efeat,
    const int* __restrict__ e2n, const float* __restrict__ cent1,
    const float* __restrict__ g, const float* __restrict__ bb,
    u16* __restrict__ XE)
{
    const int lane = threadIdx.x & 63, w = threadIdx.x >> 6;
    const int e = blockIdx.x * 4 + w;
    const int c4 = lane * 4;

    ushort4 q4 = *(const ushort4*)&QE[(size_t)e * QDIM + c4];
    const float q0 = b2f(q4.x), q1 = b2f(q4.y), q2 = b2f(q4.z), q3 = b2f(q4.w);

    int4 rv[8];
#pragma unroll
    for (int i = 0; i < 8; i++)
        rv[i] = *(const int4*)&e2n[(size_t)e * DE + i * 4];
    int rows[DE];
#pragma unroll
    for (int i = 0; i < 8; i++) {
        rows[i * 4 + 0] = rv[i].x; rows[i * 4 + 1] = rv[i].y;
        rows[i * 4 + 2] = rv[i].z; rows[i * 4 + 3] = rv[i].w;
    }

    float p[DE];
#pragma unroll
    for (int g0 = 0; g0 < DE; g0 += 16) {
        ushort4 k4[16];
#pragma unroll
        for (int j = 0; j < 16; j++)
            k4[j] = *(const ushort4*)&KVQn[(size_t)rows[g0 + j] * 768 + c4];
#pragma unroll
        for (int j = 0; j < 16; j++)
            p[g0 + j] = q0 * b2f(k4[j].x) + q1 * b2f(k4[j].y)
                      + q2 * b2f(k4[j].z) + q3 * b2f(k4[j].w);
    }
#pragma unroll
    for (int off = 32; off; off >>= 1)
#pragma unroll
        for (int d = 0; d < DE; d++)
            p[d] += __shfl_xor(p[d], off, 64);

    float4 cv[8];
#pragma unroll
    for (int i = 0; i < 8; i++)
        cv[i] = *(const float4*)&cent1[(size_t)e * DE + i * 4];
    float cent[DE];
#pragma unroll
    for (int i = 0; i < 8; i++) {
        cent[i * 4 + 0] = cv[i].x; cent[i * 4 + 1] = cv[i].y;
        cent[i * 4 + 2] = cv[i].z; cent[i * 4 + 3] = cv[i].w;
    }
#pragma unroll
    for (int d = 0; d < DE; d++)
        p[d] = (p[d] > 0.f ? p[d] : 0.01f * p[d]) * ATT_SCALE + cent[d];

    float mx = p[0];
#pragma unroll
    for (int d = 1; d < DE; d++) mx = fmaxf(mx, p[d]);
    float s = 0.f;
#pragma unroll
    for (int d = 0; d < DE; d++) { p[d] = __expf(p[d] - mx); s += p[d]; }
    const float inv = 1.f / s;
#pragma unroll
    for (int d = 0; d < DE; d++) p[d] *= inv;

    float a0 = 0.f, a1 = 0.f, a2 = 0.f, a3 = 0.f;
#pragma unroll
    for (int g0 = 0; g0 < DE; g0 += 16) {
        ushort4 v4[16];
#pragma unroll
        for (int j = 0; j < 16; j++)
            v4[j] = *(const ushort4*)&KVQn[(size_t)rows[g0 + j] * 768 + 256 + c4];
#pragma unroll
        for (int j = 0; j < 16; j++) {
            const float sd = p[g0 + j];
            a0 = fmaf(sd, b2f(v4[j].x), a0); a1 = fmaf(sd, b2f(v4[j].y), a1);
            a2 = fmaf(sd, b2f(v4[j].z), a2); a3 = fmaf(sd, b2f(v4[j].w), a3);
        }
    }
    float4 ef = *(const float4*)&efeat[(size_t)e * DIM + c4];
    float x0 = a0 + ef.x, x1 = a1 + ef.y, x2 = a2 + ef.z, x3 = a3 + ef.w;

    float mu = x0 + x1 + x2 + x3;
#pragma unroll
    for (int off = 32; off; off >>= 1) mu += __shfl_xor(mu, off, 64);
    mu *= (1.f / DIM);
    float d0 = x0 - mu, d1 = x1 - mu, d2 = x2 - mu, d3 = x3 - mu;
    float var = d0 * d0 + d1 * d1 + d2 * d2 + d3 * d3;
#pragma unroll
    for (int off = 32; off; off >>= 1) var += __shfl_xor(var, off, 64);
    var *= (1.f / DIM);
    float r = rsqrtf(var + LN_EPS);
    float4 gv = *(const float4*)&g[c4];
    float4 bv = *(const float4*)&bb[c4];
    ushort4 o;
    o.x = f2b(d0 * r * gv.x + bv.x); o.y = f2b(d1 * r * gv.y + bv.y);
    o.z = f2b(d2 * r * gv.z + bv.z); o.w = f2b(d3 * r * gv.w + bv.w);
    *(ushort4*)&XE[(size_t)e * DIM + c4] = o;
}

// ---------------------------------------------------------------------------
// node_attn (unchanged from R4-R9)
// ---------------------------------------------------------------------------
__global__ __launch_bounds__(256) void node_attn(
    const u16* __restrict__ KVe, const u16* __restrict__ KVQn,
    const u16* __restrict__ FV,
    const int* __restrict__ n2e, const float* __restrict__ cent2,
    const float* __restrict__ g, const float* __restrict__ bb,
    u16* __restrict__ XV)
{
    const int lane = threadIdx.x & 63, w = threadIdx.x >> 6;
    const int na = blockIdx.x * 8 + w * 2, nb = na + 1;
    const int c4 = lane * 4;

    ushort4 qa4 = *(const ushort4*)&KVQn[(size_t)na * 768 + 512 + c4];
    ushort4 qb4 = *(const ushort4*)&KVQn[(size_t)nb * 768 + 512 + c4];
    const float qa0 = b2f(qa4.x), qa1 = b2f(qa4.y), qa2 = b2f(qa4.z), qa3 = b2f(qa4.w);
    const float qb0 = b2f(qb4.x), qb1 = b2f(qb4.y), qb2 = b2f(qb4.z), qb3 = b2f(qb4.w);

    int4 r0 = *(const int4*)&n2e[(size_t)na * DV];
    int4 r1 = *(const int4*)&n2e[(size_t)na * DV + 4];
    int4 r2 = *(const int4*)&n2e[(size_t)nb * DV];
    int4 r3 = *(const int4*)&n2e[(size_t)nb * DV + 4];
    int rA[8] = {r0.x, r0.y, r0.z, r0.w, r1.x, r1.y, r1.z, r1.w};
    int rB[8] = {r2.x, r2.y, r2.z, r2.w, r3.x, r3.y, r3.z, r3.w};

    ushort4 kA[8], vA[8], kB[8], vB[8];
#pragma unroll
    for (int d = 0; d < DV; d++) {
        const u16* b = KVe + (size_t)rA[d] * 512 + c4;
        kA[d] = *(const ushort4*)b; vA[d] = *(const ushort4*)(b + 256);
    }
#pragma unroll
    for (int d = 0; d < DV; d++) {
        const u16* b = KVe + (size_t)rB[d] * 512 + c4;
        kB[d] = *(const ushort4*)b; vB[d] = *(const ushort4*)(b + 256);
    }

    float pA[8], pB[8];
#pragma unroll
    for (int d = 0; d < DV; d++) {
        pA[d] = qa0 * b2f(kA[d].x) + qa1 * b2f(kA[d].y)
              + qa2 * b2f(kA[d].z) + qa3 * b2f(kA[d].w);
        pB[d] = qb0 * b2f(kB[d].x) + qb1 * b2f(kB[d].y)
              + qb2 * b2f(kB[d].z) + qb3 * b2f(kB[d].w);
    }
#pragma unroll
    for (int off = 32; off; off >>= 1) {
#pragma unroll
        for (int d = 0; d < DV; d++) {
            pA[d] += __shfl_xor(pA[d], off, 64);
            pB[d] += __shfl_xor(pB[d], off, 64);
        }
    }
    float4 cA0 = *(const float4*)&cent2[(size_t)na * DV];
    float4 cA1 = *(const float4*)&cent2[(size_t)na * DV + 4];
    float4 cB0 = *(const float4*)&cent2[(size_t)nb * DV];
    float4 cB1 = *(const float4*)&cent2[(size_t)nb * DV + 4];
    float cA[8] = {cA0.x, cA0.y, cA0.z, cA0.w, cA1.x, cA1.y, cA1.z, cA1.w};
    float cB[8] = {cB0.x, cB0.y, cB0.z, cB0.w, cB1.x, cB1.y, cB1.z, cB1.w};
#pragma unroll
    for (int d = 0; d < DV; d++) {
        pA[d] = (pA[d] > 0.f ? pA[d] : 0.01f * pA[d]) * ATT_SCALE + cA[d];
        pB[d] = (pB[d] > 0.f ? pB[d] : 0.01f * pB[d]) * ATT_SCALE + cB[d];
    }
    float mA = pA[0], mB = pB[0];
#pragma unroll
    for (int d = 1; d < DV; d++) { mA = fmaxf(mA, pA[d]); mB = fmaxf(mB, pB[d]); }
    float sA = 0.f, sB = 0.f;
#pragma unroll
    for (int d = 0; d < DV; d++) {
        pA[d] = __expf(pA[d] - mA); sA += pA[d];
        pB[d] = __expf(pB[d] - mB); sB += pB[d];
    }
    const float iA = 1.f / sA, iB = 1.f / sB;

    float a0 = 0.f, a1 = 0.f, a2 = 0.f, a3 = 0.f;
    float b0 = 0.f, b1 = 0.f, b2 = 0.f, b3 = 0.f;
#pragma unroll
    for (int d = 0; d < DV; d++) {
        const float sa = pA[d] * iA, sb = pB[d] * iB;
        a0 = fmaf(sa, b2f(vA[d].x), a0); a1 = fmaf(sa, b2f(vA[d].y), a1);
        a2 = fmaf(sa, b2f(vA[d].z), a2); a3 = fmaf(sa, b2f(vA[d].w), a3);
        b0 = fmaf(sb, b2f(vB[d].x), b0); b1 = fmaf(sb, b2f(vB[d].y), b1);
        b2 = fmaf(sb, b2f(vB[d].z), b2); b3 = fmaf(sb, b2f(vB[d].w), b3);
    }
    ushort4 fa = *(const ushort4*)&FV[(size_t)na * DIM + c4];
    ushort4 fb = *(const ushort4*)&FV[(size_t)nb * DIM + c4];
    float xa0 = a0 + b2f(fa.x), xa1 = a1 + b2f(fa.y);
    float xa2 = a2 + b2f(fa.z), xa3 = a3 + b2f(fa.w);
    float xb0 = b0 + b2f(fb.x), xb1 = b1 + b2f(fb.y);
    float xb2 = b2 + b2f(fb.z), xb3 = b3 + b2f(fb.w);

    float muA = xa0 + xa1 + xa2 + xa3, muB = xb0 + xb1 + xb2 + xb3;
#pragma unroll
    for (int off = 32; off; off >>= 1) {
        muA += __shfl_xor(muA, off, 64);
        muB += __shfl_xor(muB, off, 64);
    }
    muA *= (1.f / DIM); muB *= (1.f / DIM);
    float da0 = xa0 - muA, da1 = xa1 - muA, da2 = xa2 - muA, da3 = xa3 - muA;
    float db0 = xb0 - muB, db1 = xb1 - muB, db2 = xb2 - muB, db3 = xb3 - muB;
    float vA_ = da0 * da0 + da1 * da1 + da2 * da2 + da3 * da3;
    float vB_ = db0 * db0 + db1 * db1 + db2 * db2 + db3 * db3;
#pragma unroll
    for (int off = 32; off; off >>= 1) {
        vA_ += __shfl_xor(vA_, off, 64);
        vB_ += __shfl_xor(vB_, off, 64);
    }
    const float rA_ = rsqrtf(vA_ * (1.f / DIM) + LN_EPS);
    const float rB_ = rsqrtf(vB_ * (1.f / DIM) + LN_EPS);
    float4 gv = *(const float4*)&g[c4];
    float4 bv = *(const float4*)&bb[c4];
    ushort4 oa, ob;
    oa.x = f2b(da0 * rA_ * gv.x + bv.x); oa.y = f2b(da1 * rA_ * gv.y + bv.y);
    oa.z = f2b(da2 * rA_ * gv.z + bv.z); oa.w = f2b(da3 * rA_ * gv.w + bv.w);
    ob.x = f2b(db0 * rB_ * gv.x + bv.x); ob.y = f2b(db1 * rB_ * gv.y + bv.y);
    ob.z = f2b(db2 * rB_ * gv.z + bv.z); ob.w = f2b(db3 * rB_ * gv.w + bv.w);
    *(ushort4*)&XV[(size_t)na * DIM + c4] = oa;
    *(ushort4*)&XV[(size_t)nb * DIM + c4] = ob;
}

extern "C" void kernel_launch(void* const* d_in, const int* in_sizes, int n_in,
                              void* d_out, int out_size, void* d_ws, size_t ws_size,
                              hipStream_t stream)
{
    const float* vfeat  = (const float*)d_in[0];
    const float* efeat  = (const float*)d_in[1];
    const float* eign   = (const float*)d_in[2];
    const float* gcn    = (const float*)d_in[3];
    const float* cent1  = (const float*)d_in[4];
    const float* cent2  = (const float*)d_in[5];
    const int*   cidx   = (const int*)d_in[6];
    const int*   uidx   = (const int*)d_in[7];
    const int*   e2n    = (const int*)d_in[8];
    const int*   n2e    = (const int*)d_in[9];
    const float* W_vtx  = (const float*)d_in[10]; const float* b_vtx = (const float*)d_in[11];
    const float* W_pe   = (const float*)d_in[12]; const float* b_pe  = (const float*)d_in[13];
    const float* cs_emb = (const float*)d_in[14]; const float* un_emb= (const float*)d_in[15];
    const float* W_kv   = (const float*)d_in[16]; const float* b_kv  = (const float*)d_in[17];
    const float* W_vv   = (const float*)d_in[18]; const float* b_vv  = (const float*)d_in[19];
    const float* W_qe   = (const float*)d_in[20]; const float* b_qe  = (const float*)d_in[21];
    const float* W_ke   = (const float*)d_in[22]; const float* b_ke  = (const float*)d_in[23];
    const float* W_ve   = (const float*)d_in[24]; const float* b_ve  = (const float*)d_in[25];
    const float* W_qv   = (const float*)d_in[26]; const float* b_qv  = (const float*)d_in[27];
    const float* W_l1   = (const float*)d_in[28]; const float* b_l1  = (const float*)d_in[29];
    const float* W_l2   = (const float*)d_in[30]; const float* b_l2  = (const float*)d_in[31];
    const float* W_l3   = (const float*)d_in[32]; const float* b_l3  = (const float*)d_in[33];
    const float* W_l4   = (const float*)d_in[34]; const float* b_l4  = (const float*)d_in[35];
    const float* ln1_g  = (const float*)d_in[36]; const float* ln1_b = (const float*)d_in[37];
    const float* ln2_g  = (const float*)d_in[38]; const float* ln2_b = (const float*)d_in[39];
    const float* W_cls  = (const float*)d_in[40]; const float* b_cls = (const float*)d_in[41];
    float* out = (float*)d_out;

    const size_t NE = (size_t)N_NODES * DIM;   // 10,240,000
    const size_t EE = (size_t)N_EDGES * DIM;   //  2,048,000
    u16* ws = (u16*)d_ws;
    u16* FVb  = ws;                 // assembled feat_v (resid for node_attn)
    u16* KVQn = FVb + NE;           // [N][768] k_n|v_n|q_v
    u16* B2   = KVQn + 3 * NE;      // x_v
    u16* QEb  = B2 + NE;
    u16* XE   = QEb + EE;           // x_e
    u16* KVe  = XE + EE;            // [E][512] k_e|v_e
    u16* Wp   = KVe + 2 * EE;       // 13 * 65536
    u16* Wt_vtx = Wp +  0 * 65536;
    u16* Wt_pe  = Wp +  1 * 65536;
    u16* Wt_kvq = Wp +  2 * 65536;  // slots 2,3,4 = [768][256]
    u16* Wt_qe  = Wp +  5 * 65536;
    u16* Wt_kve = Wp +  6 * 65536;  // slots 6,7 = [512][256]
    u16* Wt_l1  = Wp +  8 * 65536;
    u16* Wt_l2  = Wp +  9 * 65536;
    u16* Wt_l3  = Wp + 10 * 65536;
    u16* Wt_l4  = Wp + 11 * 65536;
    u16* Wt_cls = Wp + 12 * 65536;

    const dim3 blk(256);
    const dim3 gW(8, 8, 13);
    const dim3 gQE(2, N_EDGES / 64);     // (2,125)

    prep_weights<<<gW, blk, 0, stream>>>(
        W_vtx, W_pe, W_kv, W_vv, W_qv, W_qe, W_ke, W_ve,
        W_l1, W_l2, W_l3, W_l4, W_cls, Wp);

    // fused assembly + KVQ (41.75 KB LDS -> 3 blocks/CU)
    asm_kvq<<<N_NODES / 64, blk, 0, stream>>>(
        vfeat, eign, Wt_vtx, Wt_pe, b_vtx, b_pe,
        gcn, cs_emb, un_emb, cidx, uidx,
        Wt_kvq, b_kv, b_vv, b_qv, FVb, KVQn);

    // stage 1
    gemmN<0, 1, 4><<<gQE, blk, 0, stream>>>(efeat, Wt_qe,
        b_qe, b_qe, b_qe, QEb, 256);                                    // q_e
    edge_attn<<<N_EDGES / 4, blk, 0, stream>>>(KVQn, QEb, efeat, e2n, cent1,
        ln1_g, ln1_b, XE);
    ffn_fused<0><<<N_EDGES / 64, blk, 0, stream>>>(XE, Wt_l1, b_l1,
        Wt_l2, b_l2, ln1_g, ln1_b, Wt_kve, b_ke, b_ve, KVe);            // FFN+LN+{k_e|v_e}

    // stage 2
    node_attn<<<N_NODES / 8, blk, 0, stream>>>(KVe, KVQn, FVb, n2e, cent2,
        ln2_g, ln2_b, B2);                                              // x_v
    ffn_fused<1><<<N_NODES / 64, blk, 0, stream>>>(B2, Wt_l3, b_l3,
        Wt_l4, b_l4, ln2_g, ln2_b, Wt_cls, b_cls, nullptr, out);        // FFN+LN+cls
}

// Round 13
// 245.779 us; speedup vs baseline: 1.3713x; 1.2661x over previous
//
// R12: revert to R9 (best, 237 µs) + fold q_e GEMM into asm_kvq as extra
// blocks (grid 625+125; blocks >=625 run the q_e path on the phase-1
// skeleton, concurrent with node-side work). gemmN deleted. All other
// kernels byte-identical to R9.
#include <hip/hip_runtime.h>
#include <hip/hip_bf16.h>
#include <cstddef>

#define N_NODES 40000
#define N_EDGES 8000
#define DE 32
#define DV 8
#define DIM 256
#define QDIM 256
#define EIGD 64
#define NCLS 40
#define LN_EPS 1e-5f
#define ATT_SCALE 0.0625f   // 1/sqrt(256)

typedef unsigned short u16;
typedef unsigned int u32;
using i16x8 = __attribute__((ext_vector_type(8))) short;
using f32x4 = __attribute__((ext_vector_type(4))) float;

__device__ inline u16 f2b(float f) {   // RNE f32 -> bf16 bits
    union { float f; u32 u; } c; c.f = f;
    u32 u = c.u + 0x7FFF + ((c.u >> 16) & 1);
    return (u16)(u >> 16);
}
__device__ inline float b2f(u16 b) {
    union { u32 u; float f; } c; c.u = (u32)b << 16;
    return c.f;
}

__device__ inline void gload_lds16(const u16* g, u16* l) {
    __builtin_amdgcn_global_load_lds(
        (const __attribute__((address_space(1))) void*)g,
        (__attribute__((address_space(3))) void*)l, 16, 0, 0);
}

#define VMCNT0  asm volatile("s_waitcnt vmcnt(0)" ::: "memory")
#define LGKM0   asm volatile("s_waitcnt lgkmcnt(0)" ::: "memory")
#define SCHED0  __builtin_amdgcn_sched_barrier(0)
#define SBAR    __builtin_amdgcn_s_barrier()

// ---------------------------------------------------------------------------
// Batched transpose-cast. Slots: 0 vtx, 1 pe, 2 kv, 3 vv, 4 qv, 5 qe,
// 6 ke, 7 ve, 8 l1, 9 l2, 10 l3, 11 l4, 12 cls.
// ---------------------------------------------------------------------------
__global__ __launch_bounds__(256) void prep_weights(
    const float* w0, const float* w1, const float* w2, const float* w3,
    const float* w4, const float* w5, const float* w6, const float* w7,
    const float* w8, const float* w9, const float* w10, const float* w11,
    const float* w12, u16* __restrict__ pool)
{
    const float* srcs[13] = {w0,w1,w2,w3,w4,w5,w6,w7,w8,w9,w10,w11,w12};
    const int Ks[13]  = {256,64,256,256,256,256,256,256,256,256,256,256,256};
    const int Nds[13] = {256,256,256,256,256,256,256,256,256,256,256,256,40};
    const int id = blockIdx.z;
    const float* W = srcs[id];
    u16* Wt = pool + (size_t)id * 65536;
    const int K = Ks[id], Nd = Nds[id];
    const int k0 = blockIdx.x * 32, n0 = blockIdx.y * 32;
    if (k0 >= K || n0 >= Nd) return;

    __shared__ float tile[32][33];
    const int x = threadIdx.x & 31, y4 = (threadIdx.x >> 5) * 4;
#pragma unroll
    for (int j = 0; j < 4; j++) {
        int k = k0 + y4 + j;
        tile[y4 + j][x] = (k < K && (n0 + x) < Nd) ? W[(size_t)k * Nd + n0 + x] : 0.f;
    }
    __syncthreads();
#pragma unroll
    for (int j = 0; j < 4; j++) {
        int n = n0 + y4 + j;
        if (n < Nd && (k0 + x) < K)
            Wt[(size_t)n * K + k0 + x] = f2b(tile[x][y4 + j]);
    }
}

// ---------------------------------------------------------------------------
// asm_kvq (R9 structure) + q_e fold:
// blocks 0..624  : node path. Phase 1 FV = vfeat@Wt_vtx + eign@Wt_pe (NT=10);
//                  epilogue -> Msm; add pass (gcn+emb) -> FVb & Msm;
//                  phase 2 KVQ = Msm @ Wt_kvq (3 chunks, single-barrier).
// blocks 625..749: q_e path. QEb = efeat@Wt_qe + b_qe (NT=8, same phase-1
//                  skeleton, bias epilogue, early return).
// ---------------------------------------------------------------------------
#define MST 264
__global__ __launch_bounds__(256, 2) void asm_kvq(
    const float* __restrict__ vfeat, const float* __restrict__ eign,
    const float* __restrict__ efeat,
    const u16* __restrict__ Wt_vtx, const u16* __restrict__ Wt_pe,
    const u16* __restrict__ Wt_qe,
    const float* __restrict__ b_vtx, const float* __restrict__ b_pe,
    const float* __restrict__ b_qe,
    const float* __restrict__ gcn, const float* __restrict__ emb1,
    const float* __restrict__ emb2, const int* __restrict__ idx1,
    const int* __restrict__ idx2,
    const u16* __restrict__ Wt_kvq, const float* __restrict__ b_kv,
    const float* __restrict__ b_vv, const float* __restrict__ b_qv,
    u16* __restrict__ FVb, u16* __restrict__ KVQn, u16* __restrict__ QEb)
{
    __shared__ __align__(16) u16 Asm[2][64 * 32];   //  8 KB
    __shared__ __align__(16) u16 Bsm[2][256 * 32];  // 32 KB
    __shared__ __align__(16) u16 Msm[64 * MST];     // 33.75 KB
    const int t = threadIdx.x;
    const int lane = t & 63, w = t >> 6;
    const bool qe = (blockIdx.x >= 625);
    const int row0 = (qe ? ((int)blockIdx.x - 625) : (int)blockIdx.x) * 64;
    const int nt = qe ? 8 : 10;

    const int srow = lane >> 2;                          // 0..15
    const int sblk = ((lane & 3) ^ ((lane >> 3) & 3)) * 8;  // swizzled src blk
    const int fr = lane & 15, h = lane >> 4;
    const int rsw = (fr >> 1) & 3;

    f32x4 acc[4][4] = {};
    float4 fA[2][2];                                      // [parity][half]

    auto p1_issueB = [&](int kt) {
        const int buf = kt & 1;
        const int k0 = kt << 5;
        const bool tail = !qe && (k0 >= 256);
#pragma unroll
        for (int i = 0; i < 4; i++) {
            const int r = w * 64 + i * 16;
            const u16* gp = tail
                ? Wt_pe + (size_t)(r + srow) * 64 + (k0 - 256) + sblk
                : (qe ? Wt_qe : Wt_vtx) + (size_t)(r + srow) * 256 + k0 + sblk;
            gload_lds16(gp, &Bsm[buf][r * 32]);
        }
    };
    auto p1_loadA = [&](int kt) {
        const int k0 = kt << 5;
        const bool tail = !qe && (k0 >= 256);
        const float* ap = tail
            ? eign + (size_t)(row0 + w * 16 + srow) * 64 + (k0 - 256) + sblk
            : (qe ? efeat : vfeat) + (size_t)(row0 + w * 16 + srow) * 256 + k0 + sblk;
        fA[kt & 1][0] = *(const float4*)ap;
        fA[kt & 1][1] = *(const float4*)(ap + 4);
    };
    auto p1_write = [&](int kt) {                         // cvt + ds_write
        const int buf = kt & 1;
        float4 f0 = fA[buf][0], f1 = fA[buf][1];
        i16x8 v;
        v[0] = (short)f2b(f0.x); v[1] = (short)f2b(f0.y);
        v[2] = (short)f2b(f0.z); v[3] = (short)f2b(f0.w);
        v[4] = (short)f2b(f1.x); v[5] = (short)f2b(f1.y);
        v[6] = (short)f2b(f1.z); v[7] = (short)f2b(f1.w);
        *(i16x8*)&Asm[buf][(w * 16 + srow) * 32 + (lane & 3) * 8] = v;
    };

    // ---- phase 1 main loop (R8/R9-proven 2-barrier structure) ----
    p1_loadA(0); p1_issueB(0); p1_loadA(1); p1_write(0);
    for (int kt = 0; kt < nt; ++kt) {
        const int buf = kt & 1;
        if (kt + 1 < nt) p1_issueB(kt + 1);
        if (kt + 2 < nt) p1_loadA(kt + 2);
        if (kt + 1 < nt) p1_write(kt + 1);
        else { VMCNT0; }
        LGKM0;
        SBAR;

        i16x8 af[4], bfr[4];
#pragma unroll
        for (int m = 0; m < 4; m++)
            af[m] = *(const i16x8*)&Asm[buf][(m * 16 + fr) * 32 + (h ^ rsw) * 8];
#pragma unroll
        for (int n = 0; n < 4; n++)
            bfr[n] = *(const i16x8*)&Bsm[buf][(w * 64 + n * 16 + fr) * 32 + (h ^ rsw) * 8];
        LGKM0;
        SCHED0;
        SBAR;

#pragma unroll
        for (int m = 0; m < 4; m++)
#pragma unroll
            for (int n = 0; n < 4; n++)
                acc[m][n] = __builtin_amdgcn_mfma_f32_16x16x32_bf16(
                    af[m], bfr[n], acc[m][n], 0, 0, 0);
    }

    if (qe) {   // ---- q_e epilogue: QEb = acc + b_qe ----
#pragma unroll
        for (int m = 0; m < 4; m++)
#pragma unroll
            for (int j = 0; j < 4; j++) {
                const int grow = row0 + m * 16 + h * 4 + j;
#pragma unroll
                for (int n = 0; n < 4; n++) {
                    const int gcol = w * 64 + n * 16 + fr;
                    QEb[(size_t)grow * 256 + gcol] = f2b(acc[m][n][j] + b_qe[gcol]);
                }
            }
        return;
    }

    // ---- phase 1 epilogue: acc + biases -> Msm ----
#pragma unroll
    for (int m = 0; m < 4; m++)
#pragma unroll
        for (int j = 0; j < 4; j++) {
            const int row = m * 16 + h * 4 + j;
#pragma unroll
            for (int n = 0; n < 4; n++) {
                const int col = w * 64 + n * 16 + fr;
                float v = acc[m][n][j] + b_vtx[col] + b_pe[col];
                Msm[row * MST + col] = f2b(v);
            }
        }
    __syncthreads();

    // ---- coalesced add pass: Msm += gcn + emb1[idx1] + emb2[idx2] ----
    const float4* gcn4 = (const float4*)gcn;
    const float4* e1_4 = (const float4*)emb1;
    const float4* e2_4 = (const float4*)emb2;
    ushort4* FVb4 = (ushort4*)FVb;
#pragma unroll 4
    for (int it = 0; it < 16; ++it) {
        const int T = t + it * 256;
        const int row = T >> 6, cg = T & 63;
        const int grow = row0 + row;
        const int i1 = idx1[grow], i2 = idx2[grow];
        ushort4 mv = *(const ushort4*)&Msm[row * MST + cg * 4];
        float4 gv = gcn4[(size_t)grow * 64 + cg];
        float4 e1 = e1_4[(size_t)i1 * 64 + cg];
        float4 e2 = e2_4[(size_t)i2 * 64 + cg];
        ushort4 o;
        o.x = f2b(b2f(mv.x) + gv.x + e1.x + e2.x);
        o.y = f2b(b2f(mv.y) + gv.y + e1.y + e2.y);
        o.z = f2b(b2f(mv.z) + gv.z + e1.z + e2.z);
        o.w = f2b(b2f(mv.w) + gv.w + e1.w + e2.w);
        FVb4[(size_t)grow * 64 + cg] = o;
        *(ushort4*)&Msm[row * MST + cg * 4] = o;
    }
    __syncthreads();

    // ---- phase 2: KVQ = Msm @ Wt_kvq (3 chunks), single-barrier steps ----
    auto p2_issueB = [&](int buf, int kt, const u16* Wb) {
#pragma unroll
        for (int i = 0; i < 4; i++) {
            const int r = w * 64 + i * 16;
            gload_lds16(Wb + (size_t)(r + srow) * 256 + (kt << 5) + sblk,
                        &Bsm[buf][r * 32]);
        }
    };
    p2_issueB(0, 0, Wt_kvq);
    VMCNT0; SBAR;
#pragma unroll 1
    for (int c = 0; c < 3; ++c) {
        const u16* Wb = Wt_kvq + (size_t)c * 65536;
        const float* bc = (c == 0) ? b_kv : ((c == 1) ? b_vv : b_qv);
#pragma unroll
        for (int m = 0; m < 4; m++)
#pragma unroll
            for (int n = 0; n < 4; n++)
                acc[m][n] = f32x4{0.f, 0.f, 0.f, 0.f};
#pragma unroll
        for (int kt = 0; kt < 8; ++kt) {
            const int buf = kt & 1;
            if (kt < 7) p2_issueB(buf ^ 1, kt + 1, Wb);
            else if (c < 2) p2_issueB(0, 0, Wb + 65536);   // next chunk's B0

            i16x8 af[4], bfr[4];
#pragma unroll
            for (int m = 0; m < 4; m++)
                af[m] = *(const i16x8*)&Msm[(m * 16 + fr) * MST + (kt << 5) + h * 8];
#pragma unroll
            for (int n = 0; n < 4; n++)
                bfr[n] = *(const i16x8*)&Bsm[buf][(w * 64 + n * 16 + fr) * 32 + (h ^ rsw) * 8];
            LGKM0;
            SCHED0;
#pragma unroll
            for (int m = 0; m < 4; m++)
#pragma unroll
                for (int n = 0; n < 4; n++)
                    acc[m][n] = __builtin_amdgcn_mfma_f32_16x16x32_bf16(
                        af[m], bfr[n], acc[m][n], 0, 0, 0);
            if (kt < 7) { VMCNT0; SBAR; }
        }
        // store chunk c (overlaps the prefetched next-chunk B0 loads)
#pragma unroll
        for (int m = 0; m < 4; m++)
#pragma unroll
            for (int j = 0; j < 4; j++) {
                const int grow = row0 + m * 16 + h * 4 + j;
#pragma unroll
                for (int n = 0; n < 4; n++) {
                    const int gcol = w * 64 + n * 16 + fr;
                    KVQn[(size_t)grow * 768 + c * 256 + gcol] =
                        f2b(acc[m][n][j] + bc[gcol]);
                }
            }
        if (c < 2) { VMCNT0; SBAR; }    // next chunk's B0 landed; reads done
    }
}

// ---------------------------------------------------------------------------
// ffn_fused (R9 version: single-barrier loops + cross-phase B0 prefetch)
// ---------------------------------------------------------------------------
template <int TAIL>
__global__ __launch_bounds__(256, 2) void ffn_fused(
    const u16* __restrict__ X, const u16* __restrict__ Wt1,
    const float* __restrict__ b1, const u16* __restrict__ Wt2,
    const float* __restrict__ b2, const float* __restrict__ lng,
    const float* __restrict__ lnb, const u16* __restrict__ WtT,
    const float* __restrict__ bT0, const float* __restrict__ bT1,
    void* __restrict__ outp)
{
    __shared__ __align__(16) u16 Asm[2][64 * 32];
    __shared__ __align__(16) u16 Bsm[2][256 * 32];
    __shared__ __align__(16) u16 Msm[64 * MST];
    const int t = threadIdx.x;
    const int lane = t & 63, w = t >> 6;
    const int row0 = blockIdx.x * 64;

    const int srow = lane >> 2;
    const int sblk = ((lane & 3) ^ ((lane >> 3) & 3)) * 8;
    const int fr = lane & 15, h = lane >> 4;
    const int rsw = (fr >> 1) & 3;

    f32x4 acc[4][4] = {};

    auto stageA = [&](int buf, int kt) {
        gload_lds16(X + (size_t)(row0 + w * 16 + srow) * 256 + (kt << 5) + sblk,
                    &Asm[buf][(w * 16) * 32]);
    };
    auto stageB = [&](int buf, int kt, const u16* W) {
#pragma unroll
        for (int i = 0; i < 4; i++) {
            const int r = w * 64 + i * 16;
            gload_lds16(W + (size_t)(r + srow) * 256 + (kt << 5) + sblk,
                        &Bsm[buf][r * 32]);
        }
    };

    // ---------------- phase 1: mid = relu(X @ Wt1 + b1) ----------------
    stageA(0, 0); stageB(0, 0, Wt1);
    VMCNT0; SBAR;
#pragma unroll
    for (int kt = 0; kt < 8; ++kt) {
        const int buf = kt & 1;
        if (kt < 7) { stageA(buf ^ 1, kt + 1); stageB(buf ^ 1, kt + 1, Wt1); }
        else        { stageB(0, 0, Wt2); }    // prefetch phase-2 B0

        i16x8 af[4], bfr[4];
#pragma unroll
        for (int m = 0; m < 4; m++)
            af[m] = *(const i16x8*)&Asm[buf][(m * 16 + fr) * 32 + (h ^ rsw) * 8];
#pragma unroll
        for (int n = 0; n < 4; n++)
            bfr[n] = *(const i16x8*)&Bsm[buf][(w * 64 + n * 16 + fr) * 32 + (h ^ rsw) * 8];
        LGKM0;
        SCHED0;
#pragma unroll
        for (int m = 0; m < 4; m++)
#pragma unroll
            for (int n = 0; n < 4; n++)
                acc[m][n] = __builtin_amdgcn_mfma_f32_16x16x32_bf16(
                    af[m], bfr[n], acc[m][n], 0, 0, 0);
        if (kt < 7) { VMCNT0; SBAR; }
    }
    {   // mid -> Msm (relu + bias), reset acc
        float b1v[4];
#pragma unroll
        for (int n = 0; n < 4; n++) b1v[n] = b1[w * 64 + n * 16 + fr];
#pragma unroll
        for (int m = 0; m < 4; m++)
#pragma unroll
            for (int j = 0; j < 4; j++) {
                const int row = m * 16 + h * 4 + j;
#pragma unroll
                for (int n = 0; n < 4; n++) {
                    const int col = w * 64 + n * 16 + fr;
                    float v = fmaxf(acc[m][n][j] + b1v[n], 0.f);
                    Msm[row * MST + col] = f2b(v);
                    acc[m][n][j] = 0.f;
                }
            }
    }
    __syncthreads();   // drains vmcnt (phase-2 B0 landed) + lgkm + sync

    // ---------------- phase 2: y = LN(mid @ Wt2 + b2 + X) ----------------
#pragma unroll
    for (int kt = 0; kt < 8; ++kt) {
        const int buf = kt & 1;
        if (kt < 7) stageB(buf ^ 1, kt + 1, Wt2);
        else if (TAIL == 0) stageB(0, 0, WtT);   // prefetch tail half-0 B0

        i16x8 af[4], bfr[4];
#pragma unroll
        for (int m = 0; m < 4; m++)
            af[m] = *(const i16x8*)&Msm[(m * 16 + fr) * MST + (kt << 5) + h * 8];
#pragma unroll
        for (int n = 0; n < 4; n++)
            bfr[n] = *(const i16x8*)&Bsm[buf][(w * 64 + n * 16 + fr) * 32 + (h ^ rsw) * 8];
        LGKM0;
        SCHED0;
#pragma unroll
        for (int m = 0; m < 4; m++)
#pragma unroll
            for (int n = 0; n < 4; n++)
                acc[m][n] = __builtin_amdgcn_mfma_f32_16x16x32_bf16(
                    af[m], bfr[n], acc[m][n], 0, 0, 0);
        if (kt < 7) { VMCNT0; SBAR; }
    }
    {   // LN epilogue (resid = X re-read from global)
        float* redS = (float*)&Asm[0][0];
        float* redQ = redS + 256;
#pragma unroll
        for (int m = 0; m < 4; m++) {
#pragma unroll
            for (int j = 0; j < 4; j++) {
                const int grow = row0 + m * 16 + h * 4 + j;
                float s = 0.f, q = 0.f;
#pragma unroll
                for (int n = 0; n < 4; n++) {
                    const int gcol = w * 64 + n * 16 + fr;
                    float v = acc[m][n][j] + b2[gcol] +
                              b2f(X[(size_t)grow * 256 + gcol]);
                    acc[m][n][j] = v;
                    s += v; q += v * v;
                }
#pragma unroll
                for (int off = 1; off < 16; off <<= 1) {
                    s += __shfl_xor(s, off, 64);
                    q += __shfl_xor(q, off, 64);
                }
                if (fr == 0) {
                    redS[(m * 16 + h * 4 + j) * 4 + w] = s;
                    redQ[(m * 16 + h * 4 + j) * 4 + w] = q;
                }
            }
        }
        __syncthreads();
#pragma unroll
        for (int m = 0; m < 4; m++) {
#pragma unroll
            for (int j = 0; j < 4; j++) {
                const int r = m * 16 + h * 4 + j;
                float4 s4 = *(const float4*)&redS[r * 4];
                float4 q4 = *(const float4*)&redQ[r * 4];
                float mu = (s4.x + s4.y + s4.z + s4.w) * (1.f / DIM);
                float var = (q4.x + q4.y + q4.z + q4.w) * (1.f / DIM) - mu * mu;
                float rr = rsqrtf(var + LN_EPS);
#pragma unroll
                for (int n = 0; n < 4; n++) {
                    const int gcol = w * 64 + n * 16 + fr;
                    float y = (acc[m][n][j] - mu) * rr * lng[gcol] + lnb[gcol];
                    acc[m][n][j] = y;
                }
            }
        }
        __syncthreads();
#pragma unroll
        for (int m = 0; m < 4; m++)
#pragma unroll
            for (int j = 0; j < 4; j++) {
                const int row = m * 16 + h * 4 + j;
#pragma unroll
                for (int n = 0; n < 4; n++)
                    Msm[row * MST + (w * 64 + n * 16 + fr)] = f2b(acc[m][n][j]);
            }
    }
    __syncthreads();   // drains vmcnt (tail B0 landed) + Msm writes visible

    // ---------------- tail ----------------
    if constexpr (TAIL == 0) {
        u16* KVe = (u16*)outp;
#pragma unroll 1
        for (int half = 0; half < 2; half++) {
            const u16* Wb = WtT + (size_t)half * 65536;
            const float* bT = half ? bT1 : bT0;
#pragma unroll
            for (int m = 0; m < 4; m++)
#pragma unroll
                for (int n = 0; n < 4; n++)
                    acc[m][n] = f32x4{0.f, 0.f, 0.f, 0.f};
#pragma unroll
            for (int kt = 0; kt < 8; ++kt) {
                const int buf = kt & 1;
                if (kt < 7) stageB(buf ^ 1, kt + 1, Wb);
                else if (half == 0) stageB(0, 0, WtT + 65536);  // half-1 B0

                i16x8 af[4], bfr[4];
#pragma unroll
                for (int m = 0; m < 4; m++)
                    af[m] = *(const i16x8*)&Msm[(m * 16 + fr) * MST + (kt << 5) + h * 8];
#pragma unroll
                for (int n = 0; n < 4; n++)
                    bfr[n] = *(const i16x8*)&Bsm[buf][(w * 64 + n * 16 + fr) * 32 + (h ^ rsw) * 8];
                LGKM0;
                SCHED0;
#pragma unroll
                for (int m = 0; m < 4; m++)
#pragma unroll
                    for (int n = 0; n < 4; n++)
                        acc[m][n] = __builtin_amdgcn_mfma_f32_16x16x32_bf16(
                            af[m], bfr[n], acc[m][n], 0, 0, 0);
                if (kt < 7) { VMCNT0; SBAR; }
            }
#pragma unroll
            for (int m = 0; m < 4; m++)
#pragma unroll
                for (int j = 0; j < 4; j++) {
                    const int grow = row0 + m * 16 + h * 4 + j;
#pragma unroll
                    for (int n = 0; n < 4; n++) {
                        const int gcol = w * 64 + n * 16 + fr;
                        KVe[(size_t)grow * 512 + half * 256 + gcol] =
                            f2b(acc[m][n][j] + bT[gcol]);
                    }
                }
            if (half == 0) { VMCNT0; SBAR; }   // half-1 B0 landed; reads done
        }
    } else {
        float* out = (float*)outp;
        f32x4 acc3[3] = {};
#pragma unroll
        for (int kk = 0; kk < 8; kk++) {
            i16x8 af = *(const i16x8*)&Msm[(w * 16 + fr) * MST + kk * 32 + h * 8];
#pragma unroll
            for (int n = 0; n < 3; n++) {
                int br = n * 16 + fr; if (br > NCLS - 1) br = NCLS - 1;
                i16x8 bfr = *(const i16x8*)(WtT + (size_t)br * 256 + kk * 32 + h * 8);
                acc3[n] = __builtin_amdgcn_mfma_f32_16x16x32_bf16(af, bfr, acc3[n], 0, 0, 0);
            }
        }
#pragma unroll
        for (int n = 0; n < 3; n++) {
            const int gcol = n * 16 + fr;
            if (gcol >= NCLS) continue;
#pragma unroll
            for (int j = 0; j < 4; j++) {
                const int grow = row0 + w * 16 + h * 4 + j;
                out[(size_t)grow * NCLS + gcol] = acc3[n][j] + bT0[gcol];
            }
        }
    }
}

// ---------------------------------------------------------------------------
// edge_attn (unchanged from R4-R9)
// ---------------------------------------------------------------------------
__global__ __launch_bounds__(256) void edge_attn(
    const u16* __restrict__ KVQn, const u16* __restrict__ QE,
    const float* __restrict__ efeat,
    const int* __restrict__ e2n, const float* __restrict__ cent1,
    const float* __restrict__ g, const float* __restrict__ bb,
    u16* __restrict__ XE)
{
    const int lane = threadIdx.x & 63, w = threadIdx.x >> 6;
    const int e = blockIdx.x * 4 + w;
    const int c4 = lane * 4;

    ushort4 q4 = *(const ushort4*)&QE[(size_t)e * QDIM + c4];
    const float q0 = b2f(q4.x), q1 = b2f(q4.y), q2 = b2f(q4.z), q3 = b2f(q4.w);

    int4 rv[8];
#pragma unroll
    for (int i = 0; i < 8; i++)
        rv[i] = *(const int4*)&e2n[(size_t)e * DE + i * 4];
    int rows[DE];
#pragma unroll
    for (int i = 0; i < 8; i++) {
        rows[i * 4 + 0] = rv[i].x; rows[i * 4 + 1] = rv[i].y;
        rows[i * 4 + 2] = rv[i].z; rows[i * 4 + 3] = rv[i].w;
    }

    float p[DE];
#pragma unroll
    for (int g0 = 0; g0 < DE; g0 += 16) {
        ushort4 k4[16];
#pragma unroll
        for (int j = 0; j < 16; j++)
            k4[j] = *(const ushort4*)&KVQn[(size_t)rows[g0 + j] * 768 + c4];
#pragma unroll
        for (int j = 0; j < 16; j++)
            p[g0 + j] = q0 * b2f(k4[j].x) + q1 * b2f(k4[j].y)
                      + q2 * b2f(k4[j].z) + q3 * b2f(k4[j].w);
    }
#pragma unroll
    for (int off = 32; off; off >>= 1)
#pragma unroll
        for (int d = 0; d < DE; d++)
            p[d] += __shfl_xor(p[d], off, 64);

    float4 cv[8];
#pragma unroll
    for (int i = 0; i < 8; i++)
        cv[i] = *(const float4*)&cent1[(size_t)e * DE + i * 4];
    float cent[DE];
#pragma unroll
    for (int i = 0; i < 8; i++) {
        cent[i * 4 + 0] = cv[i].x; cent[i * 4 + 1] = cv[i].y;
        cent[i * 4 + 2] = cv[i].z; cent[i * 4 + 3] = cv[i].w;
    }
#pragma unroll
    for (int d = 0; d < DE; d++)
        p[d] = (p[d] > 0.f ? p[d] : 0.01f * p[d]) * ATT_SCALE + cent[d];

    float mx = p[0];
#pragma unroll
    for (int d = 1; d < DE; d++) mx = fmaxf(mx, p[d]);
    float s = 0.f;
#pragma unroll
    for (int d = 0; d < DE; d++) { p[d] = __expf(p[d] - mx); s += p[d]; }
    const float inv = 1.f / s;
#pragma unroll
    for (int d = 0; d < DE; d++) p[d] *= inv;

    float a0 = 0.f, a1 = 0.f, a2 = 0.f, a3 = 0.f;
#pragma unroll
    for (int g0 = 0; g0 < DE; g0 += 16) {
        ushort4 v4[16];
#pragma unroll
        for (int j = 0; j < 16; j++)
            v4[j] = *(const ushort4*)&KVQn[(size_t)rows[g0 + j] * 768 + 256 + c4];
#pragma unroll
        for (int j = 0; j < 16; j++) {
            const float sd = p[g0 + j];
            a0 = fmaf(sd, b2f(v4[j].x), a0); a1 = fmaf(sd, b2f(v4[j].y), a1);
            a2 = fmaf(sd, b2f(v4[j].z), a2); a3 = fmaf(sd, b2f(v4[j].w), a3);
        }
    }
    float4 ef = *(const float4*)&efeat[(size_t)e * DIM + c4];
    float x0 = a0 + ef.x, x1 = a1 + ef.y, x2 = a2 + ef.z, x3 = a3 + ef.w;

    float mu = x0 + x1 + x2 + x3;
#pragma unroll
    for (int off = 32; off; off >>= 1) mu += __shfl_xor(mu, off, 64);
    mu *= (1.f / DIM);
    float d0 = x0 - mu, d1 = x1 - mu, d2 = x2 - mu, d3 = x3 - mu;
    float var = d0 * d0 + d1 * d1 + d2 * d2 + d3 * d3;
#pragma unroll
    for (int off = 32; off; off >>= 1) var += __shfl_xor(var, off, 64);
    var *= (1.f / DIM);
    float r = rsqrtf(var + LN_EPS);
    float4 gv = *(const float4*)&g[c4];
    float4 bv = *(const float4*)&bb[c4];
    ushort4 o;
    o.x = f2b(d0 * r * gv.x + bv.x); o.y = f2b(d1 * r * gv.y + bv.y);
    o.z = f2b(d2 * r * gv.z + bv.z); o.w = f2b(d3 * r * gv.w + bv.w);
    *(ushort4*)&XE[(size_t)e * DIM + c4] = o;
}

// ---------------------------------------------------------------------------
// node_attn (unchanged from R4-R9)
// ---------------------------------------------------------------------------
__global__ __launch_bounds__(256) void node_attn(
    const u16* __restrict__ KVe, const u16* __restrict__ KVQn,
    const u16* __restrict__ FV,
    const int* __restrict__ n2e, const float* __restrict__ cent2,
    const float* __restrict__ g, const float* __restrict__ bb,
    u16* __restrict__ XV)
{
    const int lane = threadIdx.x & 63, w = threadIdx.x >> 6;
    const int na = blockIdx.x * 8 + w * 2, nb = na + 1;
    const int c4 = lane * 4;

    ushort4 qa4 = *(const ushort4*)&KVQn[(size_t)na * 768 + 512 + c4];
    ushort4 qb4 = *(const ushort4*)&KVQn[(size_t)nb * 768 + 512 + c4];
    const float qa0 = b2f(qa4.x), qa1 = b2f(qa4.y), qa2 = b2f(qa4.z), qa3 = b2f(qa4.w);
    const float qb0 = b2f(qb4.x), qb1 = b2f(qb4.y), qb2 = b2f(qb4.z), qb3 = b2f(qb4.w);

    int4 r0 = *(const int4*)&n2e[(size_t)na * DV];
    int4 r1 = *(const int4*)&n2e[(size_t)na * DV + 4];
    int4 r2 = *(const int4*)&n2e[(size_t)nb * DV];
    int4 r3 = *(const int4*)&n2e[(size_t)nb * DV + 4];
    int rA[8] = {r0.x, r0.y, r0.z, r0.w, r1.x, r1.y, r1.z, r1.w};
    int rB[8] = {r2.x, r2.y, r2.z, r2.w, r3.x, r3.y, r3.z, r3.w};

    ushort4 kA[8], vA[8], kB[8], vB[8];
#pragma unroll
    for (int d = 0; d < DV; d++) {
        const u16* b = KVe + (size_t)rA[d] * 512 + c4;
        kA[d] = *(const ushort4*)b; vA[d] = *(const ushort4*)(b + 256);
    }
#pragma unroll
    for (int d = 0; d < DV; d++) {
        const u16* b = KVe + (size_t)rB[d] * 512 + c4;
        kB[d] = *(const ushort4*)b; vB[d] = *(const ushort4*)(b + 256);
    }

    float pA[8], pB[8];
#pragma unroll
    for (int d = 0; d < DV; d++) {
        pA[d] = qa0 * b2f(kA[d].x) + qa1 * b2f(kA[d].y)
              + qa2 * b2f(kA[d].z) + qa3 * b2f(kA[d].w);
        pB[d] = qb0 * b2f(kB[d].x) + qb1 * b2f(kB[d].y)
              + qb2 * b2f(kB[d].z) + qb3 * b2f(kB[d].w);
    }
#pragma unroll
    for (int off = 32; off; off >>= 1) {
#pragma unroll
        for (int d = 0; d < DV; d++) {
            pA[d] += __shfl_xor(pA[d], off, 64);
            pB[d] += __shfl_xor(pB[d], off, 64);
        }
    }
    float4 cA0 = *(const float4*)&cent2[(size_t)na * DV];
    float4 cA1 = *(const float4*)&cent2[(size_t)na * DV + 4];
    float4 cB0 = *(const float4*)&cent2[(size_t)nb * DV];
    float4 cB1 = *(const float4*)&cent2[(size_t)nb * DV + 4];
    float cA[8] = {cA0.x, cA0.y, cA0.z, cA0.w, cA1.x, cA1.y, cA1.z, cA1.w};
    float cB[8] = {cB0.x, cB0.y, cB0.z, cB0.w, cB1.x, cB1.y, cB1.z, cB1.w};
#pragma unroll
    for (int d = 0; d < DV; d++) {
        pA[d] = (pA[d] > 0.f ? pA[d] : 0.01f * pA[d]) * ATT_SCALE + cA[d];
        pB[d] = (pB[d] > 0.f ? pB[d] : 0.01f * pB[d]) * ATT_SCALE + cB[d];
    }
    float mA = pA[0], mB = pB[0];
#pragma unroll
    for (int d = 1; d < DV; d++) { mA = fmaxf(mA, pA[d]); mB = fmaxf(mB, pB[d]); }
    float sA = 0.f, sB = 0.f;
#pragma unroll
    for (int d = 0; d < DV; d++) {
        pA[d] = __expf(pA[d] - mA); sA += pA[d];
        pB[d] = __expf(pB[d] - mB); sB += pB[d];
    }
    const float iA = 1.f / sA, iB = 1.f / sB;

    float a0 = 0.f, a1 = 0.f, a2 = 0.f, a3 = 0.f;
    float b0 = 0.f, b1 = 0.f, b2 = 0.f, b3 = 0.f;
#pragma unroll
    for (int d = 0; d < DV; d++) {
        const float sa = pA[d] * iA, sb = pB[d] * iB;
        a0 = fmaf(sa, b2f(vA[d].x), a0); a1 = fmaf(sa, b2f(vA[d].y), a1);
        a2 = fmaf(sa, b2f(vA[d].z), a2); a3 = fmaf(sa, b2f(vA[d].w), a3);
        b0 = fmaf(sb, b2f(vB[d].x), b0); b1 = fmaf(sb, b2f(vB[d].y), b1);
        b2 = fmaf(sb, b2f(vB[d].z), b2); b3 = fmaf(sb, b2f(vB[d].w), b3);
    }
    ushort4 fa = *(const ushort4*)&FV[(size_t)na * DIM + c4];
    ushort4 fb = *(const ushort4*)&FV[(size_t)nb * DIM + c4];
    float xa0 = a0 + b2f(fa.x), xa1 = a1 + b2f(fa.y);
    float xa2 = a2 + b2f(fa.z), xa3 = a3 + b2f(fa.w);
    float xb0 = b0 + b2f(fb.x), xb1 = b1 + b2f(fb.y);
    float xb2 = b2 + b2f(fb.z), xb3 = b3 + b2f(fb.w);

    float muA = xa0 + xa1 + xa2 + xa3, muB = xb0 + xb1 + xb2 + xb3;
#pragma unroll
    for (int off = 32; off; off >>= 1) {
        muA += __shfl_xor(muA, off, 64);
        muB += __shfl_xor(muB, off, 64);
    }
    muA *= (1.f / DIM); muB *= (1.f / DIM);
    float da0 = xa0 - muA, da1 = xa1 - muA, da2 = xa2 - muA, da3 = xa3 - muA;
    float db0 = xb0 - muB, db1 = xb1 - muB, db2 = xb2 - muB, db3 = xb3 - muB;
    float vA_ = da0 * da0 + da1 * da1 + da2 * da2 + da3 * da3;
    float vB_ = db0 * db0 + db1 * db1 + db2 * db2 + db3 * db3;
#pragma unroll
    for (int off = 32; off; off >>= 1) {
        vA_ += __shfl_xor(vA_, off, 64);
        vB_ += __shfl_xor(vB_, off, 64);
    }
    const float rA_ = rsqrtf(vA_ * (1.f / DIM) + LN_EPS);
    const float rB_ = rsqrtf(vB_ * (1.f / DIM) + LN_EPS);
    float4 gv = *(const float4*)&g[c4];
    float4 bv = *(const float4*)&bb[c4];
    ushort4 oa, ob;
    oa.x = f2b(da0 * rA_ * gv.x + bv.x); oa.y = f2b(da1 * rA_ * gv.y + bv.y);
    oa.z = f2b(da2 * rA_ * gv.z + bv.z); oa.w = f2b(da3 * rA_ * gv.w + bv.w);
    ob.x = f2b(db0 * rB_ * gv.x + bv.x); ob.y = f2b(db1 * rB_ * gv.y + bv.y);
    ob.z = f2b(db2 * rB_ * gv.z + bv.z); ob.w = f2b(db3 * rB_ * gv.w + bv.w);
    *(ushort4*)&XV[(size_t)na * DIM + c4] = oa;
    *(ushort4*)&XV[(size_t)nb * DIM + c4] = ob;
}

extern "C" void kernel_launch(void* const* d_in, const int* in_sizes, int n_in,
                              void* d_out, int out_size, void* d_ws, size_t ws_size,
                              hipStream_t stream)
{
    const float* vfeat  = (const float*)d_in[0];
    const float* efeat  = (const float*)d_in[1];
    const float* eign   = (const float*)d_in[2];
    const float* gcn    = (const float*)d_in[3];
    const float* cent1  = (const float*)d_in[4];
    const float* cent2  = (const float*)d_in[5];
    const int*   cidx   = (const int*)d_in[6];
    const int*   uidx   = (const int*)d_in[7];
    const int*   e2n    = (const int*)d_in[8];
    const int*   n2e    = (const int*)d_in[9];
    const float* W_vtx  = (const float*)d_in[10]; const float* b_vtx = (const float*)d_in[11];
    const float* W_pe   = (const float*)d_in[12]; const float* b_pe  = (const float*)d_in[13];
    const float* cs_emb = (const float*)d_in[14]; const float* un_emb= (const float*)d_in[15];
    const float* W_kv   = (const float*)d_in[16]; const float* b_kv  = (const float*)d_in[17];
    const float* W_vv   = (const float*)d_in[18]; const float* b_vv  = (const float*)d_in[19];
    const float* W_qe   = (const float*)d_in[20]; const float* b_qe  = (const float*)d_in[21];
    const float* W_ke   = (const float*)d_in[22]; const float* b_ke  = (const float*)d_in[23];
    const float* W_ve   = (const float*)d_in[24]; const float* b_ve  = (const float*)d_in[25];
    const float* W_qv   = (const float*)d_in[26]; const float* b_qv  = (const float*)d_in[27];
    const float* W_l1   = (const float*)d_in[28]; const float* b_l1  = (const float*)d_in[29];
    const float* W_l2   = (const float*)d_in[30]; const float* b_l2  = (const float*)d_in[31];
    const float* W_l3   = (const float*)d_in[32]; const float* b_l3  = (const float*)d_in[33];
    const float* W_l4   = (const float*)d_in[34]; const float* b_l4  = (const float*)d_in[35];
    const float* ln1_g  = (const float*)d_in[36]; const float* ln1_b = (const float*)d_in[37];
    const float* ln2_g  = (const float*)d_in[38]; const float* ln2_b = (const float*)d_in[39];
    const float* W_cls  = (const float*)d_in[40]; const float* b_cls = (const float*)d_in[41];
    float* out = (float*)d_out;

    const size_t NE = (size_t)N_NODES * DIM;   // 10,240,000
    const size_t EE = (size_t)N_EDGES * DIM;   //  2,048,000
    u16* ws = (u16*)d_ws;
    u16* FVb  = ws;                 // assembled feat_v (resid for node_attn)
    u16* KVQn = FVb + NE;           // [N][768] k_n|v_n|q_v
    u16* B2   = KVQn + 3 * NE;      // x_v
    u16* QEb  = B2 + NE;
    u16* XE   = QEb + EE;           // x_e
    u16* KVe  = XE + EE;            // [E][512] k_e|v_e
    u16* Wp   = KVe + 2 * EE;       // 13 * 65536
    u16* Wt_vtx = Wp +  0 * 65536;
    u16* Wt_pe  = Wp +  1 * 65536;
    u16* Wt_kvq = Wp +  2 * 65536;  // slots 2,3,4 = [768][256]
    u16* Wt_qe  = Wp +  5 * 65536;
    u16* Wt_kve = Wp +  6 * 65536;  // slots 6,7 = [512][256]
    u16* Wt_l1  = Wp +  8 * 65536;
    u16* Wt_l2  = Wp +  9 * 65536;
    u16* Wt_l3  = Wp + 10 * 65536;
    u16* Wt_l4  = Wp + 11 * 65536;
    u16* Wt_cls = Wp + 12 * 65536;

    const dim3 blk(256);
    const dim3 gW(8, 8, 13);

    prep_weights<<<gW, blk, 0, stream>>>(
        W_vtx, W_pe, W_kv, W_vv, W_qv, W_qe, W_ke, W_ve,
        W_l1, W_l2, W_l3, W_l4, W_cls, Wp);

    // fused assembly + KVQ + q_e (blocks 0-624 node path, 625-749 q_e path)
    asm_kvq<<<N_NODES / 64 + N_EDGES / 64, blk, 0, stream>>>(
        vfeat, eign, efeat, Wt_vtx, Wt_pe, Wt_qe,
        b_vtx, b_pe, b_qe,
        gcn, cs_emb, un_emb, cidx, uidx,
        Wt_kvq, b_kv, b_vv, b_qv, FVb, KVQn, QEb);

    // stage 1
    edge_attn<<<N_EDGES / 4, blk, 0, stream>>>(KVQn, QEb, efeat, e2n, cent1,
        ln1_g, ln1_b, XE);
    ffn_fused<0><<<N_EDGES / 64, blk, 0, stream>>>(XE, Wt_l1, b_l1,
        Wt_l2, b_l2, ln1_g, ln1_b, Wt_kve, b_ke, b_ve, KVe);            // FFN+LN+{k_e|v_e}

    // stage 2
    node_attn<<<N_NODES / 8, blk, 0, stream>>>(KVe, KVQn, FVb, n2e, cent2,
        ln2_g, ln2_b, B2);                                              // x_v
    ffn_fused<1><<<N_NODES / 64, blk, 0, stream>>>(B2, Wt_l3, b_l3,
        Wt_l4, b_l4, ln2_g, ln2_b, Wt_cls, b_cls, nullptr, out);        // FFN+LN+cls
}

// Round 14
// 235.575 us; speedup vs baseline: 1.4307x; 1.0433x over previous
//
// R13: verbatim revert to R9 (best measured config, 237.3-237.7 us).
// asm_kvq: fused assembly+KVQ (R8 phase-1 + single-barrier phase 2 w/
// cross-chunk B0 prefetch). gemmN for q_e. ffn_fused x2. Attention R4.
#include <hip/hip_runtime.h>
#include <hip/hip_bf16.h>
#include <cstddef>

#define N_NODES 40000
#define N_EDGES 8000
#define DE 32
#define DV 8
#define DIM 256
#define QDIM 256
#define EIGD 64
#define NCLS 40
#define LN_EPS 1e-5f
#define ATT_SCALE 0.0625f   // 1/sqrt(256)

typedef unsigned short u16;
typedef unsigned int u32;
using i16x8 = __attribute__((ext_vector_type(8))) short;
using f32x4 = __attribute__((ext_vector_type(4))) float;

__device__ inline u16 f2b(float f) {   // RNE f32 -> bf16 bits
    union { float f; u32 u; } c; c.f = f;
    u32 u = c.u + 0x7FFF + ((c.u >> 16) & 1);
    return (u16)(u >> 16);
}
__device__ inline float b2f(u16 b) {
    union { u32 u; float f; } c; c.u = (u32)b << 16;
    return c.f;
}

__device__ inline void gload_lds16(const u16* g, u16* l) {
    __builtin_amdgcn_global_load_lds(
        (const __attribute__((address_space(1))) void*)g,
        (__attribute__((address_space(3))) void*)l, 16, 0, 0);
}

#define VMCNT12 asm volatile("s_waitcnt vmcnt(12)" ::: "memory")
#define VMCNT6  asm volatile("s_waitcnt vmcnt(6)" ::: "memory")
#define VMCNT0  asm volatile("s_waitcnt vmcnt(0)" ::: "memory")
#define LGKM0   asm volatile("s_waitcnt lgkmcnt(0)" ::: "memory")
#define SCHED0  __builtin_amdgcn_sched_barrier(0)
#define SBAR    __builtin_amdgcn_s_barrier()

// ---------------------------------------------------------------------------
// Batched transpose-cast. Slots: 0 vtx, 1 pe, 2 kv, 3 vv, 4 qv, 5 qe,
// 6 ke, 7 ve, 8 l1, 9 l2, 10 l3, 11 l4, 12 cls.
// ---------------------------------------------------------------------------
__global__ __launch_bounds__(256) void prep_weights(
    const float* w0, const float* w1, const float* w2, const float* w3,
    const float* w4, const float* w5, const float* w6, const float* w7,
    const float* w8, const float* w9, const float* w10, const float* w11,
    const float* w12, u16* __restrict__ pool)
{
    const float* srcs[13] = {w0,w1,w2,w3,w4,w5,w6,w7,w8,w9,w10,w11,w12};
    const int Ks[13]  = {256,64,256,256,256,256,256,256,256,256,256,256,256};
    const int Nds[13] = {256,256,256,256,256,256,256,256,256,256,256,256,40};
    const int id = blockIdx.z;
    const float* W = srcs[id];
    u16* Wt = pool + (size_t)id * 65536;
    const int K = Ks[id], Nd = Nds[id];
    const int k0 = blockIdx.x * 32, n0 = blockIdx.y * 32;
    if (k0 >= K || n0 >= Nd) return;

    __shared__ float tile[32][33];
    const int x = threadIdx.x & 31, y4 = (threadIdx.x >> 5) * 4;
#pragma unroll
    for (int j = 0; j < 4; j++) {
        int k = k0 + y4 + j;
        tile[y4 + j][x] = (k < K && (n0 + x) < Nd) ? W[(size_t)k * Nd + n0 + x] : 0.f;
    }
    __syncthreads();
#pragma unroll
    for (int j = 0; j < 4; j++) {
        int n = n0 + y4 + j;
        if (n < Nd && (k0 + x) < K)
            Wt[(size_t)n * K + k0 + x] = f2b(tile[x][y4 + j]);
    }
}

// ---------------------------------------------------------------------------
// asm_kvq: phase 1 (R8 2-barrier structure), add-pass, phase 2 single-barrier
// steps + cross-chunk B0 prefetch.
// ---------------------------------------------------------------------------
#define MST 264
__global__ __launch_bounds__(256, 2) void asm_kvq(
    const float* __restrict__ vfeat, const float* __restrict__ eign,
    const u16* __restrict__ Wt_vtx, const u16* __restrict__ Wt_pe,
    const float* __restrict__ b_vtx, const float* __restrict__ b_pe,
    const float* __restrict__ gcn, const float* __restrict__ emb1,
    const float* __restrict__ emb2, const int* __restrict__ idx1,
    const int* __restrict__ idx2,
    const u16* __restrict__ Wt_kvq, const float* __restrict__ b_kv,
    const float* __restrict__ b_vv, const float* __restrict__ b_qv,
    u16* __restrict__ FVb, u16* __restrict__ KVQn)
{
    __shared__ __align__(16) u16 Asm[2][64 * 32];   //  8 KB
    __shared__ __align__(16) u16 Bsm[2][256 * 32];  // 32 KB
    __shared__ __align__(16) u16 Msm[64 * MST];     // 33.75 KB
    const int t = threadIdx.x;
    const int lane = t & 63, w = t >> 6;
    const int row0 = blockIdx.x * 64;

    const int srow = lane >> 2;                          // 0..15
    const int sblk = ((lane & 3) ^ ((lane >> 3) & 3)) * 8;  // swizzled src blk
    const int fr = lane & 15, h = lane >> 4;
    const int rsw = (fr >> 1) & 3;

    f32x4 acc[4][4] = {};
    float4 fA[2][2];                                      // [parity][half]

    auto p1_issueB = [&](int kt) {
        const int buf = kt & 1;
        const int k0 = kt << 5;
        const bool tail = (k0 >= 256);
#pragma unroll
        for (int i = 0; i < 4; i++) {
            const int r = w * 64 + i * 16;
            const u16* gp = tail ? Wt_pe + (size_t)(r + srow) * 64 + (k0 - 256) + sblk
                                 : Wt_vtx + (size_t)(r + srow) * 256 + k0 + sblk;
            gload_lds16(gp, &Bsm[buf][r * 32]);
        }
    };
    auto p1_loadA = [&](int kt) {
        const int k0 = kt << 5;
        const bool tail = (k0 >= 256);
        const float* ap = tail
            ? eign + (size_t)(row0 + w * 16 + srow) * 64 + (k0 - 256) + sblk
            : vfeat + (size_t)(row0 + w * 16 + srow) * 256 + k0 + sblk;
        fA[kt & 1][0] = *(const float4*)ap;
        fA[kt & 1][1] = *(const float4*)(ap + 4);
    };
    auto p1_write = [&](int kt) {                         // cvt + ds_write
        const int buf = kt & 1;
        float4 f0 = fA[buf][0], f1 = fA[buf][1];
        i16x8 v;
        v[0] = (short)f2b(f0.x); v[1] = (short)f2b(f0.y);
        v[2] = (short)f2b(f0.z); v[3] = (short)f2b(f0.w);
        v[4] = (short)f2b(f1.x); v[5] = (short)f2b(f1.y);
        v[6] = (short)f2b(f1.z); v[7] = (short)f2b(f1.w);
        *(i16x8*)&Asm[buf][(w * 16 + srow) * 32 + (lane & 3) * 8] = v;
    };

    // ---- phase 1 main loop (NT=10; R8-proven 2-barrier structure) ----
    p1_loadA(0); p1_issueB(0); p1_loadA(1); p1_write(0);
#pragma unroll
    for (int kt = 0; kt < 10; ++kt) {
        const int buf = kt & 1;
        if (kt + 1 < 10) p1_issueB(kt + 1);
        if (kt + 2 < 10) p1_loadA(kt + 2);
        if (kt + 1 < 10) p1_write(kt + 1);
        else { VMCNT0; }
        LGKM0;
        SBAR;

        i16x8 af[4], bfr[4];
#pragma unroll
        for (int m = 0; m < 4; m++)
            af[m] = *(const i16x8*)&Asm[buf][(m * 16 + fr) * 32 + (h ^ rsw) * 8];
#pragma unroll
        for (int n = 0; n < 4; n++)
            bfr[n] = *(const i16x8*)&Bsm[buf][(w * 64 + n * 16 + fr) * 32 + (h ^ rsw) * 8];
        LGKM0;
        SCHED0;
        SBAR;

#pragma unroll
        for (int m = 0; m < 4; m++)
#pragma unroll
            for (int n = 0; n < 4; n++)
                acc[m][n] = __builtin_amdgcn_mfma_f32_16x16x32_bf16(
                    af[m], bfr[n], acc[m][n], 0, 0, 0);
    }

    // ---- phase 1 epilogue: acc + biases -> Msm ----
#pragma unroll
    for (int m = 0; m < 4; m++)
#pragma unroll
        for (int j = 0; j < 4; j++) {
            const int row = m * 16 + h * 4 + j;
#pragma unroll
            for (int n = 0; n < 4; n++) {
                const int col = w * 64 + n * 16 + fr;
                float v = acc[m][n][j] + b_vtx[col] + b_pe[col];
                Msm[row * MST + col] = f2b(v);
            }
        }
    __syncthreads();

    // ---- coalesced add pass: Msm += gcn + emb1[idx1] + emb2[idx2] ----
    const float4* gcn4 = (const float4*)gcn;
    const float4* e1_4 = (const float4*)emb1;
    const float4* e2_4 = (const float4*)emb2;
    ushort4* FVb4 = (ushort4*)FVb;
#pragma unroll 4
    for (int it = 0; it < 16; ++it) {
        const int T = t + it * 256;
        const int row = T >> 6, cg = T & 63;
        const int grow = row0 + row;
        const int i1 = idx1[grow], i2 = idx2[grow];
        ushort4 mv = *(const ushort4*)&Msm[row * MST + cg * 4];
        float4 gv = gcn4[(size_t)grow * 64 + cg];
        float4 e1 = e1_4[(size_t)i1 * 64 + cg];
        float4 e2 = e2_4[(size_t)i2 * 64 + cg];
        ushort4 o;
        o.x = f2b(b2f(mv.x) + gv.x + e1.x + e2.x);
        o.y = f2b(b2f(mv.y) + gv.y + e1.y + e2.y);
        o.z = f2b(b2f(mv.z) + gv.z + e1.z + e2.z);
        o.w = f2b(b2f(mv.w) + gv.w + e1.w + e2.w);
        FVb4[(size_t)grow * 64 + cg] = o;
        *(ushort4*)&Msm[row * MST + cg * 4] = o;
    }
    __syncthreads();

    // ---- phase 2: KVQ = Msm @ Wt_kvq (3 chunks), single-barrier steps ----
    auto p2_issueB = [&](int buf, int kt, const u16* Wb) {
#pragma unroll
        for (int i = 0; i < 4; i++) {
            const int r = w * 64 + i * 16;
            gload_lds16(Wb + (size_t)(r + srow) * 256 + (kt << 5) + sblk,
                        &Bsm[buf][r * 32]);
        }
    };
    p2_issueB(0, 0, Wt_kvq);
    VMCNT0; SBAR;
#pragma unroll 1
    for (int c = 0; c < 3; ++c) {
        const u16* Wb = Wt_kvq + (size_t)c * 65536;
        const float* bc = (c == 0) ? b_kv : ((c == 1) ? b_vv : b_qv);
#pragma unroll
        for (int m = 0; m < 4; m++)
#pragma unroll
            for (int n = 0; n < 4; n++)
                acc[m][n] = f32x4{0.f, 0.f, 0.f, 0.f};
#pragma unroll
        for (int kt = 0; kt < 8; ++kt) {
            const int buf = kt & 1;
            if (kt < 7) p2_issueB(buf ^ 1, kt + 1, Wb);
            else if (c < 2) p2_issueB(0, 0, Wb + 65536);   // next chunk's B0

            i16x8 af[4], bfr[4];
#pragma unroll
            for (int m = 0; m < 4; m++)
                af[m] = *(const i16x8*)&Msm[(m * 16 + fr) * MST + (kt << 5) + h * 8];
#pragma unroll
            for (int n = 0; n < 4; n++)
                bfr[n] = *(const i16x8*)&Bsm[buf][(w * 64 + n * 16 + fr) * 32 + (h ^ rsw) * 8];
            LGKM0;
            SCHED0;
#pragma unroll
            for (int m = 0; m < 4; m++)
#pragma unroll
                for (int n = 0; n < 4; n++)
                    acc[m][n] = __builtin_amdgcn_mfma_f32_16x16x32_bf16(
                        af[m], bfr[n], acc[m][n], 0, 0, 0);
            if (kt < 7) { VMCNT0; SBAR; }
        }
        // store chunk c (overlaps the prefetched next-chunk B0 loads)
#pragma unroll
        for (int m = 0; m < 4; m++)
#pragma unroll
            for (int j = 0; j < 4; j++) {
                const int grow = row0 + m * 16 + h * 4 + j;
#pragma unroll
                for (int n = 0; n < 4; n++) {
                    const int gcol = w * 64 + n * 16 + fr;
                    KVQn[(size_t)grow * 768 + c * 256 + gcol] =
                        f2b(acc[m][n][j] + bc[gcol]);
                }
            }
        if (c < 2) { VMCNT0; SBAR; }    // next chunk's B0 landed; reads done
    }
}

// ---------------------------------------------------------------------------
// gemmN: BM=64, BN=128, BK=64 (used for q_e only)
// ---------------------------------------------------------------------------
template <int EPI, int AMODE, int NT>
__global__ __launch_bounds__(256, 2) void gemmN(
    const void* __restrict__ Av, const u16* __restrict__ Wt,
    const float* __restrict__ bias0, const float* __restrict__ bias1,
    const float* __restrict__ bias2,
    void* __restrict__ Cv, int Nd)
{
    __shared__ u16 Asm[3][64 * 64];
    __shared__ u16 Bsm[3][128 * 64];
    const int t = threadIdx.x;
    const int lane = t & 63, w = t >> 6;
    const int wr = w >> 1, wc = w & 1;
    const int row0 = blockIdx.y * 64, col0 = blockIdx.x * 128;

    f32x4 acc[2][4] = {};

    const int srow = lane >> 3;
    const int sblk = ((lane & 7) ^ srow) * 8;
    const int fr = lane & 15, h = lane >> 4;
    const int lsw = fr & 7;

    float4 farA[2][2][2];

    auto stage_load = [&](int kt) {
        const int buf = kt % 3;
        const int k0 = kt << 6;
        if constexpr (AMODE == 0) {
#pragma unroll
            for (int i = 0; i < 2; i++) {
                const int r = w * 16 + i * 8;
                gload_lds16((const u16*)Av + (size_t)(row0 + r + srow) * 256 + k0 + sblk,
                            &Asm[buf][r * 64]);
            }
        } else {
#pragma unroll
            for (int i = 0; i < 2; i++) {
                const int r = w * 16 + i * 8;
                const float* ap = (const float*)Av + (size_t)(row0 + r + srow) * 256 + k0 + sblk;
                farA[kt & 1][i][0] = *(const float4*)ap;
                farA[kt & 1][i][1] = *(const float4*)(ap + 4);
            }
        }
#pragma unroll
        for (int i = 0; i < 4; i++) {
            const int r = w * 32 + i * 8;
            int ng = col0 + r + srow; if (ng > Nd - 1) ng = Nd - 1;
            gload_lds16(Wt + (size_t)ng * 256 + k0 + sblk, &Bsm[buf][r * 64]);
        }
    };
    auto stage_write = [&](int kt) {
        const int buf = kt % 3;
#pragma unroll
        for (int i = 0; i < 2; i++) {
            const int r = w * 16 + i * 8;
            float4 f0 = farA[kt & 1][i][0], f1 = farA[kt & 1][i][1];
            i16x8 v;
            v[0] = (short)f2b(f0.x); v[1] = (short)f2b(f0.y);
            v[2] = (short)f2b(f0.z); v[3] = (short)f2b(f0.w);
            v[4] = (short)f2b(f1.x); v[5] = (short)f2b(f1.y);
            v[6] = (short)f2b(f1.z); v[7] = (short)f2b(f1.w);
            *(i16x8*)&Asm[buf][(r + srow) * 64 + (lane & 7) * 8] = v;
        }
    };

    stage_load(0);
    if (NT > 1) stage_load(1);
    if constexpr (AMODE != 0) stage_write(0);

#pragma unroll
    for (int kt = 0; kt < NT; ++kt) {
        const int buf = kt % 3;
        if (kt + 2 < NT) stage_load(kt + 2);
        if constexpr (AMODE != 0) {
            if (kt + 1 < NT) stage_write(kt + 1);
            else { VMCNT0; }
        } else {
            if (kt + 2 < NT) { VMCNT12; }
            else if (kt + 1 < NT) { VMCNT6; }
            else { VMCNT0; }
        }
        LGKM0;
        SBAR;

        i16x8 af[2][2], bfr[2][4];
#pragma unroll
        for (int kk = 0; kk < 2; kk++) {
#pragma unroll
            for (int m = 0; m < 2; m++)
                af[kk][m] = *(const i16x8*)&Asm[buf][(wr * 32 + m * 16 + fr) * 64 +
                                                    ((kk * 4 + h) ^ lsw) * 8];
#pragma unroll
            for (int n = 0; n < 4; n++)
                bfr[kk][n] = *(const i16x8*)&Bsm[buf][(wc * 64 + n * 16 + fr) * 64 +
                                                     ((kk * 4 + h) ^ lsw) * 8];
        }
        LGKM0;
        SCHED0;
        SBAR;

#pragma unroll
        for (int kk = 0; kk < 2; kk++)
#pragma unroll
            for (int m = 0; m < 2; m++)
#pragma unroll
                for (int n = 0; n < 4; n++)
                    acc[m][n] = __builtin_amdgcn_mfma_f32_16x16x32_bf16(
                        af[kk][m], bfr[kk][n], acc[m][n], 0, 0, 0);
    }

    const int seg = (int)(blockIdx.x >> 1);
    const float* bp = (seg == 0) ? bias0 : ((seg == 1) ? bias1 : bias2);
#pragma unroll
    for (int m = 0; m < 2; m++) {
#pragma unroll
        for (int j = 0; j < 4; j++) {
            const int grow = row0 + wr * 32 + m * 16 + h * 4 + j;
#pragma unroll
            for (int n = 0; n < 4; n++) {
                const int gcol = col0 + wc * 64 + n * 16 + fr;
                if (EPI == 4 && gcol >= Nd) continue;
                float v = acc[m][n][j] + bp[gcol & 255];
                if constexpr (EPI == 1) v = fmaxf(v, 0.f);
                if constexpr (EPI == 4)
                    ((float*)Cv)[(size_t)grow * Nd + gcol] = v;
                else
                    ((u16*)Cv)[(size_t)grow * Nd + gcol] = f2b(v);
            }
        }
    }
}

// ---------------------------------------------------------------------------
// ffn_fused (single-barrier loops + cross-phase B0 prefetch)
// ---------------------------------------------------------------------------
template <int TAIL>
__global__ __launch_bounds__(256, 2) void ffn_fused(
    const u16* __restrict__ X, const u16* __restrict__ Wt1,
    const float* __restrict__ b1, const u16* __restrict__ Wt2,
    const float* __restrict__ b2, const float* __restrict__ lng,
    const float* __restrict__ lnb, const u16* __restrict__ WtT,
    const float* __restrict__ bT0, const float* __restrict__ bT1,
    void* __restrict__ outp)
{
    __shared__ __align__(16) u16 Asm[2][64 * 32];
    __shared__ __align__(16) u16 Bsm[2][256 * 32];
    __shared__ __align__(16) u16 Msm[64 * MST];
    const int t = threadIdx.x;
    const int lane = t & 63, w = t >> 6;
    const int row0 = blockIdx.x * 64;

    const int srow = lane >> 2;
    const int sblk = ((lane & 3) ^ ((lane >> 3) & 3)) * 8;
    const int fr = lane & 15, h = lane >> 4;
    const int rsw = (fr >> 1) & 3;

    f32x4 acc[4][4] = {};

    auto stageA = [&](int buf, int kt) {
        gload_lds16(X + (size_t)(row0 + w * 16 + srow) * 256 + (kt << 5) + sblk,
                    &Asm[buf][(w * 16) * 32]);
    };
    auto stageB = [&](int buf, int kt, const u16* W) {
#pragma unroll
        for (int i = 0; i < 4; i++) {
            const int r = w * 64 + i * 16;
            gload_lds16(W + (size_t)(r + srow) * 256 + (kt << 5) + sblk,
                        &Bsm[buf][r * 32]);
        }
    };

    // ---------------- phase 1: mid = relu(X @ Wt1 + b1) ----------------
    stageA(0, 0); stageB(0, 0, Wt1);
    VMCNT0; SBAR;
#pragma unroll
    for (int kt = 0; kt < 8; ++kt) {
        const int buf = kt & 1;
        if (kt < 7) { stageA(buf ^ 1, kt + 1); stageB(buf ^ 1, kt + 1, Wt1); }
        else        { stageB(0, 0, Wt2); }    // prefetch phase-2 B0

        i16x8 af[4], bfr[4];
#pragma unroll
        for (int m = 0; m < 4; m++)
            af[m] = *(const i16x8*)&Asm[buf][(m * 16 + fr) * 32 + (h ^ rsw) * 8];
#pragma unroll
        for (int n = 0; n < 4; n++)
            bfr[n] = *(const i16x8*)&Bsm[buf][(w * 64 + n * 16 + fr) * 32 + (h ^ rsw) * 8];
        LGKM0;
        SCHED0;
#pragma unroll
        for (int m = 0; m < 4; m++)
#pragma unroll
            for (int n = 0; n < 4; n++)
                acc[m][n] = __builtin_amdgcn_mfma_f32_16x16x32_bf16(
                    af[m], bfr[n], acc[m][n], 0, 0, 0);
        if (kt < 7) { VMCNT0; SBAR; }
    }
    {   // mid -> Msm (relu + bias), reset acc
        float b1v[4];
#pragma unroll
        for (int n = 0; n < 4; n++) b1v[n] = b1[w * 64 + n * 16 + fr];
#pragma unroll
        for (int m = 0; m < 4; m++)
#pragma unroll
            for (int j = 0; j < 4; j++) {
                const int row = m * 16 + h * 4 + j;
#pragma unroll
                for (int n = 0; n < 4; n++) {
                    const int col = w * 64 + n * 16 + fr;
                    float v = fmaxf(acc[m][n][j] + b1v[n], 0.f);
                    Msm[row * MST + col] = f2b(v);
                    acc[m][n][j] = 0.f;
                }
            }
    }
    __syncthreads();   // drains vmcnt (phase-2 B0 landed) + lgkm + sync

    // ---------------- phase 2: y = LN(mid @ Wt2 + b2 + X) ----------------
#pragma unroll
    for (int kt = 0; kt < 8; ++kt) {
        const int buf = kt & 1;
        if (kt < 7) stageB(buf ^ 1, kt + 1, Wt2);
        else if (TAIL == 0) stageB(0, 0, WtT);   // prefetch tail half-0 B0

        i16x8 af[4], bfr[4];
#pragma unroll
        for (int m = 0; m < 4; m++)
            af[m] = *(const i16x8*)&Msm[(m * 16 + fr) * MST + (kt << 5) + h * 8];
#pragma unroll
        for (int n = 0; n < 4; n++)
            bfr[n] = *(const i16x8*)&Bsm[buf][(w * 64 + n * 16 + fr) * 32 + (h ^ rsw) * 8];
        LGKM0;
        SCHED0;
#pragma unroll
        for (int m = 0; m < 4; m++)
#pragma unroll
            for (int n = 0; n < 4; n++)
                acc[m][n] = __builtin_amdgcn_mfma_f32_16x16x32_bf16(
                    af[m], bfr[n], acc[m][n], 0, 0, 0);
        if (kt < 7) { VMCNT0; SBAR; }
    }
    {   // LN epilogue (resid = X re-read from global)
        float* redS = (float*)&Asm[0][0];
        float* redQ = redS + 256;
#pragma unroll
        for (int m = 0; m < 4; m++) {
#pragma unroll
            for (int j = 0; j < 4; j++) {
                const int grow = row0 + m * 16 + h * 4 + j;
                float s = 0.f, q = 0.f;
#pragma unroll
                for (int n = 0; n < 4; n++) {
                    const int gcol = w * 64 + n * 16 + fr;
                    float v = acc[m][n][j] + b2[gcol] +
                              b2f(X[(size_t)grow * 256 + gcol]);
                    acc[m][n][j] = v;
                    s += v; q += v * v;
                }
#pragma unroll
                for (int off = 1; off < 16; off <<= 1) {
                    s += __shfl_xor(s, off, 64);
                    q += __shfl_xor(q, off, 64);
                }
                if (fr == 0) {
                    redS[(m * 16 + h * 4 + j) * 4 + w] = s;
                    redQ[(m * 16 + h * 4 + j) * 4 + w] = q;
                }
            }
        }
        __syncthreads();
#pragma unroll
        for (int m = 0; m < 4; m++) {
#pragma unroll
            for (int j = 0; j < 4; j++) {
                const int r = m * 16 + h * 4 + j;
                float4 s4 = *(const float4*)&redS[r * 4];
                float4 q4 = *(const float4*)&redQ[r * 4];
                float mu = (s4.x + s4.y + s4.z + s4.w) * (1.f / DIM);
                float var = (q4.x + q4.y + q4.z + q4.w) * (1.f / DIM) - mu * mu;
                float rr = rsqrtf(var + LN_EPS);
#pragma unroll
                for (int n = 0; n < 4; n++) {
                    const int gcol = w * 64 + n * 16 + fr;
                    float y = (acc[m][n][j] - mu) * rr * lng[gcol] + lnb[gcol];
                    acc[m][n][j] = y;
                }
            }
        }
        __syncthreads();
#pragma unroll
        for (int m = 0; m < 4; m++)
#pragma unroll
            for (int j = 0; j < 4; j++) {
                const int row = m * 16 + h * 4 + j;
#pragma unroll
                for (int n = 0; n < 4; n++)
                    Msm[row * MST + (w * 64 + n * 16 + fr)] = f2b(acc[m][n][j]);
            }
    }
    __syncthreads();   // drains vmcnt (tail B0 landed) + Msm writes visible

    // ---------------- tail ----------------
    if constexpr (TAIL == 0) {
        u16* KVe = (u16*)outp;
#pragma unroll 1
        for (int half = 0; half < 2; half++) {
            const u16* Wb = WtT + (size_t)half * 65536;
            const float* bT = half ? bT1 : bT0;
#pragma unroll
            for (int m = 0; m < 4; m++)
#pragma unroll
                for (int n = 0; n < 4; n++)
                    acc[m][n] = f32x4{0.f, 0.f, 0.f, 0.f};
#pragma unroll
            for (int kt = 0; kt < 8; ++kt) {
                const int buf = kt & 1;
                if (kt < 7) stageB(buf ^ 1, kt + 1, Wb);
                else if (half == 0) stageB(0, 0, WtT + 65536);  // half-1 B0

                i16x8 af[4], bfr[4];
#pragma unroll
                for (int m = 0; m < 4; m++)
                    af[m] = *(const i16x8*)&Msm[(m * 16 + fr) * MST + (kt << 5) + h * 8];
#pragma unroll
                for (int n = 0; n < 4; n++)
                    bfr[n] = *(const i16x8*)&Bsm[buf][(w * 64 + n * 16 + fr) * 32 + (h ^ rsw) * 8];
                LGKM0;
                SCHED0;
#pragma unroll
                for (int m = 0; m < 4; m++)
#pragma unroll
                    for (int n = 0; n < 4; n++)
                        acc[m][n] = __builtin_amdgcn_mfma_f32_16x16x32_bf16(
                            af[m], bfr[n], acc[m][n], 0, 0, 0);
                if (kt < 7) { VMCNT0; SBAR; }
            }
#pragma unroll
            for (int m = 0; m < 4; m++)
#pragma unroll
                for (int j = 0; j < 4; j++) {
                    const int grow = row0 + m * 16 + h * 4 + j;
#pragma unroll
                    for (int n = 0; n < 4; n++) {
                        const int gcol = w * 64 + n * 16 + fr;
                        KVe[(size_t)grow * 512 + half * 256 + gcol] =
                            f2b(acc[m][n][j] + bT[gcol]);
                    }
                }
            if (half == 0) { VMCNT0; SBAR; }   // half-1 B0 landed; reads done
        }
    } else {
        float* out = (float*)outp;
        f32x4 acc3[3] = {};
#pragma unroll
        for (int kk = 0; kk < 8; kk++) {
            i16x8 af = *(const i16x8*)&Msm[(w * 16 + fr) * MST + kk * 32 + h * 8];
#pragma unroll
            for (int n = 0; n < 3; n++) {
                int br = n * 16 + fr; if (br > NCLS - 1) br = NCLS - 1;
                i16x8 bfr = *(const i16x8*)(WtT + (size_t)br * 256 + kk * 32 + h * 8);
                acc3[n] = __builtin_amdgcn_mfma_f32_16x16x32_bf16(af, bfr, acc3[n], 0, 0, 0);
            }
        }
#pragma unroll
        for (int n = 0; n < 3; n++) {
            const int gcol = n * 16 + fr;
            if (gcol >= NCLS) continue;
#pragma unroll
            for (int j = 0; j < 4; j++) {
                const int grow = row0 + w * 16 + h * 4 + j;
                out[(size_t)grow * NCLS + gcol] = acc3[n][j] + bT0[gcol];
            }
        }
    }
}

// ---------------------------------------------------------------------------
// edge_attn (R4 structure)
// ---------------------------------------------------------------------------
__global__ __launch_bounds__(256) void edge_attn(
    const u16* __restrict__ KVQn, const u16* __restrict__ QE,
    const float* __restrict__ efeat,
    const int* __restrict__ e2n, const float* __restrict__ cent1,
    const float* __restrict__ g, const float* __restrict__ bb,
    u16* __restrict__ XE)
{
    const int lane = threadIdx.x & 63, w = threadIdx.x >> 6;
    const int e = blockIdx.x * 4 + w;
    const int c4 = lane * 4;

    ushort4 q4 = *(const ushort4*)&QE[(size_t)e * QDIM + c4];
    const float q0 = b2f(q4.x), q1 = b2f(q4.y), q2 = b2f(q4.z), q3 = b2f(q4.w);

    int4 rv[8];
#pragma unroll
    for (int i = 0; i < 8; i++)
        rv[i] = *(const int4*)&e2n[(size_t)e * DE + i * 4];
    int rows[DE];
#pragma unroll
    for (int i = 0; i < 8; i++) {
        rows[i * 4 + 0] = rv[i].x; rows[i * 4 + 1] = rv[i].y;
        rows[i * 4 + 2] = rv[i].z; rows[i * 4 + 3] = rv[i].w;
    }

    float p[DE];
#pragma unroll
    for (int g0 = 0; g0 < DE; g0 += 16) {
        ushort4 k4[16];
#pragma unroll
        for (int j = 0; j < 16; j++)
            k4[j] = *(const ushort4*)&KVQn[(size_t)rows[g0 + j] * 768 + c4];
#pragma unroll
        for (int j = 0; j < 16; j++)
            p[g0 + j] = q0 * b2f(k4[j].x) + q1 * b2f(k4[j].y)
                      + q2 * b2f(k4[j].z) + q3 * b2f(k4[j].w);
    }
#pragma unroll
    for (int off = 32; off; off >>= 1)
#pragma unroll
        for (int d = 0; d < DE; d++)
            p[d] += __shfl_xor(p[d], off, 64);

    float4 cv[8];
#pragma unroll
    for (int i = 0; i < 8; i++)
        cv[i] = *(const float4*)&cent1[(size_t)e * DE + i * 4];
    float cent[DE];
#pragma unroll
    for (int i = 0; i < 8; i++) {
        cent[i * 4 + 0] = cv[i].x; cent[i * 4 + 1] = cv[i].y;
        cent[i * 4 + 2] = cv[i].z; cent[i * 4 + 3] = cv[i].w;
    }
#pragma unroll
    for (int d = 0; d < DE; d++)
        p[d] = (p[d] > 0.f ? p[d] : 0.01f * p[d]) * ATT_SCALE + cent[d];

    float mx = p[0];
#pragma unroll
    for (int d = 1; d < DE; d++) mx = fmaxf(mx, p[d]);
    float s = 0.f;
#pragma unroll
    for (int d = 0; d < DE; d++) { p[d] = __expf(p[d] - mx); s += p[d]; }
    const float inv = 1.f / s;
#pragma unroll
    for (int d = 0; d < DE; d++) p[d] *= inv;

    float a0 = 0.f, a1 = 0.f, a2 = 0.f, a3 = 0.f;
#pragma unroll
    for (int g0 = 0; g0 < DE; g0 += 16) {
        ushort4 v4[16];
#pragma unroll
        for (int j = 0; j < 16; j++)
            v4[j] = *(const ushort4*)&KVQn[(size_t)rows[g0 + j] * 768 + 256 + c4];
#pragma unroll
        for (int j = 0; j < 16; j++) {
            const float sd = p[g0 + j];
            a0 = fmaf(sd, b2f(v4[j].x), a0); a1 = fmaf(sd, b2f(v4[j].y), a1);
            a2 = fmaf(sd, b2f(v4[j].z), a2); a3 = fmaf(sd, b2f(v4[j].w), a3);
        }
    }
    float4 ef = *(const float4*)&efeat[(size_t)e * DIM + c4];
    float x0 = a0 + ef.x, x1 = a1 + ef.y, x2 = a2 + ef.z, x3 = a3 + ef.w;

    float mu = x0 + x1 + x2 + x3;
#pragma unroll
    for (int off = 32; off; off >>= 1) mu += __shfl_xor(mu, off, 64);
    mu *= (1.f / DIM);
    float d0 = x0 - mu, d1 = x1 - mu, d2 = x2 - mu, d3 = x3 - mu;
    float var = d0 * d0 + d1 * d1 + d2 * d2 + d3 * d3;
#pragma unroll
    for (int off = 32; off; off >>= 1) var += __shfl_xor(var, off, 64);
    var *= (1.f / DIM);
    float r = rsqrtf(var + LN_EPS);
    float4 gv = *(const float4*)&g[c4];
    float4 bv = *(const float4*)&bb[c4];
    ushort4 o;
    o.x = f2b(d0 * r * gv.x + bv.x); o.y = f2b(d1 * r * gv.y + bv.y);
    o.z = f2b(d2 * r * gv.z + bv.z); o.w = f2b(d3 * r * gv.w + bv.w);
    *(ushort4*)&XE[(size_t)e * DIM + c4] = o;
}

// ---------------------------------------------------------------------------
// node_attn (R4 structure)
// ---------------------------------------------------------------------------
__global__ __launch_bounds__(256) void node_attn(
    const u16* __restrict__ KVe, const u16* __restrict__ KVQn,
    const u16* __restrict__ FV,
    const int* __restrict__ n2e, const float* __restrict__ cent2,
    const float* __restrict__ g, const float* __restrict__ bb,
    u16* __restrict__ XV)
{
    const int lane = threadIdx.x & 63, w = threadIdx.x >> 6;
    const int na = blockIdx.x * 8 + w * 2, nb = na + 1;
    const int c4 = lane * 4;

    ushort4 qa4 = *(const ushort4*)&KVQn[(size_t)na * 768 + 512 + c4];
    ushort4 qb4 = *(const ushort4*)&KVQn[(size_t)nb * 768 + 512 + c4];
    const float qa0 = b2f(qa4.x), qa1 = b2f(qa4.y), qa2 = b2f(qa4.z), qa3 = b2f(qa4.w);
    const float qb0 = b2f(qb4.x), qb1 = b2f(qb4.y), qb2 = b2f(qb4.z), qb3 = b2f(qb4.w);

    int4 r0 = *(const int4*)&n2e[(size_t)na * DV];
    int4 r1 = *(const int4*)&n2e[(size_t)na * DV + 4];
    int4 r2 = *(const int4*)&n2e[(size_t)nb * DV];
    int4 r3 = *(const int4*)&n2e[(size_t)nb * DV + 4];
    int rA[8] = {r0.x, r0.y, r0.z, r0.w, r1.x, r1.y, r1.z, r1.w};
    int rB[8] = {r2.x, r2.y, r2.z, r2.w, r3.x, r3.y, r3.z, r3.w};

    ushort4 kA[8], vA[8], kB[8], vB[8];
#pragma unroll
    for (int d = 0; d < DV; d++) {
        const u16* b = KVe + (size_t)rA[d] * 512 + c4;
        kA[d] = *(const ushort4*)b; vA[d] = *(const ushort4*)(b + 256);
    }
#pragma unroll
    for (int d = 0; d < DV; d++) {
        const u16* b = KVe + (size_t)rB[d] * 512 + c4;
        kB[d] = *(const ushort4*)b; vB[d] = *(const ushort4*)(b + 256);
    }

    float pA[8], pB[8];
#pragma unroll
    for (int d = 0; d < DV; d++) {
        pA[d] = qa0 * b2f(kA[d].x) + qa1 * b2f(kA[d].y)
              + qa2 * b2f(kA[d].z) + qa3 * b2f(kA[d].w);
        pB[d] = qb0 * b2f(kB[d].x) + qb1 * b2f(kB[d].y)
              + qb2 * b2f(kB[d].z) + qb3 * b2f(kB[d].w);
    }
#pragma unroll
    for (int off = 32; off; off >>= 1) {
#pragma unroll
        for (int d = 0; d < DV; d++) {
            pA[d] += __shfl_xor(pA[d], off, 64);
            pB[d] += __shfl_xor(pB[d], off, 64);
        }
    }
    float4 cA0 = *(const float4*)&cent2[(size_t)na * DV];
    float4 cA1 = *(const float4*)&cent2[(size_t)na * DV + 4];
    float4 cB0 = *(const float4*)&cent2[(size_t)nb * DV];
    float4 cB1 = *(const float4*)&cent2[(size_t)nb * DV + 4];
    float cA[8] = {cA0.x, cA0.y, cA0.z, cA0.w, cA1.x, cA1.y, cA1.z, cA1.w};
    float cB[8] = {cB0.x, cB0.y, cB0.z, cB0.w, cB1.x, cB1.y, cB1.z, cB1.w};
#pragma unroll
    for (int d = 0; d < DV; d++) {
        pA[d] = (pA[d] > 0.f ? pA[d] : 0.01f * pA[d]) * ATT_SCALE + cA[d];
        pB[d] = (pB[d] > 0.f ? pB[d] : 0.01f * pB[d]) * ATT_SCALE + cB[d];
    }
    float mA = pA[0], mB = pB[0];
#pragma unroll
    for (int d = 1; d < DV; d++) { mA = fmaxf(mA, pA[d]); mB = fmaxf(mB, pB[d]); }
    float sA = 0.f, sB = 0.f;
#pragma unroll
    for (int d = 0; d < DV; d++) {
        pA[d] = __expf(pA[d] - mA); sA += pA[d];
        pB[d] = __expf(pB[d] - mB); sB += pB[d];
    }
    const float iA = 1.f / sA, iB = 1.f / sB;

    float a0 = 0.f, a1 = 0.f, a2 = 0.f, a3 = 0.f;
    float b0 = 0.f, b1 = 0.f, b2 = 0.f, b3 = 0.f;
#pragma unroll
    for (int d = 0; d < DV; d++) {
        const float sa = pA[d] * iA, sb = pB[d] * iB;
        a0 = fmaf(sa, b2f(vA[d].x), a0); a1 = fmaf(sa, b2f(vA[d].y), a1);
        a2 = fmaf(sa, b2f(vA[d].z), a2); a3 = fmaf(sa, b2f(vA[d].w), a3);
        b0 = fmaf(sb, b2f(vB[d].x), b0); b1 = fmaf(sb, b2f(vB[d].y), b1);
        b2 = fmaf(sb, b2f(vB[d].z), b2); b3 = fmaf(sb, b2f(vB[d].w), b3);
    }
    ushort4 fa = *(const ushort4*)&FV[(size_t)na * DIM + c4];
    ushort4 fb = *(const ushort4*)&FV[(size_t)nb * DIM + c4];
    float xa0 = a0 + b2f(fa.x), xa1 = a1 + b2f(fa.y);
    float xa2 = a2 + b2f(fa.z), xa3 = a3 + b2f(fa.w);
    float xb0 = b0 + b2f(fb.x), xb1 = b1 + b2f(fb.y);
    float xb2 = b2 + b2f(fb.z), xb3 = b3 + b2f(fb.w);

    float muA = xa0 + xa1 + xa2 + xa3, muB = xb0 + xb1 + xb2 + xb3;
#pragma unroll
    for (int off = 32; off; off >>= 1) {
        muA += __shfl_xor(muA, off, 64);
        muB += __shfl_xor(muB, off, 64);
    }
    muA *= (1.f / DIM); muB *= (1.f / DIM);
    float da0 = xa0 - muA, da1 = xa1 - muA, da2 = xa2 - muA, da3 = xa3 - muA;
    float db0 = xb0 - muB, db1 = xb1 - muB, db2 = xb2 - muB, db3 = xb3 - muB;
    float vA_ = da0 * da0 + da1 * da1 + da2 * da2 + da3 * da3;
    float vB_ = db0 * db0 + db1 * db1 + db2 * db2 + db3 * db3;
#pragma unroll
    for (int off = 32; off; off >>= 1) {
        vA_ += __shfl_xor(vA_, off, 64);
        vB_ += __shfl_xor(vB_, off, 64);
    }
    const float rA_ = rsqrtf(vA_ * (1.f / DIM) + LN_EPS);
    const float rB_ = rsqrtf(vB_ * (1.f / DIM) + LN_EPS);
    float4 gv = *(const float4*)&g[c4];
    float4 bv = *(const float4*)&bb[c4];
    ushort4 oa, ob;
    oa.x = f2b(da0 * rA_ * gv.x + bv.x); oa.y = f2b(da1 * rA_ * gv.y + bv.y);
    oa.z = f2b(da2 * rA_ * gv.z + bv.z); oa.w = f2b(da3 * rA_ * gv.w + bv.w);
    ob.x = f2b(db0 * rB_ * gv.x + bv.x); ob.y = f2b(db1 * rB_ * gv.y + bv.y);
    ob.z = f2b(db2 * rB_ * gv.z + bv.z); ob.w = f2b(db3 * rB_ * gv.w + bv.w);
    *(ushort4*)&XV[(size_t)na * DIM + c4] = oa;
    *(ushort4*)&XV[(size_t)nb * DIM + c4] = ob;
}

extern "C" void kernel_launch(void* const* d_in, const int* in_sizes, int n_in,
                              void* d_out, int out_size, void* d_ws, size_t ws_size,
                              hipStream_t stream)
{
    const float* vfeat  = (const float*)d_in[0];
    const float* efeat  = (const float*)d_in[1];
    const float* eign   = (const float*)d_in[2];
    const float* gcn    = (const float*)d_in[3];
    const float* cent1  = (const float*)d_in[4];
    const float* cent2  = (const float*)d_in[5];
    const int*   cidx   = (const int*)d_in[6];
    const int*   uidx   = (const int*)d_in[7];
    const int*   e2n    = (const int*)d_in[8];
    const int*   n2e    = (const int*)d_in[9];
    const float* W_vtx  = (const float*)d_in[10]; const float* b_vtx = (const float*)d_in[11];
    const float* W_pe   = (const float*)d_in[12]; const float* b_pe  = (const float*)d_in[13];
    const float* cs_emb = (const float*)d_in[14]; const float* un_emb= (const float*)d_in[15];
    const float* W_kv   = (const float*)d_in[16]; const float* b_kv  = (const float*)d_in[17];
    const float* W_vv   = (const float*)d_in[18]; const float* b_vv  = (const float*)d_in[19];
    const float* W_qe   = (const float*)d_in[20]; const float* b_qe  = (const float*)d_in[21];
    const float* W_ke   = (const float*)d_in[22]; const float* b_ke  = (const float*)d_in[23];
    const float* W_ve   = (const float*)d_in[24]; const float* b_ve  = (const float*)d_in[25];
    const float* W_qv   = (const float*)d_in[26]; const float* b_qv  = (const float*)d_in[27];
    const float* W_l1   = (const float*)d_in[28]; const float* b_l1  = (const float*)d_in[29];
    const float* W_l2   = (const float*)d_in[30]; const float* b_l2  = (const float*)d_in[31];
    const float* W_l3   = (const float*)d_in[32]; const float* b_l3  = (const float*)d_in[33];
    const float* W_l4   = (const float*)d_in[34]; const float* b_l4  = (const float*)d_in[35];
    const float* ln1_g  = (const float*)d_in[36]; const float* ln1_b = (const float*)d_in[37];
    const float* ln2_g  = (const float*)d_in[38]; const float* ln2_b = (const float*)d_in[39];
    const float* W_cls  = (const float*)d_in[40]; const float* b_cls = (const float*)d_in[41];
    float* out = (float*)d_out;

    const size_t NE = (size_t)N_NODES * DIM;   // 10,240,000
    const size_t EE = (size_t)N_EDGES * DIM;   //  2,048,000
    u16* ws = (u16*)d_ws;
    u16* FVb  = ws;                 // assembled feat_v (resid for node_attn)
    u16* KVQn = FVb + NE;           // [N][768] k_n|v_n|q_v
    u16* B2   = KVQn + 3 * NE;      // x_v
    u16* QEb  = B2 + NE;
    u16* XE   = QEb + EE;           // x_e
    u16* KVe  = XE + EE;            // [E][512] k_e|v_e
    u16* Wp   = KVe + 2 * EE;       // 13 * 65536
    u16* Wt_vtx = Wp +  0 * 65536;
    u16* Wt_pe  = Wp +  1 * 65536;
    u16* Wt_kvq = Wp +  2 * 65536;  // slots 2,3,4 = [768][256]
    u16* Wt_qe  = Wp +  5 * 65536;
    u16* Wt_kve = Wp +  6 * 65536;  // slots 6,7 = [512][256]
    u16* Wt_l1  = Wp +  8 * 65536;
    u16* Wt_l2  = Wp +  9 * 65536;
    u16* Wt_l3  = Wp + 10 * 65536;
    u16* Wt_l4  = Wp + 11 * 65536;
    u16* Wt_cls = Wp + 12 * 65536;

    const dim3 blk(256);
    const dim3 gW(8, 8, 13);
    const dim3 gQE(2, N_EDGES / 64);     // (2,125)

    prep_weights<<<gW, blk, 0, stream>>>(
        W_vtx, W_pe, W_kv, W_vv, W_qv, W_qe, W_ke, W_ve,
        W_l1, W_l2, W_l3, W_l4, W_cls, Wp);

    // fused assembly + KVQ
    asm_kvq<<<N_NODES / 64, blk, 0, stream>>>(
        vfeat, eign, Wt_vtx, Wt_pe, b_vtx, b_pe,
        gcn, cs_emb, un_emb, cidx, uidx,
        Wt_kvq, b_kv, b_vv, b_qv, FVb, KVQn);

    // stage 1
    gemmN<0, 1, 4><<<gQE, blk, 0, stream>>>(efeat, Wt_qe,
        b_qe, b_qe, b_qe, QEb, 256);                                    // q_e
    edge_attn<<<N_EDGES / 4, blk, 0, stream>>>(KVQn, QEb, efeat, e2n, cent1,
        ln1_g, ln1_b, XE);
    ffn_fused<0><<<N_EDGES / 64, blk, 0, stream>>>(XE, Wt_l1, b_l1,
        Wt_l2, b_l2, ln1_g, ln1_b, Wt_kve, b_ke, b_ve, KVe);            // FFN+LN+{k_e|v_e}

    // stage 2
    node_attn<<<N_NODES / 8, blk, 0, stream>>>(KVe, KVQn, FVb, n2e, cent2,
        ln2_g, ln2_b, B2);                                              // x_v
    ffn_fused<1><<<N_NODES / 64, blk, 0, stream>>>(B2, Wt_l3, b_l3,
        Wt_l4, b_l4, ln2_g, ln2_b, Wt_cls, b_cls, nullptr, out);        // FFN+LN+cls
}

// Round 15
// 229.089 us; speedup vs baseline: 1.4712x; 1.0283x over previous
//
// R14: fp8(e4m3) K/V for attention gathers. asm_kvq writes K_n/V_n fp8 +
// Q_v bf16 (separate buffers); ffn_fused<0> tail writes K_e/V_e fp8;
// attention kernels gather u32 (4B/lane) + HW cvt_pk_f32_fp8 (guarded).
// All GEMMs/weights/Q/residuals stay bf16. Base = R13 (235.6 us).
#include <hip/hip_runtime.h>
#include <hip/hip_bf16.h>
#include <cstddef>

#define N_NODES 40000
#define N_EDGES 8000
#define DE 32
#define DV 8
#define DIM 256
#define QDIM 256
#define EIGD 64
#define NCLS 40
#define LN_EPS 1e-5f
#define ATT_SCALE 0.0625f   // 1/sqrt(256)

typedef unsigned short u16;
typedef unsigned int u32;
typedef unsigned char u8;
using i16x8 = __attribute__((ext_vector_type(8))) short;
using f32x4 = __attribute__((ext_vector_type(4))) float;

__device__ inline u16 f2b(float f) {   // RNE f32 -> bf16 bits
    union { float f; u32 u; } c; c.f = f;
    u32 u = c.u + 0x7FFF + ((c.u >> 16) & 1);
    return (u16)(u >> 16);
}
__device__ inline float b2f(u16 b) {
    union { u32 u; float f; } c; c.u = (u32)b << 16;
    return c.f;
}

// ---- fp8 e4m3 pack/unpack (HW builtins when available; self-consistent) ----
#if __has_builtin(__builtin_amdgcn_cvt_pk_f32_fp8)
__device__ inline void f8x4_to_f32(u32 w, float o[4]) {
    using f32x2 = __attribute__((ext_vector_type(2))) float;
    f32x2 lo = __builtin_amdgcn_cvt_pk_f32_fp8((int)w, false);
    f32x2 hi = __builtin_amdgcn_cvt_pk_f32_fp8((int)w, true);
    o[0] = lo[0]; o[1] = lo[1]; o[2] = hi[0]; o[3] = hi[1];
}
#else
__device__ inline float f8_one(u32 b) {
    u32 s = (b & 0x80) << 24;
    u32 em = b & 0x7f;
    union { u32 u; float f; } n, sg;
    n.u = s | ((em + 960) << 20);        // normal path (em >= 8)
    sg.u = s | 0x3f800000;               // +/-1.0
    float subv = sg.f * (float)em * 0.001953125f;  // em * 2^-9
    return (em >= 8) ? n.f : subv;
}
__device__ inline void f8x4_to_f32(u32 w, float o[4]) {
    o[0] = f8_one(w & 0xff); o[1] = f8_one((w >> 8) & 0xff);
    o[2] = f8_one((w >> 16) & 0xff); o[3] = f8_one(w >> 24);
}
#endif

#if __has_builtin(__builtin_amdgcn_cvt_pk_fp8_f32)
__device__ inline u8 f32_to_f8(float v) {
    return (u8)(__builtin_amdgcn_cvt_pk_fp8_f32(v, v, 0, false) & 0xff);
}
#else
__device__ inline u8 f32_to_f8(float v) {
    union { float f; u32 u; } c; c.f = v;
    u32 s = (c.u >> 24) & 0x80;
    float a = __builtin_fabsf(v);
    if (!(a > 1.953125e-3f)) return (u8)s;          // ~0
    if (a > 448.f) a = 448.f;
    c.f = a;
    u32 absu = c.u;
    if (absu < 0x3c800000) {                         // subnormal (< 2^-6)
        u32 m = (u32)(a * 512.f + 0.5f);
        return (u8)(s | (m > 7 ? 8u : m));
    }
    u32 rounded = absu + 0x0007ffff + ((absu >> 20) & 1);  // RNE at bit 20
    u32 e = (rounded >> 23) - 120;
    u32 m = (rounded >> 20) & 7;
    if (e > 15) { e = 15; m = 6; }
    return (u8)(s | (e << 3) | m);
}
#endif

__device__ inline void gload_lds16(const u16* g, u16* l) {
    __builtin_amdgcn_global_load_lds(
        (const __attribute__((address_space(1))) void*)g,
        (__attribute__((address_space(3))) void*)l, 16, 0, 0);
}

#define VMCNT12 asm volatile("s_waitcnt vmcnt(12)" ::: "memory")
#define VMCNT6  asm volatile("s_waitcnt vmcnt(6)" ::: "memory")
#define VMCNT0  asm volatile("s_waitcnt vmcnt(0)" ::: "memory")
#define LGKM0   asm volatile("s_waitcnt lgkmcnt(0)" ::: "memory")
#define SCHED0  __builtin_amdgcn_sched_barrier(0)
#define SBAR    __builtin_amdgcn_s_barrier()

// ---------------------------------------------------------------------------
// Batched transpose-cast. Slots: 0 vtx, 1 pe, 2 kv, 3 vv, 4 qv, 5 qe,
// 6 ke, 7 ve, 8 l1, 9 l2, 10 l3, 11 l4, 12 cls.
// ---------------------------------------------------------------------------
__global__ __launch_bounds__(256) void prep_weights(
    const float* w0, const float* w1, const float* w2, const float* w3,
    const float* w4, const float* w5, const float* w6, const float* w7,
    const float* w8, const float* w9, const float* w10, const float* w11,
    const float* w12, u16* __restrict__ pool)
{
    const float* srcs[13] = {w0,w1,w2,w3,w4,w5,w6,w7,w8,w9,w10,w11,w12};
    const int Ks[13]  = {256,64,256,256,256,256,256,256,256,256,256,256,256};
    const int Nds[13] = {256,256,256,256,256,256,256,256,256,256,256,256,40};
    const int id = blockIdx.z;
    const float* W = srcs[id];
    u16* Wt = pool + (size_t)id * 65536;
    const int K = Ks[id], Nd = Nds[id];
    const int k0 = blockIdx.x * 32, n0 = blockIdx.y * 32;
    if (k0 >= K || n0 >= Nd) return;

    __shared__ float tile[32][33];
    const int x = threadIdx.x & 31, y4 = (threadIdx.x >> 5) * 4;
#pragma unroll
    for (int j = 0; j < 4; j++) {
        int k = k0 + y4 + j;
        tile[y4 + j][x] = (k < K && (n0 + x) < Nd) ? W[(size_t)k * Nd + n0 + x] : 0.f;
    }
    __syncthreads();
#pragma unroll
    for (int j = 0; j < 4; j++) {
        int n = n0 + y4 + j;
        if (n < Nd && (k0 + x) < K)
            Wt[(size_t)n * K + k0 + x] = f2b(tile[x][y4 + j]);
    }
}

// ---------------------------------------------------------------------------
// asm_kvq: phase 1 (R8 2-barrier structure), add-pass, phase 2 single-barrier
// steps + cross-chunk B0 prefetch. Chunks 0/1 (K/V) -> fp8 KV8n; chunk 2 (Q)
// -> bf16 QVb.
// ---------------------------------------------------------------------------
#define MST 264
__global__ __launch_bounds__(256, 2) void asm_kvq(
    const float* __restrict__ vfeat, const float* __restrict__ eign,
    const u16* __restrict__ Wt_vtx, const u16* __restrict__ Wt_pe,
    const float* __restrict__ b_vtx, const float* __restrict__ b_pe,
    const float* __restrict__ gcn, const float* __restrict__ emb1,
    const float* __restrict__ emb2, const int* __restrict__ idx1,
    const int* __restrict__ idx2,
    const u16* __restrict__ Wt_kvq, const float* __restrict__ b_kv,
    const float* __restrict__ b_vv, const float* __restrict__ b_qv,
    u16* __restrict__ FVb, u8* __restrict__ KV8n, u16* __restrict__ QVb)
{
    __shared__ __align__(16) u16 Asm[2][64 * 32];   //  8 KB
    __shared__ __align__(16) u16 Bsm[2][256 * 32];  // 32 KB
    __shared__ __align__(16) u16 Msm[64 * MST];     // 33.75 KB
    const int t = threadIdx.x;
    const int lane = t & 63, w = t >> 6;
    const int row0 = blockIdx.x * 64;

    const int srow = lane >> 2;                          // 0..15
    const int sblk = ((lane & 3) ^ ((lane >> 3) & 3)) * 8;  // swizzled src blk
    const int fr = lane & 15, h = lane >> 4;
    const int rsw = (fr >> 1) & 3;

    f32x4 acc[4][4] = {};
    float4 fA[2][2];                                      // [parity][half]

    auto p1_issueB = [&](int kt) {
        const int buf = kt & 1;
        const int k0 = kt << 5;
        const bool tail = (k0 >= 256);
#pragma unroll
        for (int i = 0; i < 4; i++) {
            const int r = w * 64 + i * 16;
            const u16* gp = tail ? Wt_pe + (size_t)(r + srow) * 64 + (k0 - 256) + sblk
                                 : Wt_vtx + (size_t)(r + srow) * 256 + k0 + sblk;
            gload_lds16(gp, &Bsm[buf][r * 32]);
        }
    };
    auto p1_loadA = [&](int kt) {
        const int k0 = kt << 5;
        const bool tail = (k0 >= 256);
        const float* ap = tail
            ? eign + (size_t)(row0 + w * 16 + srow) * 64 + (k0 - 256) + sblk
            : vfeat + (size_t)(row0 + w * 16 + srow) * 256 + k0 + sblk;
        fA[kt & 1][0] = *(const float4*)ap;
        fA[kt & 1][1] = *(const float4*)(ap + 4);
    };
    auto p1_write = [&](int kt) {                         // cvt + ds_write
        const int buf = kt & 1;
        float4 f0 = fA[buf][0], f1 = fA[buf][1];
        i16x8 v;
        v[0] = (short)f2b(f0.x); v[1] = (short)f2b(f0.y);
        v[2] = (short)f2b(f0.z); v[3] = (short)f2b(f0.w);
        v[4] = (short)f2b(f1.x); v[5] = (short)f2b(f1.y);
        v[6] = (short)f2b(f1.z); v[7] = (short)f2b(f1.w);
        *(i16x8*)&Asm[buf][(w * 16 + srow) * 32 + (lane & 3) * 8] = v;
    };

    // ---- phase 1 main loop (NT=10; R8-proven 2-barrier structure) ----
    p1_loadA(0); p1_issueB(0); p1_loadA(1); p1_write(0);
#pragma unroll
    for (int kt = 0; kt < 10; ++kt) {
        const int buf = kt & 1;
        if (kt + 1 < 10) p1_issueB(kt + 1);
        if (kt + 2 < 10) p1_loadA(kt + 2);
        if (kt + 1 < 10) p1_write(kt + 1);
        else { VMCNT0; }
        LGKM0;
        SBAR;

        i16x8 af[4], bfr[4];
#pragma unroll
        for (int m = 0; m < 4; m++)
            af[m] = *(const i16x8*)&Asm[buf][(m * 16 + fr) * 32 + (h ^ rsw) * 8];
#pragma unroll
        for (int n = 0; n < 4; n++)
            bfr[n] = *(const i16x8*)&Bsm[buf][(w * 64 + n * 16 + fr) * 32 + (h ^ rsw) * 8];
        LGKM0;
        SCHED0;
        SBAR;

#pragma unroll
        for (int m = 0; m < 4; m++)
#pragma unroll
            for (int n = 0; n < 4; n++)
                acc[m][n] = __builtin_amdgcn_mfma_f32_16x16x32_bf16(
                    af[m], bfr[n], acc[m][n], 0, 0, 0);
    }

    // ---- phase 1 epilogue: acc + biases -> Msm ----
#pragma unroll
    for (int m = 0; m < 4; m++)
#pragma unroll
        for (int j = 0; j < 4; j++) {
            const int row = m * 16 + h * 4 + j;
#pragma unroll
            for (int n = 0; n < 4; n++) {
                const int col = w * 64 + n * 16 + fr;
                float v = acc[m][n][j] + b_vtx[col] + b_pe[col];
                Msm[row * MST + col] = f2b(v);
            }
        }
    __syncthreads();

    // ---- coalesced add pass: Msm += gcn + emb1[idx1] + emb2[idx2] ----
    const float4* gcn4 = (const float4*)gcn;
    const float4* e1_4 = (const float4*)emb1;
    const float4* e2_4 = (const float4*)emb2;
    ushort4* FVb4 = (ushort4*)FVb;
#pragma unroll 4
    for (int it = 0; it < 16; ++it) {
        const int T = t + it * 256;
        const int row = T >> 6, cg = T & 63;
        const int grow = row0 + row;
        const int i1 = idx1[grow], i2 = idx2[grow];
        ushort4 mv = *(const ushort4*)&Msm[row * MST + cg * 4];
        float4 gv = gcn4[(size_t)grow * 64 + cg];
        float4 e1 = e1_4[(size_t)i1 * 64 + cg];
        float4 e2 = e2_4[(size_t)i2 * 64 + cg];
        ushort4 o;
        o.x = f2b(b2f(mv.x) + gv.x + e1.x + e2.x);
        o.y = f2b(b2f(mv.y) + gv.y + e1.y + e2.y);
        o.z = f2b(b2f(mv.z) + gv.z + e1.z + e2.z);
        o.w = f2b(b2f(mv.w) + gv.w + e1.w + e2.w);
        FVb4[(size_t)grow * 64 + cg] = o;
        *(ushort4*)&Msm[row * MST + cg * 4] = o;
    }
    __syncthreads();

    // ---- phase 2: KVQ = Msm @ Wt_kvq (3 chunks), single-barrier steps ----
    auto p2_issueB = [&](int buf, int kt, const u16* Wb) {
#pragma unroll
        for (int i = 0; i < 4; i++) {
            const int r = w * 64 + i * 16;
            gload_lds16(Wb + (size_t)(r + srow) * 256 + (kt << 5) + sblk,
                        &Bsm[buf][r * 32]);
        }
    };
    p2_issueB(0, 0, Wt_kvq);
    VMCNT0; SBAR;
#pragma unroll 1
    for (int c = 0; c < 3; ++c) {
        const u16* Wb = Wt_kvq + (size_t)c * 65536;
        const float* bc = (c == 0) ? b_kv : ((c == 1) ? b_vv : b_qv);
#pragma unroll
        for (int m = 0; m < 4; m++)
#pragma unroll
            for (int n = 0; n < 4; n++)
                acc[m][n] = f32x4{0.f, 0.f, 0.f, 0.f};
#pragma unroll
        for (int kt = 0; kt < 8; ++kt) {
            const int buf = kt & 1;
            if (kt < 7) p2_issueB(buf ^ 1, kt + 1, Wb);
            else if (c < 2) p2_issueB(0, 0, Wb + 65536);   // next chunk's B0

            i16x8 af[4], bfr[4];
#pragma unroll
            for (int m = 0; m < 4; m++)
                af[m] = *(const i16x8*)&Msm[(m * 16 + fr) * MST + (kt << 5) + h * 8];
#pragma unroll
            for (int n = 0; n < 4; n++)
                bfr[n] = *(const i16x8*)&Bsm[buf][(w * 64 + n * 16 + fr) * 32 + (h ^ rsw) * 8];
            LGKM0;
            SCHED0;
#pragma unroll
            for (int m = 0; m < 4; m++)
#pragma unroll
                for (int n = 0; n < 4; n++)
                    acc[m][n] = __builtin_amdgcn_mfma_f32_16x16x32_bf16(
                        af[m], bfr[n], acc[m][n], 0, 0, 0);
            if (kt < 7) { VMCNT0; SBAR; }
        }
        // store chunk c: c<2 -> fp8 KV8n; c==2 -> bf16 QVb
#pragma unroll
        for (int m = 0; m < 4; m++)
#pragma unroll
            for (int j = 0; j < 4; j++) {
                const int grow = row0 + m * 16 + h * 4 + j;
#pragma unroll
                for (int n = 0; n < 4; n++) {
                    const int gcol = w * 64 + n * 16 + fr;
                    float v = acc[m][n][j] + bc[gcol];
                    if (c < 2)
                        KV8n[(size_t)grow * 512 + c * 256 + gcol] = f32_to_f8(v);
                    else
                        QVb[(size_t)grow * 256 + gcol] = f2b(v);
                }
            }
        if (c < 2) { VMCNT0; SBAR; }    // next chunk's B0 landed; reads done
    }
}

// ---------------------------------------------------------------------------
// gemmN: BM=64, BN=128, BK=64 (used for q_e only; unchanged)
// ---------------------------------------------------------------------------
template <int EPI, int AMODE, int NT>
__global__ __launch_bounds__(256, 2) void gemmN(
    const void* __restrict__ Av, const u16* __restrict__ Wt,
    const float* __restrict__ bias0, const float* __restrict__ bias1,
    const float* __restrict__ bias2,
    void* __restrict__ Cv, int Nd)
{
    __shared__ u16 Asm[3][64 * 64];
    __shared__ u16 Bsm[3][128 * 64];
    const int t = threadIdx.x;
    const int lane = t & 63, w = t >> 6;
    const int wr = w >> 1, wc = w & 1;
    const int row0 = blockIdx.y * 64, col0 = blockIdx.x * 128;

    f32x4 acc[2][4] = {};

    const int srow = lane >> 3;
    const int sblk = ((lane & 7) ^ srow) * 8;
    const int fr = lane & 15, h = lane >> 4;
    const int lsw = fr & 7;

    float4 farA[2][2][2];

    auto stage_load = [&](int kt) {
        const int buf = kt % 3;
        const int k0 = kt << 6;
        if constexpr (AMODE == 0) {
#pragma unroll
            for (int i = 0; i < 2; i++) {
                const int r = w * 16 + i * 8;
                gload_lds16((const u16*)Av + (size_t)(row0 + r + srow) * 256 + k0 + sblk,
                            &Asm[buf][r * 64]);
            }
        } else {
#pragma unroll
            for (int i = 0; i < 2; i++) {
                const int r = w * 16 + i * 8;
                const float* ap = (const float*)Av + (size_t)(row0 + r + srow) * 256 + k0 + sblk;
                farA[kt & 1][i][0] = *(const float4*)ap;
                farA[kt & 1][i][1] = *(const float4*)(ap + 4);
            }
        }
#pragma unroll
        for (int i = 0; i < 4; i++) {
            const int r = w * 32 + i * 8;
            int ng = col0 + r + srow; if (ng > Nd - 1) ng = Nd - 1;
            gload_lds16(Wt + (size_t)ng * 256 + k0 + sblk, &Bsm[buf][r * 64]);
        }
    };
    auto stage_write = [&](int kt) {
        const int buf = kt % 3;
#pragma unroll
        for (int i = 0; i < 2; i++) {
            const int r = w * 16 + i * 8;
            float4 f0 = farA[kt & 1][i][0], f1 = farA[kt & 1][i][1];
            i16x8 v;
            v[0] = (short)f2b(f0.x); v[1] = (short)f2b(f0.y);
            v[2] = (short)f2b(f0.z); v[3] = (short)f2b(f0.w);
            v[4] = (short)f2b(f1.x); v[5] = (short)f2b(f1.y);
            v[6] = (short)f2b(f1.z); v[7] = (short)f2b(f1.w);
            *(i16x8*)&Asm[buf][(r + srow) * 64 + (lane & 7) * 8] = v;
        }
    };

    stage_load(0);
    if (NT > 1) stage_load(1);
    if constexpr (AMODE != 0) stage_write(0);

#pragma unroll
    for (int kt = 0; kt < NT; ++kt) {
        const int buf = kt % 3;
        if (kt + 2 < NT) stage_load(kt + 2);
        if constexpr (AMODE != 0) {
            if (kt + 1 < NT) stage_write(kt + 1);
            else { VMCNT0; }
        } else {
            if (kt + 2 < NT) { VMCNT12; }
            else if (kt + 1 < NT) { VMCNT6; }
            else { VMCNT0; }
        }
        LGKM0;
        SBAR;

        i16x8 af[2][2], bfr[2][4];
#pragma unroll
        for (int kk = 0; kk < 2; kk++) {
#pragma unroll
            for (int m = 0; m < 2; m++)
                af[kk][m] = *(const i16x8*)&Asm[buf][(wr * 32 + m * 16 + fr) * 64 +
                                                    ((kk * 4 + h) ^ lsw) * 8];
#pragma unroll
            for (int n = 0; n < 4; n++)
                bfr[kk][n] = *(const i16x8*)&Bsm[buf][(wc * 64 + n * 16 + fr) * 64 +
                                                     ((kk * 4 + h) ^ lsw) * 8];
        }
        LGKM0;
        SCHED0;
        SBAR;

#pragma unroll
        for (int kk = 0; kk < 2; kk++)
#pragma unroll
            for (int m = 0; m < 2; m++)
#pragma unroll
                for (int n = 0; n < 4; n++)
                    acc[m][n] = __builtin_amdgcn_mfma_f32_16x16x32_bf16(
                        af[kk][m], bfr[kk][n], acc[m][n], 0, 0, 0);
    }

    const int seg = (int)(blockIdx.x >> 1);
    const float* bp = (seg == 0) ? bias0 : ((seg == 1) ? bias1 : bias2);
#pragma unroll
    for (int m = 0; m < 2; m++) {
#pragma unroll
        for (int j = 0; j < 4; j++) {
            const int grow = row0 + wr * 32 + m * 16 + h * 4 + j;
#pragma unroll
            for (int n = 0; n < 4; n++) {
                const int gcol = col0 + wc * 64 + n * 16 + fr;
                if (EPI == 4 && gcol >= Nd) continue;
                float v = acc[m][n][j] + bp[gcol & 255];
                if constexpr (EPI == 1) v = fmaxf(v, 0.f);
                if constexpr (EPI == 4)
                    ((float*)Cv)[(size_t)grow * Nd + gcol] = v;
                else
                    ((u16*)Cv)[(size_t)grow * Nd + gcol] = f2b(v);
            }
        }
    }
}

// ---------------------------------------------------------------------------
// ffn_fused: single-barrier loops + cross-phase B0 prefetch.
// TAIL 0 writes K_e|V_e as fp8 into KV8e [E][512]B.
// ---------------------------------------------------------------------------
template <int TAIL>
__global__ __launch_bounds__(256, 2) void ffn_fused(
    const u16* __restrict__ X, const u16* __restrict__ Wt1,
    const float* __restrict__ b1, const u16* __restrict__ Wt2,
    const float* __restrict__ b2, const float* __restrict__ lng,
    const float* __restrict__ lnb, const u16* __restrict__ WtT,
    const float* __restrict__ bT0, const float* __restrict__ bT1,
    void* __restrict__ outp)
{
    __shared__ __align__(16) u16 Asm[2][64 * 32];
    __shared__ __align__(16) u16 Bsm[2][256 * 32];
    __shared__ __align__(16) u16 Msm[64 * MST];
    const int t = threadIdx.x;
    const int lane = t & 63, w = t >> 6;
    const int row0 = blockIdx.x * 64;

    const int srow = lane >> 2;
    const int sblk = ((lane & 3) ^ ((lane >> 3) & 3)) * 8;
    const int fr = lane & 15, h = lane >> 4;
    const int rsw = (fr >> 1) & 3;

    f32x4 acc[4][4] = {};

    auto stageA = [&](int buf, int kt) {
        gload_lds16(X + (size_t)(row0 + w * 16 + srow) * 256 + (kt << 5) + sblk,
                    &Asm[buf][(w * 16) * 32]);
    };
    auto stageB = [&](int buf, int kt, const u16* W) {
#pragma unroll
        for (int i = 0; i < 4; i++) {
            const int r = w * 64 + i * 16;
            gload_lds16(W + (size_t)(r + srow) * 256 + (kt << 5) + sblk,
                        &Bsm[buf][r * 32]);
        }
    };

    // ---------------- phase 1: mid = relu(X @ Wt1 + b1) ----------------
    stageA(0, 0); stageB(0, 0, Wt1);
    VMCNT0; SBAR;
#pragma unroll
    for (int kt = 0; kt < 8; ++kt) {
        const int buf = kt & 1;
        if (kt < 7) { stageA(buf ^ 1, kt + 1); stageB(buf ^ 1, kt + 1, Wt1); }
        else        { stageB(0, 0, Wt2); }    // prefetch phase-2 B0

        i16x8 af[4], bfr[4];
#pragma unroll
        for (int m = 0; m < 4; m++)
            af[m] = *(const i16x8*)&Asm[buf][(m * 16 + fr) * 32 + (h ^ rsw) * 8];
#pragma unroll
        for (int n = 0; n < 4; n++)
            bfr[n] = *(const i16x8*)&Bsm[buf][(w * 64 + n * 16 + fr) * 32 + (h ^ rsw) * 8];
        LGKM0;
        SCHED0;
#pragma unroll
        for (int m = 0; m < 4; m++)
#pragma unroll
            for (int n = 0; n < 4; n++)
                acc[m][n] = __builtin_amdgcn_mfma_f32_16x16x32_bf16(
                    af[m], bfr[n], acc[m][n], 0, 0, 0);
        if (kt < 7) { VMCNT0; SBAR; }
    }
    {   // mid -> Msm (relu + bias), reset acc
        float b1v[4];
#pragma unroll
        for (int n = 0; n < 4; n++) b1v[n] = b1[w * 64 + n * 16 + fr];
#pragma unroll
        for (int m = 0; m < 4; m++)
#pragma unroll
            for (int j = 0; j < 4; j++) {
                const int row = m * 16 + h * 4 + j;
#pragma unroll
                for (int n = 0; n < 4; n++) {
                    const int col = w * 64 + n * 16 + fr;
                    float v = fmaxf(acc[m][n][j] + b1v[n], 0.f);
                    Msm[row * MST + col] = f2b(v);
                    acc[m][n][j] = 0.f;
                }
            }
    }
    __syncthreads();   // drains vmcnt (phase-2 B0 landed) + lgkm + sync

    // ---------------- phase 2: y = LN(mid @ Wt2 + b2 + X) ----------------
#pragma unroll
    for (int kt = 0; kt < 8; ++kt) {
        const int buf = kt & 1;
        if (kt < 7) stageB(buf ^ 1, kt + 1, Wt2);
        else if (TAIL == 0) stageB(0, 0, WtT);   // prefetch tail half-0 B0

        i16x8 af[4], bfr[4];
#pragma unroll
        for (int m = 0; m < 4; m++)
            af[m] = *(const i16x8*)&Msm[(m * 16 + fr) * MST + (kt << 5) + h * 8];
#pragma unroll
        for (int n = 0; n < 4; n++)
            bfr[n] = *(const i16x8*)&Bsm[buf][(w * 64 + n * 16 + fr) * 32 + (h ^ rsw) * 8];
        LGKM0;
        SCHED0;
#pragma unroll
        for (int m = 0; m < 4; m++)
#pragma unroll
            for (int n = 0; n < 4; n++)
                acc[m][n] = __builtin_amdgcn_mfma_f32_16x16x32_bf16(
                    af[m], bfr[n], acc[m][n], 0, 0, 0);
        if (kt < 7) { VMCNT0; SBAR; }
    }
    {   // LN epilogue (resid = X re-read from global)
        float* redS = (float*)&Asm[0][0];
        float* redQ = redS + 256;
#pragma unroll
        for (int m = 0; m < 4; m++) {
#pragma unroll
            for (int j = 0; j < 4; j++) {
                const int grow = row0 + m * 16 + h * 4 + j;
                float s = 0.f, q = 0.f;
#pragma unroll
                for (int n = 0; n < 4; n++) {
                    const int gcol = w * 64 + n * 16 + fr;
                    float v = acc[m][n][j] + b2[gcol] +
                              b2f(X[(size_t)grow * 256 + gcol]);
                    acc[m][n][j] = v;
                    s += v; q += v * v;
                }
#pragma unroll
                for (int off = 1; off < 16; off <<= 1) {
                    s += __shfl_xor(s, off, 64);
                    q += __shfl_xor(q, off, 64);
                }
                if (fr == 0) {
                    redS[(m * 16 + h * 4 + j) * 4 + w] = s;
                    redQ[(m * 16 + h * 4 + j) * 4 + w] = q;
                }
            }
        }
        __syncthreads();
#pragma unroll
        for (int m = 0; m < 4; m++) {
#pragma unroll
            for (int j = 0; j < 4; j++) {
                const int r = m * 16 + h * 4 + j;
                float4 s4 = *(const float4*)&redS[r * 4];
                float4 q4 = *(const float4*)&redQ[r * 4];
                float mu = (s4.x + s4.y + s4.z + s4.w) * (1.f / DIM);
                float var = (q4.x + q4.y + q4.z + q4.w) * (1.f / DIM) - mu * mu;
                float rr = rsqrtf(var + LN_EPS);
#pragma unroll
                for (int n = 0; n < 4; n++) {
                    const int gcol = w * 64 + n * 16 + fr;
                    float y = (acc[m][n][j] - mu) * rr * lng[gcol] + lnb[gcol];
                    acc[m][n][j] = y;
                }
            }
        }
        __syncthreads();
#pragma unroll
        for (int m = 0; m < 4; m++)
#pragma unroll
            for (int j = 0; j < 4; j++) {
                const int row = m * 16 + h * 4 + j;
#pragma unroll
                for (int n = 0; n < 4; n++)
                    Msm[row * MST + (w * 64 + n * 16 + fr)] = f2b(acc[m][n][j]);
            }
    }
    __syncthreads();   // drains vmcnt (tail B0 landed) + Msm writes visible

    // ---------------- tail ----------------
    if constexpr (TAIL == 0) {
        u8* KV8e = (u8*)outp;
#pragma unroll 1
        for (int half = 0; half < 2; half++) {
            const u16* Wb = WtT + (size_t)half * 65536;
            const float* bT = half ? bT1 : bT0;
#pragma unroll
            for (int m = 0; m < 4; m++)
#pragma unroll
                for (int n = 0; n < 4; n++)
                    acc[m][n] = f32x4{0.f, 0.f, 0.f, 0.f};
#pragma unroll
            for (int kt = 0; kt < 8; ++kt) {
                const int buf = kt & 1;
                if (kt < 7) stageB(buf ^ 1, kt + 1, Wb);
                else if (half == 0) stageB(0, 0, WtT + 65536);  // half-1 B0

                i16x8 af[4], bfr[4];
#pragma unroll
                for (int m = 0; m < 4; m++)
                    af[m] = *(const i16x8*)&Msm[(m * 16 + fr) * MST + (kt << 5) + h * 8];
#pragma unroll
                for (int n = 0; n < 4; n++)
                    bfr[n] = *(const i16x8*)&Bsm[buf][(w * 64 + n * 16 + fr) * 32 + (h ^ rsw) * 8];
                LGKM0;
                SCHED0;
#pragma unroll
                for (int m = 0; m < 4; m++)
#pragma unroll
                    for (int n = 0; n < 4; n++)
                        acc[m][n] = __builtin_amdgcn_mfma_f32_16x16x32_bf16(
                            af[m], bfr[n], acc[m][n], 0, 0, 0);
                if (kt < 7) { VMCNT0; SBAR; }
            }
#pragma unroll
            for (int m = 0; m < 4; m++)
#pragma unroll
                for (int j = 0; j < 4; j++) {
                    const int grow = row0 + m * 16 + h * 4 + j;
#pragma unroll
                    for (int n = 0; n < 4; n++) {
                        const int gcol = w * 64 + n * 16 + fr;
                        KV8e[(size_t)grow * 512 + half * 256 + gcol] =
                            f32_to_f8(acc[m][n][j] + bT[gcol]);
                    }
                }
            if (half == 0) { VMCNT0; SBAR; }   // half-1 B0 landed; reads done
        }
    } else {
        float* out = (float*)outp;
        f32x4 acc3[3] = {};
#pragma unroll
        for (int kk = 0; kk < 8; kk++) {
            i16x8 af = *(const i16x8*)&Msm[(w * 16 + fr) * MST + kk * 32 + h * 8];
#pragma unroll
            for (int n = 0; n < 3; n++) {
                int br = n * 16 + fr; if (br > NCLS - 1) br = NCLS - 1;
                i16x8 bfr = *(const i16x8*)(WtT + (size_t)br * 256 + kk * 32 + h * 8);
                acc3[n] = __builtin_amdgcn_mfma_f32_16x16x32_bf16(af, bfr, acc3[n], 0, 0, 0);
            }
        }
#pragma unroll
        for (int n = 0; n < 3; n++) {
            const int gcol = n * 16 + fr;
            if (gcol >= NCLS) continue;
#pragma unroll
            for (int j = 0; j < 4; j++) {
                const int grow = row0 + w * 16 + h * 4 + j;
                out[(size_t)grow * NCLS + gcol] = acc3[n][j] + bT0[gcol];
            }
        }
    }
}

// ---------------------------------------------------------------------------
// edge_attn: gathers fp8 K/V from KV8n (u32/lane + cvt); Q bf16 from QEb.
// ---------------------------------------------------------------------------
__global__ __launch_bounds__(256) void edge_attn(
    const u8* __restrict__ KV8n, const u16* __restrict__ QE,
    const float* __restrict__ efeat,
    const int* __restrict__ e2n, const float* __restrict__ cent1,
    const float* __restrict__ g, const float* __restrict__ bb,
    u16* __restrict__ XE)
{
    const int lane = threadIdx.x & 63, w = threadIdx.x >> 6;
    const int e = blockIdx.x * 4 + w;
    const int c4 = lane * 4;

    ushort4 q4 = *(const ushort4*)&QE[(size_t)e * QDIM + c4];
    const float q0 = b2f(q4.x), q1 = b2f(q4.y), q2 = b2f(q4.z), q3 = b2f(q4.w);

    int4 rv[8];
#pragma unroll
    for (int i = 0; i < 8; i++)
        rv[i] = *(const int4*)&e2n[(size_t)e * DE + i * 4];
    int rows[DE];
#pragma unroll
    for (int i = 0; i < 8; i++) {
        rows[i * 4 + 0] = rv[i].x; rows[i * 4 + 1] = rv[i].y;
        rows[i * 4 + 2] = rv[i].z; rows[i * 4 + 3] = rv[i].w;
    }

    float p[DE];
#pragma unroll
    for (int g0 = 0; g0 < DE; g0 += 16) {       // 16 K-loads in flight
        u32 kw[16];
#pragma unroll
        for (int j = 0; j < 16; j++)
            kw[j] = *(const u32*)(KV8n + (size_t)rows[g0 + j] * 512 + c4);
#pragma unroll
        for (int j = 0; j < 16; j++) {
            float kf[4]; f8x4_to_f32(kw[j], kf);
            p[g0 + j] = q0 * kf[0] + q1 * kf[1] + q2 * kf[2] + q3 * kf[3];
        }
    }
#pragma unroll
    for (int off = 32; off; off >>= 1)          // 32 interleaved chains
#pragma unroll
        for (int d = 0; d < DE; d++)
            p[d] += __shfl_xor(p[d], off, 64);

    float4 cv[8];
#pragma unroll
    for (int i = 0; i < 8; i++)
        cv[i] = *(const float4*)&cent1[(size_t)e * DE + i * 4];
    float cent[DE];
#pragma unroll
    for (int i = 0; i < 8; i++) {
        cent[i * 4 + 0] = cv[i].x; cent[i * 4 + 1] = cv[i].y;
        cent[i * 4 + 2] = cv[i].z; cent[i * 4 + 3] = cv[i].w;
    }
#pragma unroll
    for (int d = 0; d < DE; d++)
        p[d] = (p[d] > 0.f ? p[d] : 0.01f * p[d]) * ATT_SCALE + cent[d];

    float mx = p[0];
#pragma unroll
    for (int d = 1; d < DE; d++) mx = fmaxf(mx, p[d]);
    float s = 0.f;
#pragma unroll
    for (int d = 0; d < DE; d++) { p[d] = __expf(p[d] - mx); s += p[d]; }
    const float inv = 1.f / s;
#pragma unroll
    for (int d = 0; d < DE; d++) p[d] *= inv;

    float a0 = 0.f, a1 = 0.f, a2 = 0.f, a3 = 0.f;
#pragma unroll
    for (int g0 = 0; g0 < DE; g0 += 16) {       // 16 V-loads in flight
        u32 vw[16];
#pragma unroll
        for (int j = 0; j < 16; j++)
            vw[j] = *(const u32*)(KV8n + (size_t)rows[g0 + j] * 512 + 256 + c4);
#pragma unroll
        for (int j = 0; j < 16; j++) {
            float vf[4]; f8x4_to_f32(vw[j], vf);
            const float sd = p[g0 + j];
            a0 = fmaf(sd, vf[0], a0); a1 = fmaf(sd, vf[1], a1);
            a2 = fmaf(sd, vf[2], a2); a3 = fmaf(sd, vf[3], a3);
        }
    }
    float4 ef = *(const float4*)&efeat[(size_t)e * DIM + c4];
    float x0 = a0 + ef.x, x1 = a1 + ef.y, x2 = a2 + ef.z, x3 = a3 + ef.w;

    float mu = x0 + x1 + x2 + x3;
#pragma unroll
    for (int off = 32; off; off >>= 1) mu += __shfl_xor(mu, off, 64);
    mu *= (1.f / DIM);
    float d0 = x0 - mu, d1 = x1 - mu, d2 = x2 - mu, d3 = x3 - mu;
    float var = d0 * d0 + d1 * d1 + d2 * d2 + d3 * d3;
#pragma unroll
    for (int off = 32; off; off >>= 1) var += __shfl_xor(var, off, 64);
    var *= (1.f / DIM);
    float r = rsqrtf(var + LN_EPS);
    float4 gv = *(const float4*)&g[c4];
    float4 bv = *(const float4*)&bb[c4];
    ushort4 o;
    o.x = f2b(d0 * r * gv.x + bv.x); o.y = f2b(d1 * r * gv.y + bv.y);
    o.z = f2b(d2 * r * gv.z + bv.z); o.w = f2b(d3 * r * gv.w + bv.w);
    *(ushort4*)&XE[(size_t)e * DIM + c4] = o;
}

// ---------------------------------------------------------------------------
// node_attn: gathers fp8 K/V from KV8e; q_v bf16 from QVb; resid FVb bf16.
// ---------------------------------------------------------------------------
__global__ __launch_bounds__(256) void node_attn(
    const u8* __restrict__ KV8e, const u16* __restrict__ QVb,
    const u16* __restrict__ FV,
    const int* __restrict__ n2e, const float* __restrict__ cent2,
    const float* __restrict__ g, const float* __restrict__ bb,
    u16* __restrict__ XV)
{
    const int lane = threadIdx.x & 63, w = threadIdx.x >> 6;
    const int na = blockIdx.x * 8 + w * 2, nb = na + 1;
    const int c4 = lane * 4;

    ushort4 qa4 = *(const ushort4*)&QVb[(size_t)na * 256 + c4];
    ushort4 qb4 = *(const ushort4*)&QVb[(size_t)nb * 256 + c4];
    const float qa0 = b2f(qa4.x), qa1 = b2f(qa4.y), qa2 = b2f(qa4.z), qa3 = b2f(qa4.w);
    const float qb0 = b2f(qb4.x), qb1 = b2f(qb4.y), qb2 = b2f(qb4.z), qb3 = b2f(qb4.w);

    int4 r0 = *(const int4*)&n2e[(size_t)na * DV];
    int4 r1 = *(const int4*)&n2e[(size_t)na * DV + 4];
    int4 r2 = *(const int4*)&n2e[(size_t)nb * DV];
    int4 r3 = *(const int4*)&n2e[(size_t)nb * DV + 4];
    int rA[8] = {r0.x, r0.y, r0.z, r0.w, r1.x, r1.y, r1.z, r1.w};
    int rB[8] = {r2.x, r2.y, r2.z, r2.w, r3.x, r3.y, r3.z, r3.w};

    u32 kA[8], vA[8], kB[8], vB[8];
#pragma unroll
    for (int d = 0; d < DV; d++) {
        const u8* b = KV8e + (size_t)rA[d] * 512 + c4;
        kA[d] = *(const u32*)b; vA[d] = *(const u32*)(b + 256);
    }
#pragma unroll
    for (int d = 0; d < DV; d++) {
        const u8* b = KV8e + (size_t)rB[d] * 512 + c4;
        kB[d] = *(const u32*)b; vB[d] = *(const u32*)(b + 256);
    }

    float pA[8], pB[8];
#pragma unroll
    for (int d = 0; d < DV; d++) {
        float ka[4], kb[4];
        f8x4_to_f32(kA[d], ka); f8x4_to_f32(kB[d], kb);
        pA[d] = qa0 * ka[0] + qa1 * ka[1] + qa2 * ka[2] + qa3 * ka[3];
        pB[d] = qb0 * kb[0] + qb1 * kb[1] + qb2 * kb[2] + qb3 * kb[3];
    }
#pragma unroll
    for (int off = 32; off; off >>= 1) {
#pragma unroll
        for (int d = 0; d < DV; d++) {
            pA[d] += __shfl_xor(pA[d], off, 64);
            pB[d] += __shfl_xor(pB[d], off, 64);
        }
    }
    float4 cA0 = *(const float4*)&cent2[(size_t)na * DV];
    float4 cA1 = *(const float4*)&cent2[(size_t)na * DV + 4];
    float4 cB0 = *(const float4*)&cent2[(size_t)nb * DV];
    float4 cB1 = *(const float4*)&cent2[(size_t)nb * DV + 4];
    float cA[8] = {cA0.x, cA0.y, cA0.z, cA0.w, cA1.x, cA1.y, cA1.z, cA1.w};
    float cB[8] = {cB0.x, cB0.y, cB0.z, cB0.w, cB1.x, cB1.y, cB1.z, cB1.w};
#pragma unroll
    for (int d = 0; d < DV; d++) {
        pA[d] = (pA[d] > 0.f ? pA[d] : 0.01f * pA[d]) * ATT_SCALE + cA[d];
        pB[d] = (pB[d] > 0.f ? pB[d] : 0.01f * pB[d]) * ATT_SCALE + cB[d];
    }
    float mA = pA[0], mB = pB[0];
#pragma unroll
    for (int d = 1; d < DV; d++) { mA = fmaxf(mA, pA[d]); mB = fmaxf(mB, pB[d]); }
    float sA = 0.f, sB = 0.f;
#pragma unroll
    for (int d = 0; d < DV; d++) {
        pA[d] = __expf(pA[d] - mA); sA += pA[d];
        pB[d] = __expf(pB[d] - mB); sB += pB[d];
    }
    const float iA = 1.f / sA, iB = 1.f / sB;

    float a0 = 0.f, a1 = 0.f, a2 = 0.f, a3 = 0.f;
    float b0 = 0.f, b1 = 0.f, b2 = 0.f, b3 = 0.f;
#pragma unroll
    for (int d = 0; d < DV; d++) {
        float va[4], vb[4];
        f8x4_to_f32(vA[d], va); f8x4_to_f32(vB[d], vb);
        const float sa = pA[d] * iA, sb = pB[d] * iB;
        a0 = fmaf(sa, va[0], a0); a1 = fmaf(sa, va[1], a1);
        a2 = fmaf(sa, va[2], a2); a3 = fmaf(sa, va[3], a3);
        b0 = fmaf(sb, vb[0], b0); b1 = fmaf(sb, vb[1], b1);
        b2 = fmaf(sb, vb[2], b2); b3 = fmaf(sb, vb[3], b3);
    }
    ushort4 fa = *(const ushort4*)&FV[(size_t)na * DIM + c4];
    ushort4 fb = *(const ushort4*)&FV[(size_t)nb * DIM + c4];
    float xa0 = a0 + b2f(fa.x), xa1 = a1 + b2f(fa.y);
    float xa2 = a2 + b2f(fa.z), xa3 = a3 + b2f(fa.w);
    float xb0 = b0 + b2f(fb.x), xb1 = b1 + b2f(fb.y);
    float xb2 = b2 + b2f(fb.z), xb3 = b3 + b2f(fb.w);

    float muA = xa0 + xa1 + xa2 + xa3, muB = xb0 + xb1 + xb2 + xb3;
#pragma unroll
    for (int off = 32; off; off >>= 1) {
        muA += __shfl_xor(muA, off, 64);
        muB += __shfl_xor(muB, off, 64);
    }
    muA *= (1.f / DIM); muB *= (1.f / DIM);
    float da0 = xa0 - muA, da1 = xa1 - muA, da2 = xa2 - muA, da3 = xa3 - muA;
    float db0 = xb0 - muB, db1 = xb1 - muB, db2 = xb2 - muB, db3 = xb3 - muB;
    float vA_ = da0 * da0 + da1 * da1 + da2 * da2 + da3 * da3;
    float vB_ = db0 * db0 + db1 * db1 + db2 * db2 + db3 * db3;
#pragma unroll
    for (int off = 32; off; off >>= 1) {
        vA_ += __shfl_xor(vA_, off, 64);
        vB_ += __shfl_xor(vB_, off, 64);
    }
    const float rA_ = rsqrtf(vA_ * (1.f / DIM) + LN_EPS);
    const float rB_ = rsqrtf(vB_ * (1.f / DIM) + LN_EPS);
    float4 gv = *(const float4*)&g[c4];
    float4 bv = *(const float4*)&bb[c4];
    ushort4 oa, ob;
    oa.x = f2b(da0 * rA_ * gv.x + bv.x); oa.y = f2b(da1 * rA_ * gv.y + bv.y);
    oa.z = f2b(da2 * rA_ * gv.z + bv.z); oa.w = f2b(da3 * rA_ * gv.w + bv.w);
    ob.x = f2b(db0 * rB_ * gv.x + bv.x); ob.y = f2b(db1 * rB_ * gv.y + bv.y);
    ob.z = f2b(db2 * rB_ * gv.z + bv.z); ob.w = f2b(db3 * rB_ * gv.w + bv.w);
    *(ushort4*)&XV[(size_t)na * DIM + c4] = oa;
    *(ushort4*)&XV[(size_t)nb * DIM + c4] = ob;
}

extern "C" void kernel_launch(void* const* d_in, const int* in_sizes, int n_in,
                              void* d_out, int out_size, void* d_ws, size_t ws_size,
                              hipStream_t stream)
{
    const float* vfeat  = (const float*)d_in[0];
    const float* efeat  = (const float*)d_in[1];
    const float* eign   = (const float*)d_in[2];
    const float* gcn    = (const float*)d_in[3];
    const float* cent1  = (const float*)d_in[4];
    const float* cent2  = (const float*)d_in[5];
    const int*   cidx   = (const int*)d_in[6];
    const int*   uidx   = (const int*)d_in[7];
    const int*   e2n    = (const int*)d_in[8];
    const int*   n2e    = (const int*)d_in[9];
    const float* W_vtx  = (const float*)d_in[10]; const float* b_vtx = (const float*)d_in[11];
    const float* W_pe   = (const float*)d_in[12]; const float* b_pe  = (const float*)d_in[13];
    const float* cs_emb = (const float*)d_in[14]; const float* un_emb= (const float*)d_in[15];
    const float* W_kv   = (const float*)d_in[16]; const float* b_kv  = (const float*)d_in[17];
    const float* W_vv   = (const float*)d_in[18]; const float* b_vv  = (const float*)d_in[19];
    const float* W_qe   = (const float*)d_in[20]; const float* b_qe  = (const float*)d_in[21];
    const float* W_ke   = (const float*)d_in[22]; const float* b_ke  = (const float*)d_in[23];
    const float* W_ve   = (const float*)d_in[24]; const float* b_ve  = (const float*)d_in[25];
    const float* W_qv   = (const float*)d_in[26]; const float* b_qv  = (const float*)d_in[27];
    const float* W_l1   = (const float*)d_in[28]; const float* b_l1  = (const float*)d_in[29];
    const float* W_l2   = (const float*)d_in[30]; const float* b_l2  = (const float*)d_in[31];
    const float* W_l3   = (const float*)d_in[32]; const float* b_l3  = (const float*)d_in[33];
    const float* W_l4   = (const float*)d_in[34]; const float* b_l4  = (const float*)d_in[35];
    const float* ln1_g  = (const float*)d_in[36]; const float* ln1_b = (const float*)d_in[37];
    const float* ln2_g  = (const float*)d_in[38]; const float* ln2_b = (const float*)d_in[39];
    const float* W_cls  = (const float*)d_in[40]; const float* b_cls = (const float*)d_in[41];
    float* out = (float*)d_out;

    const size_t NE = (size_t)N_NODES * DIM;   // 10,240,000
    const size_t EE = (size_t)N_EDGES * DIM;   //  2,048,000
    u16* ws = (u16*)d_ws;
    u16* FVb  = ws;                          // bf16 feat_v (resid for node_attn)
    u16* QVb  = FVb + NE;                    // bf16 q_v [N][256]
    u16* B2   = QVb + NE;                    // bf16 x_v
    u16* QEb  = B2 + NE;                     // bf16 q_e
    u16* XE   = QEb + EE;                    // bf16 x_e
    u8*  KV8n = (u8*)(XE + EE);              // fp8 [N][512]B k_n|v_n
    u8*  KV8e = KV8n + (size_t)N_NODES * 512;// fp8 [E][512]B k_e|v_e
    u16* Wp   = (u16*)(KV8e + (size_t)N_EDGES * 512);  // 13 * 65536 u16
    u16* Wt_vtx = Wp +  0 * 65536;
    u16* Wt_pe  = Wp +  1 * 65536;
    u16* Wt_kvq = Wp +  2 * 65536;  // slots 2,3,4 = [768][256]
    u16* Wt_qe  = Wp +  5 * 65536;
    u16* Wt_kve = Wp +  6 * 65536;  // slots 6,7 = [512][256]
    u16* Wt_l1  = Wp +  8 * 65536;
    u16* Wt_l2  = Wp +  9 * 65536;
    u16* Wt_l3  = Wp + 10 * 65536;
    u16* Wt_l4  = Wp + 11 * 65536;
    u16* Wt_cls = Wp + 12 * 65536;

    const dim3 blk(256);
    const dim3 gW(8, 8, 13);
    const dim3 gQE(2, N_EDGES / 64);     // (2,125)

    prep_weights<<<gW, blk, 0, stream>>>(
        W_vtx, W_pe, W_kv, W_vv, W_qv, W_qe, W_ke, W_ve,
        W_l1, W_l2, W_l3, W_l4, W_cls, Wp);

    // fused assembly + KVQ (K/V -> fp8, Q -> bf16)
    asm_kvq<<<N_NODES / 64, blk, 0, stream>>>(
        vfeat, eign, Wt_vtx, Wt_pe, b_vtx, b_pe,
        gcn, cs_emb, un_emb, cidx, uidx,
        Wt_kvq, b_kv, b_vv, b_qv, FVb, KV8n, QVb);

    // stage 1
    gemmN<0, 1, 4><<<gQE, blk, 0, stream>>>(efeat, Wt_qe,
        b_qe, b_qe, b_qe, QEb, 256);                                    // q_e
    edge_attn<<<N_EDGES / 4, blk, 0, stream>>>(KV8n, QEb, efeat, e2n, cent1,
        ln1_g, ln1_b, XE);
    ffn_fused<0><<<N_EDGES / 64, blk, 0, stream>>>(XE, Wt_l1, b_l1,
        Wt_l2, b_l2, ln1_g, ln1_b, Wt_kve, b_ke, b_ve, KV8e);           // FFN+LN+{k_e|v_e fp8}

    // stage 2
    node_attn<<<N_NODES / 8, blk, 0, stream>>>(KV8e, QVb, FVb, n2e, cent2,
        ln2_g, ln2_b, B2);                                              // x_v
    ffn_fused<1><<<N_NODES / 64, blk, 0, stream>>>(B2, Wt_l3, b_l3,
        Wt_l4, b_l4, ln2_g, ln2_b, Wt_cls, b_cls, nullptr, out);        // FFN+LN+cls
}

// Round 16
// 219.015 us; speedup vs baseline: 1.5388x; 1.0460x over previous
//
// R15: hardware fp8 converts. Guarded helpers now fall back to inline-asm
// v_cvt_pk_fp8_f32 / v_cvt_pk_f32_fp8 (not software emulation); epilogue
// stores use pair-packed conversion (2 values/inst). Everything else
// byte-identical to R14 (229.1 us).
#include <hip/hip_runtime.h>
#include <hip/hip_bf16.h>
#include <cstddef>

#define N_NODES 40000
#define N_EDGES 8000
#define DE 32
#define DV 8
#define DIM 256
#define QDIM 256
#define EIGD 64
#define NCLS 40
#define LN_EPS 1e-5f
#define ATT_SCALE 0.0625f   // 1/sqrt(256)

typedef unsigned short u16;
typedef unsigned int u32;
typedef unsigned char u8;
using i16x8 = __attribute__((ext_vector_type(8))) short;
using f32x4 = __attribute__((ext_vector_type(4))) float;
using f32x2 = __attribute__((ext_vector_type(2))) float;

__device__ inline u16 f2b(float f) {   // RNE f32 -> bf16 bits
    union { float f; u32 u; } c; c.f = f;
    u32 u = c.u + 0x7FFF + ((c.u >> 16) & 1);
    return (u16)(u >> 16);
}
__device__ inline float b2f(u16 b) {
    union { u32 u; float f; } c; c.u = (u32)b << 16;
    return c.f;
}

// ---- fp8 e4m3 unpack: 4 bytes -> 4 f32 (HW either way) ----
__device__ inline void f8x4_to_f32(u32 w, float o[4]) {
#if __has_builtin(__builtin_amdgcn_cvt_pk_f32_fp8)
    f32x2 lo = __builtin_amdgcn_cvt_pk_f32_fp8((int)w, false);
    f32x2 hi = __builtin_amdgcn_cvt_pk_f32_fp8((int)w, true);
    o[0] = lo[0]; o[1] = lo[1]; o[2] = hi[0]; o[3] = hi[1];
#else
    f32x2 lo, hi;
    u32 wh = w >> 16;
    asm("v_cvt_pk_f32_fp8 %0, %1" : "=v"(lo) : "v"(w));
    asm("v_cvt_pk_f32_fp8 %0, %1" : "=v"(hi) : "v"(wh));
    o[0] = lo[0]; o[1] = lo[1]; o[2] = hi[0]; o[3] = hi[1];
#endif
}

// ---- fp8 e4m3 pack: 2 f32 -> 2 bytes in low half of u32 (HW either way) ----
__device__ inline u32 f8pk2(float a, float b) {
#if __has_builtin(__builtin_amdgcn_cvt_pk_fp8_f32)
    return (u32)__builtin_amdgcn_cvt_pk_fp8_f32(a, b, 0, false) & 0xffffu;
#else
    u32 d = 0;
    asm("v_cvt_pk_fp8_f32 %0, %1, %2" : "+v"(d) : "v"(a), "v"(b));
    return d & 0xffffu;
#endif
}

__device__ inline void gload_lds16(const u16* g, u16* l) {
    __builtin_amdgcn_global_load_lds(
        (const __attribute__((address_space(1))) void*)g,
        (__attribute__((address_space(3))) void*)l, 16, 0, 0);
}

#define VMCNT12 asm volatile("s_waitcnt vmcnt(12)" ::: "memory")
#define VMCNT6  asm volatile("s_waitcnt vmcnt(6)" ::: "memory")
#define VMCNT0  asm volatile("s_waitcnt vmcnt(0)" ::: "memory")
#define LGKM0   asm volatile("s_waitcnt lgkmcnt(0)" ::: "memory")
#define SCHED0  __builtin_amdgcn_sched_barrier(0)
#define SBAR    __builtin_amdgcn_s_barrier()

// ---------------------------------------------------------------------------
// Batched transpose-cast. Slots: 0 vtx, 1 pe, 2 kv, 3 vv, 4 qv, 5 qe,
// 6 ke, 7 ve, 8 l1, 9 l2, 10 l3, 11 l4, 12 cls.
// ---------------------------------------------------------------------------
__global__ __launch_bounds__(256) void prep_weights(
    const float* w0, const float* w1, const float* w2, const float* w3,
    const float* w4, const float* w5, const float* w6, const float* w7,
    const float* w8, const float* w9, const float* w10, const float* w11,
    const float* w12, u16* __restrict__ pool)
{
    const float* srcs[13] = {w0,w1,w2,w3,w4,w5,w6,w7,w8,w9,w10,w11,w12};
    const int Ks[13]  = {256,64,256,256,256,256,256,256,256,256,256,256,256};
    const int Nds[13] = {256,256,256,256,256,256,256,256,256,256,256,256,40};
    const int id = blockIdx.z;
    const float* W = srcs[id];
    u16* Wt = pool + (size_t)id * 65536;
    const int K = Ks[id], Nd = Nds[id];
    const int k0 = blockIdx.x * 32, n0 = blockIdx.y * 32;
    if (k0 >= K || n0 >= Nd) return;

    __shared__ float tile[32][33];
    const int x = threadIdx.x & 31, y4 = (threadIdx.x >> 5) * 4;
#pragma unroll
    for (int j = 0; j < 4; j++) {
        int k = k0 + y4 + j;
        tile[y4 + j][x] = (k < K && (n0 + x) < Nd) ? W[(size_t)k * Nd + n0 + x] : 0.f;
    }
    __syncthreads();
#pragma unroll
    for (int j = 0; j < 4; j++) {
        int n = n0 + y4 + j;
        if (n < Nd && (k0 + x) < K)
            Wt[(size_t)n * K + k0 + x] = f2b(tile[x][y4 + j]);
    }
}

// ---------------------------------------------------------------------------
// asm_kvq: phase 1 (R8 2-barrier structure), add-pass, phase 2 single-barrier
// steps + cross-chunk B0 prefetch. Chunks 0/1 (K/V) -> fp8 KV8n via pair-pack;
// chunk 2 (Q) -> bf16 QVb.
// ---------------------------------------------------------------------------
#define MST 264
__global__ __launch_bounds__(256, 2) void asm_kvq(
    const float* __restrict__ vfeat, const float* __restrict__ eign,
    const u16* __restrict__ Wt_vtx, const u16* __restrict__ Wt_pe,
    const float* __restrict__ b_vtx, const float* __restrict__ b_pe,
    const float* __restrict__ gcn, const float* __restrict__ emb1,
    const float* __restrict__ emb2, const int* __restrict__ idx1,
    const int* __restrict__ idx2,
    const u16* __restrict__ Wt_kvq, const float* __restrict__ b_kv,
    const float* __restrict__ b_vv, const float* __restrict__ b_qv,
    u16* __restrict__ FVb, u8* __restrict__ KV8n, u16* __restrict__ QVb)
{
    __shared__ __align__(16) u16 Asm[2][64 * 32];   //  8 KB
    __shared__ __align__(16) u16 Bsm[2][256 * 32];  // 32 KB
    __shared__ __align__(16) u16 Msm[64 * MST];     // 33.75 KB
    const int t = threadIdx.x;
    const int lane = t & 63, w = t >> 6;
    const int row0 = blockIdx.x * 64;

    const int srow = lane >> 2;                          // 0..15
    const int sblk = ((lane & 3) ^ ((lane >> 3) & 3)) * 8;  // swizzled src blk
    const int fr = lane & 15, h = lane >> 4;
    const int rsw = (fr >> 1) & 3;

    f32x4 acc[4][4] = {};
    float4 fA[2][2];                                      // [parity][half]

    auto p1_issueB = [&](int kt) {
        const int buf = kt & 1;
        const int k0 = kt << 5;
        const bool tail = (k0 >= 256);
#pragma unroll
        for (int i = 0; i < 4; i++) {
            const int r = w * 64 + i * 16;
            const u16* gp = tail ? Wt_pe + (size_t)(r + srow) * 64 + (k0 - 256) + sblk
                                 : Wt_vtx + (size_t)(r + srow) * 256 + k0 + sblk;
            gload_lds16(gp, &Bsm[buf][r * 32]);
        }
    };
    auto p1_loadA = [&](int kt) {
        const int k0 = kt << 5;
        const bool tail = (k0 >= 256);
        const float* ap = tail
            ? eign + (size_t)(row0 + w * 16 + srow) * 64 + (k0 - 256) + sblk
            : vfeat + (size_t)(row0 + w * 16 + srow) * 256 + k0 + sblk;
        fA[kt & 1][0] = *(const float4*)ap;
        fA[kt & 1][1] = *(const float4*)(ap + 4);
    };
    auto p1_write = [&](int kt) {                         // cvt + ds_write
        const int buf = kt & 1;
        float4 f0 = fA[buf][0], f1 = fA[buf][1];
        i16x8 v;
        v[0] = (short)f2b(f0.x); v[1] = (short)f2b(f0.y);
        v[2] = (short)f2b(f0.z); v[3] = (short)f2b(f0.w);
        v[4] = (short)f2b(f1.x); v[5] = (short)f2b(f1.y);
        v[6] = (short)f2b(f1.z); v[7] = (short)f2b(f1.w);
        *(i16x8*)&Asm[buf][(w * 16 + srow) * 32 + (lane & 3) * 8] = v;
    };

    // ---- phase 1 main loop (NT=10; R8-proven 2-barrier structure) ----
    p1_loadA(0); p1_issueB(0); p1_loadA(1); p1_write(0);
#pragma unroll
    for (int kt = 0; kt < 10; ++kt) {
        const int buf = kt & 1;
        if (kt + 1 < 10) p1_issueB(kt + 1);
        if (kt + 2 < 10) p1_loadA(kt + 2);
        if (kt + 1 < 10) p1_write(kt + 1);
        else { VMCNT0; }
        LGKM0;
        SBAR;

        i16x8 af[4], bfr[4];
#pragma unroll
        for (int m = 0; m < 4; m++)
            af[m] = *(const i16x8*)&Asm[buf][(m * 16 + fr) * 32 + (h ^ rsw) * 8];
#pragma unroll
        for (int n = 0; n < 4; n++)
            bfr[n] = *(const i16x8*)&Bsm[buf][(w * 64 + n * 16 + fr) * 32 + (h ^ rsw) * 8];
        LGKM0;
        SCHED0;
        SBAR;

#pragma unroll
        for (int m = 0; m < 4; m++)
#pragma unroll
            for (int n = 0; n < 4; n++)
                acc[m][n] = __builtin_amdgcn_mfma_f32_16x16x32_bf16(
                    af[m], bfr[n], acc[m][n], 0, 0, 0);
    }

    // ---- phase 1 epilogue: acc + biases -> Msm ----
#pragma unroll
    for (int m = 0; m < 4; m++)
#pragma unroll
        for (int j = 0; j < 4; j++) {
            const int row = m * 16 + h * 4 + j;
#pragma unroll
            for (int n = 0; n < 4; n++) {
                const int col = w * 64 + n * 16 + fr;
                float v = acc[m][n][j] + b_vtx[col] + b_pe[col];
                Msm[row * MST + col] = f2b(v);
            }
        }
    __syncthreads();

    // ---- coalesced add pass: Msm += gcn + emb1[idx1] + emb2[idx2] ----
    const float4* gcn4 = (const float4*)gcn;
    const float4* e1_4 = (const float4*)emb1;
    const float4* e2_4 = (const float4*)emb2;
    ushort4* FVb4 = (ushort4*)FVb;
#pragma unroll 4
    for (int it = 0; it < 16; ++it) {
        const int T = t + it * 256;
        const int row = T >> 6, cg = T & 63;
        const int grow = row0 + row;
        const int i1 = idx1[grow], i2 = idx2[grow];
        ushort4 mv = *(const ushort4*)&Msm[row * MST + cg * 4];
        float4 gv = gcn4[(size_t)grow * 64 + cg];
        float4 e1 = e1_4[(size_t)i1 * 64 + cg];
        float4 e2 = e2_4[(size_t)i2 * 64 + cg];
        ushort4 o;
        o.x = f2b(b2f(mv.x) + gv.x + e1.x + e2.x);
        o.y = f2b(b2f(mv.y) + gv.y + e1.y + e2.y);
        o.z = f2b(b2f(mv.z) + gv.z + e1.z + e2.z);
        o.w = f2b(b2f(mv.w) + gv.w + e1.w + e2.w);
        FVb4[(size_t)grow * 64 + cg] = o;
        *(ushort4*)&Msm[row * MST + cg * 4] = o;
    }
    __syncthreads();

    // ---- phase 2: KVQ = Msm @ Wt_kvq (3 chunks), single-barrier steps ----
    auto p2_issueB = [&](int buf, int kt, const u16* Wb) {
#pragma unroll
        for (int i = 0; i < 4; i++) {
            const int r = w * 64 + i * 16;
            gload_lds16(Wb + (size_t)(r + srow) * 256 + (kt << 5) + sblk,
                        &Bsm[buf][r * 32]);
        }
    };
    p2_issueB(0, 0, Wt_kvq);
    VMCNT0; SBAR;
#pragma unroll 1
    for (int c = 0; c < 3; ++c) {
        const u16* Wb = Wt_kvq + (size_t)c * 65536;
        const float* bc = (c == 0) ? b_kv : ((c == 1) ? b_vv : b_qv);
#pragma unroll
        for (int m = 0; m < 4; m++)
#pragma unroll
            for (int n = 0; n < 4; n++)
                acc[m][n] = f32x4{0.f, 0.f, 0.f, 0.f};
#pragma unroll
        for (int kt = 0; kt < 8; ++kt) {
            const int buf = kt & 1;
            if (kt < 7) p2_issueB(buf ^ 1, kt + 1, Wb);
            else if (c < 2) p2_issueB(0, 0, Wb + 65536);   // next chunk's B0

            i16x8 af[4], bfr[4];
#pragma unroll
            for (int m = 0; m < 4; m++)
                af[m] = *(const i16x8*)&Msm[(m * 16 + fr) * MST + (kt << 5) + h * 8];
#pragma unroll
            for (int n = 0; n < 4; n++)
                bfr[n] = *(const i16x8*)&Bsm[buf][(w * 64 + n * 16 + fr) * 32 + (h ^ rsw) * 8];
            LGKM0;
            SCHED0;
#pragma unroll
            for (int m = 0; m < 4; m++)
#pragma unroll
                for (int n = 0; n < 4; n++)
                    acc[m][n] = __builtin_amdgcn_mfma_f32_16x16x32_bf16(
                        af[m], bfr[n], acc[m][n], 0, 0, 0);
            if (kt < 7) { VMCNT0; SBAR; }
        }
        // store chunk c: c<2 -> fp8 (pair-packed); c==2 -> bf16 QVb
        if (c < 2) {
#pragma unroll
            for (int m = 0; m < 4; m++) {
                const size_t rbase = (size_t)(row0 + m * 16 + h * 4) * 512 + c * 256;
#pragma unroll
                for (int n = 0; n < 4; n++) {
                    const int gcol = w * 64 + n * 16 + fr;
                    const float bcv = bc[gcol];
                    u32 p01 = f8pk2(acc[m][n][0] + bcv, acc[m][n][1] + bcv);
                    u32 p23 = f8pk2(acc[m][n][2] + bcv, acc[m][n][3] + bcv);
                    KV8n[rbase + gcol]        = (u8)p01;
                    KV8n[rbase + 512 + gcol]  = (u8)(p01 >> 8);
                    KV8n[rbase + 1024 + gcol] = (u8)p23;
                    KV8n[rbase + 1536 + gcol] = (u8)(p23 >> 8);
                }
            }
        } else {
#pragma unroll
            for (int m = 0; m < 4; m++)
#pragma unroll
                for (int j = 0; j < 4; j++) {
                    const int grow = row0 + m * 16 + h * 4 + j;
#pragma unroll
                    for (int n = 0; n < 4; n++) {
                        const int gcol = w * 64 + n * 16 + fr;
                        QVb[(size_t)grow * 256 + gcol] = f2b(acc[m][n][j] + bc[gcol]);
                    }
                }
        }
        if (c < 2) { VMCNT0; SBAR; }    // next chunk's B0 landed; reads done
    }
}

// ---------------------------------------------------------------------------
// gemmN: BM=64, BN=128, BK=64 (used for q_e only; unchanged)
// ---------------------------------------------------------------------------
template <int EPI, int AMODE, int NT>
__global__ __launch_bounds__(256, 2) void gemmN(
    const void* __restrict__ Av, const u16* __restrict__ Wt,
    const float* __restrict__ bias0, const float* __restrict__ bias1,
    const float* __restrict__ bias2,
    void* __restrict__ Cv, int Nd)
{
    __shared__ u16 Asm[3][64 * 64];
    __shared__ u16 Bsm[3][128 * 64];
    const int t = threadIdx.x;
    const int lane = t & 63, w = t >> 6;
    const int wr = w >> 1, wc = w & 1;
    const int row0 = blockIdx.y * 64, col0 = blockIdx.x * 128;

    f32x4 acc[2][4] = {};

    const int srow = lane >> 3;
    const int sblk = ((lane & 7) ^ srow) * 8;
    const int fr = lane & 15, h = lane >> 4;
    const int lsw = fr & 7;

    float4 farA[2][2][2];

    auto stage_load = [&](int kt) {
        const int buf = kt % 3;
        const int k0 = kt << 6;
        if constexpr (AMODE == 0) {
#pragma unroll
            for (int i = 0; i < 2; i++) {
                const int r = w * 16 + i * 8;
                gload_lds16((const u16*)Av + (size_t)(row0 + r + srow) * 256 + k0 + sblk,
                            &Asm[buf][r * 64]);
            }
        } else {
#pragma unroll
            for (int i = 0; i < 2; i++) {
                const int r = w * 16 + i * 8;
                const float* ap = (const float*)Av + (size_t)(row0 + r + srow) * 256 + k0 + sblk;
                farA[kt & 1][i][0] = *(const float4*)ap;
                farA[kt & 1][i][1] = *(const float4*)(ap + 4);
            }
        }
#pragma unroll
        for (int i = 0; i < 4; i++) {
            const int r = w * 32 + i * 8;
            int ng = col0 + r + srow; if (ng > Nd - 1) ng = Nd - 1;
            gload_lds16(Wt + (size_t)ng * 256 + k0 + sblk, &Bsm[buf][r * 64]);
        }
    };
    auto stage_write = [&](int kt) {
        const int buf = kt % 3;
#pragma unroll
        for (int i = 0; i < 2; i++) {
            const int r = w * 16 + i * 8;
            float4 f0 = farA[kt & 1][i][0], f1 = farA[kt & 1][i][1];
            i16x8 v;
            v[0] = (short)f2b(f0.x); v[1] = (short)f2b(f0.y);
            v[2] = (short)f2b(f0.z); v[3] = (short)f2b(f0.w);
            v[4] = (short)f2b(f1.x); v[5] = (short)f2b(f1.y);
            v[6] = (short)f2b(f1.z); v[7] = (short)f2b(f1.w);
            *(i16x8*)&Asm[buf][(r + srow) * 64 + (lane & 7) * 8] = v;
        }
    };

    stage_load(0);
    if (NT > 1) stage_load(1);
    if constexpr (AMODE != 0) stage_write(0);

#pragma unroll
    for (int kt = 0; kt < NT; ++kt) {
        const int buf = kt % 3;
        if (kt + 2 < NT) stage_load(kt + 2);
        if constexpr (AMODE != 0) {
            if (kt + 1 < NT) stage_write(kt + 1);
            else { VMCNT0; }
        } else {
            if (kt + 2 < NT) { VMCNT12; }
            else if (kt + 1 < NT) { VMCNT6; }
            else { VMCNT0; }
        }
        LGKM0;
        SBAR;

        i16x8 af[2][2], bfr[2][4];
#pragma unroll
        for (int kk = 0; kk < 2; kk++) {
#pragma unroll
            for (int m = 0; m < 2; m++)
                af[kk][m] = *(const i16x8*)&Asm[buf][(wr * 32 + m * 16 + fr) * 64 +
                                                    ((kk * 4 + h) ^ lsw) * 8];
#pragma unroll
            for (int n = 0; n < 4; n++)
                bfr[kk][n] = *(const i16x8*)&Bsm[buf][(wc * 64 + n * 16 + fr) * 64 +
                                                     ((kk * 4 + h) ^ lsw) * 8];
        }
        LGKM0;
        SCHED0;
        SBAR;

#pragma unroll
        for (int kk = 0; kk < 2; kk++)
#pragma unroll
            for (int m = 0; m < 2; m++)
#pragma unroll
                for (int n = 0; n < 4; n++)
                    acc[m][n] = __builtin_amdgcn_mfma_f32_16x16x32_bf16(
                        af[kk][m], bfr[kk][n], acc[m][n], 0, 0, 0);
    }

    const int seg = (int)(blockIdx.x >> 1);
    const float* bp = (seg == 0) ? bias0 : ((seg == 1) ? bias1 : bias2);
#pragma unroll
    for (int m = 0; m < 2; m++) {
#pragma unroll
        for (int j = 0; j < 4; j++) {
            const int grow = row0 + wr * 32 + m * 16 + h * 4 + j;
#pragma unroll
            for (int n = 0; n < 4; n++) {
                const int gcol = col0 + wc * 64 + n * 16 + fr;
                if (EPI == 4 && gcol >= Nd) continue;
                float v = acc[m][n][j] + bp[gcol & 255];
                if constexpr (EPI == 1) v = fmaxf(v, 0.f);
                if constexpr (EPI == 4)
                    ((float*)Cv)[(size_t)grow * Nd + gcol] = v;
                else
                    ((u16*)Cv)[(size_t)grow * Nd + gcol] = f2b(v);
            }
        }
    }
}

// ---------------------------------------------------------------------------
// ffn_fused: single-barrier loops + cross-phase B0 prefetch.
// TAIL 0 writes K_e|V_e as fp8 (pair-packed) into KV8e [E][512]B.
// ---------------------------------------------------------------------------
template <int TAIL>
__global__ __launch_bounds__(256, 2) void ffn_fused(
    const u16* __restrict__ X, const u16* __restrict__ Wt1,
    const float* __restrict__ b1, const u16* __restrict__ Wt2,
    const float* __restrict__ b2, const float* __restrict__ lng,
    const float* __restrict__ lnb, const u16* __restrict__ WtT,
    const float* __restrict__ bT0, const float* __restrict__ bT1,
    void* __restrict__ outp)
{
    __shared__ __align__(16) u16 Asm[2][64 * 32];
    __shared__ __align__(16) u16 Bsm[2][256 * 32];
    __shared__ __align__(16) u16 Msm[64 * MST];
    const int t = threadIdx.x;
    const int lane = t & 63, w = t >> 6;
    const int row0 = blockIdx.x * 64;

    const int srow = lane >> 2;
    const int sblk = ((lane & 3) ^ ((lane >> 3) & 3)) * 8;
    const int fr = lane & 15, h = lane >> 4;
    const int rsw = (fr >> 1) & 3;

    f32x4 acc[4][4] = {};

    auto stageA = [&](int buf, int kt) {
        gload_lds16(X + (size_t)(row0 + w * 16 + srow) * 256 + (kt << 5) + sblk,
                    &Asm[buf][(w * 16) * 32]);
    };
    auto stageB = [&](int buf, int kt, const u16* W) {
#pragma unroll
        for (int i = 0; i < 4; i++) {
            const int r = w * 64 + i * 16;
            gload_lds16(W + (size_t)(r + srow) * 256 + (kt << 5) + sblk,
                        &Bsm[buf][r * 32]);
        }
    };

    // ---------------- phase 1: mid = relu(X @ Wt1 + b1) ----------------
    stageA(0, 0); stageB(0, 0, Wt1);
    VMCNT0; SBAR;
#pragma unroll
    for (int kt = 0; kt < 8; ++kt) {
        const int buf = kt & 1;
        if (kt < 7) { stageA(buf ^ 1, kt + 1); stageB(buf ^ 1, kt + 1, Wt1); }
        else        { stageB(0, 0, Wt2); }    // prefetch phase-2 B0

        i16x8 af[4], bfr[4];
#pragma unroll
        for (int m = 0; m < 4; m++)
            af[m] = *(const i16x8*)&Asm[buf][(m * 16 + fr) * 32 + (h ^ rsw) * 8];
#pragma unroll
        for (int n = 0; n < 4; n++)
            bfr[n] = *(const i16x8*)&Bsm[buf][(w * 64 + n * 16 + fr) * 32 + (h ^ rsw) * 8];
        LGKM0;
        SCHED0;
#pragma unroll
        for (int m = 0; m < 4; m++)
#pragma unroll
            for (int n = 0; n < 4; n++)
                acc[m][n] = __builtin_amdgcn_mfma_f32_16x16x32_bf16(
                    af[m], bfr[n], acc[m][n], 0, 0, 0);
        if (kt < 7) { VMCNT0; SBAR; }
    }
    {   // mid -> Msm (relu + bias), reset acc
        float b1v[4];
#pragma unroll
        for (int n = 0; n < 4; n++) b1v[n] = b1[w * 64 + n * 16 + fr];
#pragma unroll
        for (int m = 0; m < 4; m++)
#pragma unroll
            for (int j = 0; j < 4; j++) {
                const int row = m * 16 + h * 4 + j;
#pragma unroll
                for (int n = 0; n < 4; n++) {
                    const int col = w * 64 + n * 16 + fr;
                    float v = fmaxf(acc[m][n][j] + b1v[n], 0.f);
                    Msm[row * MST + col] = f2b(v);
                    acc[m][n][j] = 0.f;
                }
            }
    }
    __syncthreads();   // drains vmcnt (phase-2 B0 landed) + lgkm + sync

    // ---------------- phase 2: y = LN(mid @ Wt2 + b2 + X) ----------------
#pragma unroll
    for (int kt = 0; kt < 8; ++kt) {
        const int buf = kt & 1;
        if (kt < 7) stageB(buf ^ 1, kt + 1, Wt2);
        else if (TAIL == 0) stageB(0, 0, WtT);   // prefetch tail half-0 B0

        i16x8 af[4], bfr[4];
#pragma unroll
        for (int m = 0; m < 4; m++)
            af[m] = *(const i16x8*)&Msm[(m * 16 + fr) * MST + (kt << 5) + h * 8];
#pragma unroll
        for (int n = 0; n < 4; n++)
            bfr[n] = *(const i16x8*)&Bsm[buf][(w * 64 + n * 16 + fr) * 32 + (h ^ rsw) * 8];
        LGKM0;
        SCHED0;
#pragma unroll
        for (int m = 0; m < 4; m++)
#pragma unroll
            for (int n = 0; n < 4; n++)
                acc[m][n] = __builtin_amdgcn_mfma_f32_16x16x32_bf16(
                    af[m], bfr[n], acc[m][n], 0, 0, 0);
        if (kt < 7) { VMCNT0; SBAR; }
    }
    {   // LN epilogue (resid = X re-read from global)
        float* redS = (float*)&Asm[0][0];
        float* redQ = redS + 256;
#pragma unroll
        for (int m = 0; m < 4; m++) {
#pragma unroll
            for (int j = 0; j < 4; j++) {
                const int grow = row0 + m * 16 + h * 4 + j;
                float s = 0.f, q = 0.f;
#pragma unroll
                for (int n = 0; n < 4; n++) {
                    const int gcol = w * 64 + n * 16 + fr;
                    float v = acc[m][n][j] + b2[gcol] +
                              b2f(X[(size_t)grow * 256 + gcol]);
                    acc[m][n][j] = v;
                    s += v; q += v * v;
                }
#pragma unroll
                for (int off = 1; off < 16; off <<= 1) {
                    s += __shfl_xor(s, off, 64);
                    q += __shfl_xor(q, off, 64);
                }
                if (fr == 0) {
                    redS[(m * 16 + h * 4 + j) * 4 + w] = s;
                    redQ[(m * 16 + h * 4 + j) * 4 + w] = q;
                }
            }
        }
        __syncthreads();
#pragma unroll
        for (int m = 0; m < 4; m++) {
#pragma unroll
            for (int j = 0; j < 4; j++) {
                const int r = m * 16 + h * 4 + j;
                float4 s4 = *(const float4*)&redS[r * 4];
                float4 q4 = *(const float4*)&redQ[r * 4];
                float mu = (s4.x + s4.y + s4.z + s4.w) * (1.f / DIM);
                float var = (q4.x + q4.y + q4.z + q4.w) * (1.f / DIM) - mu * mu;
                float rr = rsqrtf(var + LN_EPS);
#pragma unroll
                for (int n = 0; n < 4; n++) {
                    const int gcol = w * 64 + n * 16 + fr;
                    float y = (acc[m][n][j] - mu) * rr * lng[gcol] + lnb[gcol];
                    acc[m][n][j] = y;
                }
            }
        }
        __syncthreads();
#pragma unroll
        for (int m = 0; m < 4; m++)
#pragma unroll
            for (int j = 0; j < 4; j++) {
                const int row = m * 16 + h * 4 + j;
#pragma unroll
                for (int n = 0; n < 4; n++)
                    Msm[row * MST + (w * 64 + n * 16 + fr)] = f2b(acc[m][n][j]);
            }
    }
    __syncthreads();   // drains vmcnt (tail B0 landed) + Msm writes visible

    // ---------------- tail ----------------
    if constexpr (TAIL == 0) {
        u8* KV8e = (u8*)outp;
#pragma unroll 1
        for (int half = 0; half < 2; half++) {
            const u16* Wb = WtT + (size_t)half * 65536;
            const float* bT = half ? bT1 : bT0;
#pragma unroll
            for (int m = 0; m < 4; m++)
#pragma unroll
                for (int n = 0; n < 4; n++)
                    acc[m][n] = f32x4{0.f, 0.f, 0.f, 0.f};
#pragma unroll
            for (int kt = 0; kt < 8; ++kt) {
                const int buf = kt & 1;
                if (kt < 7) stageB(buf ^ 1, kt + 1, Wb);
                else if (half == 0) stageB(0, 0, WtT + 65536);  // half-1 B0

                i16x8 af[4], bfr[4];
#pragma unroll
                for (int m = 0; m < 4; m++)
                    af[m] = *(const i16x8*)&Msm[(m * 16 + fr) * MST + (kt << 5) + h * 8];
#pragma unroll
                for (int n = 0; n < 4; n++)
                    bfr[n] = *(const i16x8*)&Bsm[buf][(w * 64 + n * 16 + fr) * 32 + (h ^ rsw) * 8];
                LGKM0;
                SCHED0;
#pragma unroll
                for (int m = 0; m < 4; m++)
#pragma unroll
                    for (int n = 0; n < 4; n++)
                        acc[m][n] = __builtin_amdgcn_mfma_f32_16x16x32_bf16(
                            af[m], bfr[n], acc[m][n], 0, 0, 0);
                if (kt < 7) { VMCNT0; SBAR; }
            }
#pragma unroll
            for (int m = 0; m < 4; m++) {
                const size_t rbase = (size_t)(row0 + m * 16 + h * 4) * 512 + half * 256;
#pragma unroll
                for (int n = 0; n < 4; n++) {
                    const int gcol = w * 64 + n * 16 + fr;
                    const float bTv = bT[gcol];
                    u32 p01 = f8pk2(acc[m][n][0] + bTv, acc[m][n][1] + bTv);
                    u32 p23 = f8pk2(acc[m][n][2] + bTv, acc[m][n][3] + bTv);
                    KV8e[rbase + gcol]        = (u8)p01;
                    KV8e[rbase + 512 + gcol]  = (u8)(p01 >> 8);
                    KV8e[rbase + 1024 + gcol] = (u8)p23;
                    KV8e[rbase + 1536 + gcol] = (u8)(p23 >> 8);
                }
            }
            if (half == 0) { VMCNT0; SBAR; }   // half-1 B0 landed; reads done
        }
    } else {
        float* out = (float*)outp;
        f32x4 acc3[3] = {};
#pragma unroll
        for (int kk = 0; kk < 8; kk++) {
            i16x8 af = *(const i16x8*)&Msm[(w * 16 + fr) * MST + kk * 32 + h * 8];
#pragma unroll
            for (int n = 0; n < 3; n++) {
                int br = n * 16 + fr; if (br > NCLS - 1) br = NCLS - 1;
                i16x8 bfr = *(const i16x8*)(WtT + (size_t)br * 256 + kk * 32 + h * 8);
                acc3[n] = __builtin_amdgcn_mfma_f32_16x16x32_bf16(af, bfr, acc3[n], 0, 0, 0);
            }
        }
#pragma unroll
        for (int n = 0; n < 3; n++) {
            const int gcol = n * 16 + fr;
            if (gcol >= NCLS) continue;
#pragma unroll
            for (int j = 0; j < 4; j++) {
                const int grow = row0 + w * 16 + h * 4 + j;
                out[(size_t)grow * NCLS + gcol] = acc3[n][j] + bT0[gcol];
            }
        }
    }
}

// ---------------------------------------------------------------------------
// edge_attn: gathers fp8 K/V from KV8n (u32/lane + HW cvt); Q bf16 from QEb.
// ---------------------------------------------------------------------------
__global__ __launch_bounds__(256) void edge_attn(
    const u8* __restrict__ KV8n, const u16* __restrict__ QE,
    const float* __restrict__ efeat,
    const int* __restrict__ e2n, const float* __restrict__ cent1,
    const float* __restrict__ g, const float* __restrict__ bb,
    u16* __restrict__ XE)
{
    const int lane = threadIdx.x & 63, w = threadIdx.x >> 6;
    const int e = blockIdx.x * 4 + w;
    const int c4 = lane * 4;

    ushort4 q4 = *(const ushort4*)&QE[(size_t)e * QDIM + c4];
    const float q0 = b2f(q4.x), q1 = b2f(q4.y), q2 = b2f(q4.z), q3 = b2f(q4.w);

    int4 rv[8];
#pragma unroll
    for (int i = 0; i < 8; i++)
        rv[i] = *(const int4*)&e2n[(size_t)e * DE + i * 4];
    int rows[DE];
#pragma unroll
    for (int i = 0; i < 8; i++) {
        rows[i * 4 + 0] = rv[i].x; rows[i * 4 + 1] = rv[i].y;
        rows[i * 4 + 2] = rv[i].z; rows[i * 4 + 3] = rv[i].w;
    }

    float p[DE];
#pragma unroll
    for (int g0 = 0; g0 < DE; g0 += 16) {       // 16 K-loads in flight
        u32 kw[16];
#pragma unroll
        for (int j = 0; j < 16; j++)
            kw[j] = *(const u32*)(KV8n + (size_t)rows[g0 + j] * 512 + c4);
#pragma unroll
        for (int j = 0; j < 16; j++) {
            float kf[4]; f8x4_to_f32(kw[j], kf);
            p[g0 + j] = q0 * kf[0] + q1 * kf[1] + q2 * kf[2] + q3 * kf[3];
        }
    }
#pragma unroll
    for (int off = 32; off; off >>= 1)          // 32 interleaved chains
#pragma unroll
        for (int d = 0; d < DE; d++)
            p[d] += __shfl_xor(p[d], off, 64);

    float4 cv[8];
#pragma unroll
    for (int i = 0; i < 8; i++)
        cv[i] = *(const float4*)&cent1[(size_t)e * DE + i * 4];
    float cent[DE];
#pragma unroll
    for (int i = 0; i < 8; i++) {
        cent[i * 4 + 0] = cv[i].x; cent[i * 4 + 1] = cv[i].y;
        cent[i * 4 + 2] = cv[i].z; cent[i * 4 + 3] = cv[i].w;
    }
#pragma unroll
    for (int d = 0; d < DE; d++)
        p[d] = (p[d] > 0.f ? p[d] : 0.01f * p[d]) * ATT_SCALE + cent[d];

    float mx = p[0];
#pragma unroll
    for (int d = 1; d < DE; d++) mx = fmaxf(mx, p[d]);
    float s = 0.f;
#pragma unroll
    for (int d = 0; d < DE; d++) { p[d] = __expf(p[d] - mx); s += p[d]; }
    const float inv = 1.f / s;
#pragma unroll
    for (int d = 0; d < DE; d++) p[d] *= inv;

    float a0 = 0.f, a1 = 0.f, a2 = 0.f, a3 = 0.f;
#pragma unroll
    for (int g0 = 0; g0 < DE; g0 += 16) {       // 16 V-loads in flight
        u32 vw[16];
#pragma unroll
        for (int j = 0; j < 16; j++)
            vw[j] = *(const u32*)(KV8n + (size_t)rows[g0 + j] * 512 + 256 + c4);
#pragma unroll
        for (int j = 0; j < 16; j++) {
            float vf[4]; f8x4_to_f32(vw[j], vf);
            const float sd = p[g0 + j];
            a0 = fmaf(sd, vf[0], a0); a1 = fmaf(sd, vf[1], a1);
            a2 = fmaf(sd, vf[2], a2); a3 = fmaf(sd, vf[3], a3);
        }
    }
    float4 ef = *(const float4*)&efeat[(size_t)e * DIM + c4];
    float x0 = a0 + ef.x, x1 = a1 + ef.y, x2 = a2 + ef.z, x3 = a3 + ef.w;

    float mu = x0 + x1 + x2 + x3;
#pragma unroll
    for (int off = 32; off; off >>= 1) mu += __shfl_xor(mu, off, 64);
    mu *= (1.f / DIM);
    float d0 = x0 - mu, d1 = x1 - mu, d2 = x2 - mu, d3 = x3 - mu;
    float var = d0 * d0 + d1 * d1 + d2 * d2 + d3 * d3;
#pragma unroll
    for (int off = 32; off; off >>= 1) var += __shfl_xor(var, off, 64);
    var *= (1.f / DIM);
    float r = rsqrtf(var + LN_EPS);
    float4 gv = *(const float4*)&g[c4];
    float4 bv = *(const float4*)&bb[c4];
    ushort4 o;
    o.x = f2b(d0 * r * gv.x + bv.x); o.y = f2b(d1 * r * gv.y + bv.y);
    o.z = f2b(d2 * r * gv.z + bv.z); o.w = f2b(d3 * r * gv.w + bv.w);
    *(ushort4*)&XE[(size_t)e * DIM + c4] = o;
}

// ---------------------------------------------------------------------------
// node_attn: gathers fp8 K/V from KV8e; q_v bf16 from QVb; resid FVb bf16.
// ---------------------------------------------------------------------------
__global__ __launch_bounds__(256) void node_attn(
    const u8* __restrict__ KV8e, const u16* __restrict__ QVb,
    const u16* __restrict__ FV,
    const int* __restrict__ n2e, const float* __restrict__ cent2,
    const float* __restrict__ g, const float* __restrict__ bb,
    u16* __restrict__ XV)
{
    const int lane = threadIdx.x & 63, w = threadIdx.x >> 6;
    const int na = blockIdx.x * 8 + w * 2, nb = na + 1;
    const int c4 = lane * 4;

    ushort4 qa4 = *(const ushort4*)&QVb[(size_t)na * 256 + c4];
    ushort4 qb4 = *(const ushort4*)&QVb[(size_t)nb * 256 + c4];
    const float qa0 = b2f(qa4.x), qa1 = b2f(qa4.y), qa2 = b2f(qa4.z), qa3 = b2f(qa4.w);
    const float qb0 = b2f(qb4.x), qb1 = b2f(qb4.y), qb2 = b2f(qb4.z), qb3 = b2f(qb4.w);

    int4 r0 = *(const int4*)&n2e[(size_t)na * DV];
    int4 r1 = *(const int4*)&n2e[(size_t)na * DV + 4];
    int4 r2 = *(const int4*)&n2e[(size_t)nb * DV];
    int4 r3 = *(const int4*)&n2e[(size_t)nb * DV + 4];
    int rA[8] = {r0.x, r0.y, r0.z, r0.w, r1.x, r1.y, r1.z, r1.w};
    int rB[8] = {r2.x, r2.y, r2.z, r2.w, r3.x, r3.y, r3.z, r3.w};

    u32 kA[8], vA[8], kB[8], vB[8];
#pragma unroll
    for (int d = 0; d < DV; d++) {
        const u8* b = KV8e + (size_t)rA[d] * 512 + c4;
        kA[d] = *(const u32*)b; vA[d] = *(const u32*)(b + 256);
    }
#pragma unroll
    for (int d = 0; d < DV; d++) {
        const u8* b = KV8e + (size_t)rB[d] * 512 + c4;
        kB[d] = *(const u32*)b; vB[d] = *(const u32*)(b + 256);
    }

    float pA[8], pB[8];
#pragma unroll
    for (int d = 0; d < DV; d++) {
        float ka[4], kb[4];
        f8x4_to_f32(kA[d], ka); f8x4_to_f32(kB[d], kb);
        pA[d] = qa0 * ka[0] + qa1 * ka[1] + qa2 * ka[2] + qa3 * ka[3];
        pB[d] = qb0 * kb[0] + qb1 * kb[1] + qb2 * kb[2] + qb3 * kb[3];
    }
#pragma unroll
    for (int off = 32; off; off >>= 1) {
#pragma unroll
        for (int d = 0; d < DV; d++) {
            pA[d] += __shfl_xor(pA[d], off, 64);
            pB[d] += __shfl_xor(pB[d], off, 64);
        }
    }
    float4 cA0 = *(const float4*)&cent2[(size_t)na * DV];
    float4 cA1 = *(const float4*)&cent2[(size_t)na * DV + 4];
    float4 cB0 = *(const float4*)&cent2[(size_t)nb * DV];
    float4 cB1 = *(const float4*)&cent2[(size_t)nb * DV + 4];
    float cA[8] = {cA0.x, cA0.y, cA0.z, cA0.w, cA1.x, cA1.y, cA1.z, cA1.w};
    float cB[8] = {cB0.x, cB0.y, cB0.z, cB0.w, cB1.x, cB1.y, cB1.z, cB1.w};
#pragma unroll
    for (int d = 0; d < DV; d++) {
        pA[d] = (pA[d] > 0.f ? pA[d] : 0.01f * pA[d]) * ATT_SCALE + cA[d];
        pB[d] = (pB[d] > 0.f ? pB[d] : 0.01f * pB[d]) * ATT_SCALE + cB[d];
    }
    float mA = pA[0], mB = pB[0];
#pragma unroll
    for (int d = 1; d < DV; d++) { mA = fmaxf(mA, pA[d]); mB = fmaxf(mB, pB[d]); }
    float sA = 0.f, sB = 0.f;
#pragma unroll
    for (int d = 0; d < DV; d++) {
        pA[d] = __expf(pA[d] - mA); sA += pA[d];
        pB[d] = __expf(pB[d] - mB); sB += pB[d];
    }
    const float iA = 1.f / sA, iB = 1.f / sB;

    float a0 = 0.f, a1 = 0.f, a2 = 0.f, a3 = 0.f;
    float b0 = 0.f, b1 = 0.f, b2 = 0.f, b3 = 0.f;
#pragma unroll
    for (int d = 0; d < DV; d++) {
        float va[4], vb[4];
        f8x4_to_f32(vA[d], va); f8x4_to_f32(vB[d], vb);
        const float sa = pA[d] * iA, sb = pB[d] * iB;
        a0 = fmaf(sa, va[0], a0); a1 = fmaf(sa, va[1], a1);
        a2 = fmaf(sa, va[2], a2); a3 = fmaf(sa, va[3], a3);
        b0 = fmaf(sb, vb[0], b0); b1 = fmaf(sb, vb[1], b1);
        b2 = fmaf(sb, vb[2], b2); b3 = fmaf(sb, vb[3], b3);
    }
    ushort4 fa = *(const ushort4*)&FV[(size_t)na * DIM + c4];
    ushort4 fb = *(const ushort4*)&FV[(size_t)nb * DIM + c4];
    float xa0 = a0 + b2f(fa.x), xa1 = a1 + b2f(fa.y);
    float xa2 = a2 + b2f(fa.z), xa3 = a3 + b2f(fa.w);
    float xb0 = b0 + b2f(fb.x), xb1 = b1 + b2f(fb.y);
    float xb2 = b2 + b2f(fb.z), xb3 = b3 + b2f(fb.w);

    float muA = xa0 + xa1 + xa2 + xa3, muB = xb0 + xb1 + xb2 + xb3;
#pragma unroll
    for (int off = 32; off; off >>= 1) {
        muA += __shfl_xor(muA, off, 64);
        muB += __shfl_xor(muB, off, 64);
    }
    muA *= (1.f / DIM); muB *= (1.f / DIM);
    float da0 = xa0 - muA, da1 = xa1 - muA, da2 = xa2 - muA, da3 = xa3 - muA;
    float db0 = xb0 - muB, db1 = xb1 - muB, db2 = xb2 - muB, db3 = xb3 - muB;
    float vA_ = da0 * da0 + da1 * da1 + da2 * da2 + da3 * da3;
    float vB_ = db0 * db0 + db1 * db1 + db2 * db2 + db3 * db3;
#pragma unroll
    for (int off = 32; off; off >>= 1) {
        vA_ += __shfl_xor(vA_, off, 64);
        vB_ += __shfl_xor(vB_, off, 64);
    }
    const float rA_ = rsqrtf(vA_ * (1.f / DIM) + LN_EPS);
    const float rB_ = rsqrtf(vB_ * (1.f / DIM) + LN_EPS);
    float4 gv = *(const float4*)&g[c4];
    float4 bv = *(const float4*)&bb[c4];
    ushort4 oa, ob;
    oa.x = f2b(da0 * rA_ * gv.x + bv.x); oa.y = f2b(da1 * rA_ * gv.y + bv.y);
    oa.z = f2b(da2 * rA_ * gv.z + bv.z); oa.w = f2b(da3 * rA_ * gv.w + bv.w);
    ob.x = f2b(db0 * rB_ * gv.x + bv.x); ob.y = f2b(db1 * rB_ * gv.y + bv.y);
    ob.z = f2b(db2 * rB_ * gv.z + bv.z); ob.w = f2b(db3 * rB_ * gv.w + bv.w);
    *(ushort4*)&XV[(size_t)na * DIM + c4] = oa;
    *(ushort4*)&XV[(size_t)nb * DIM + c4] = ob;
}

extern "C" void kernel_launch(void* const* d_in, const int* in_sizes, int n_in,
                              void* d_out, int out_size, void* d_ws, size_t ws_size,
                              hipStream_t stream)
{
    const float* vfeat  = (const float*)d_in[0];
    const float* efeat  = (const float*)d_in[1];
    const float* eign   = (const float*)d_in[2];
    const float* gcn    = (const float*)d_in[3];
    const float* cent1  = (const float*)d_in[4];
    const float* cent2  = (const float*)d_in[5];
    const int*   cidx   = (const int*)d_in[6];
    const int*   uidx   = (const int*)d_in[7];
    const int*   e2n    = (const int*)d_in[8];
    const int*   n2e    = (const int*)d_in[9];
    const float* W_vtx  = (const float*)d_in[10]; const float* b_vtx = (const float*)d_in[11];
    const float* W_pe   = (const float*)d_in[12]; const float* b_pe  = (const float*)d_in[13];
    const float* cs_emb = (const float*)d_in[14]; const float* un_emb= (const float*)d_in[15];
    const float* W_kv   = (const float*)d_in[16]; const float* b_kv  = (const float*)d_in[17];
    const float* W_vv   = (const float*)d_in[18]; const float* b_vv  = (const float*)d_in[19];
    const float* W_qe   = (const float*)d_in[20]; const float* b_qe  = (const float*)d_in[21];
    const float* W_ke   = (const float*)d_in[22]; const float* b_ke  = (const float*)d_in[23];
    const float* W_ve   = (const float*)d_in[24]; const float* b_ve  = (const float*)d_in[25];
    const float* W_qv   = (const float*)d_in[26]; const float* b_qv  = (const float*)d_in[27];
    const float* W_l1   = (const float*)d_in[28]; const float* b_l1  = (const float*)d_in[29];
    const float* W_l2   = (const float*)d_in[30]; const float* b_l2  = (const float*)d_in[31];
    const float* W_l3   = (const float*)d_in[32]; const float* b_l3  = (const float*)d_in[33];
    const float* W_l4   = (const float*)d_in[34]; const float* b_l4  = (const float*)d_in[35];
    const float* ln1_g  = (const float*)d_in[36]; const float* ln1_b = (const float*)d_in[37];
    const float* ln2_g  = (const float*)d_in[38]; const float* ln2_b = (const float*)d_in[39];
    const float* W_cls  = (const float*)d_in[40]; const float* b_cls = (const float*)d_in[41];
    float* out = (float*)d_out;

    const size_t NE = (size_t)N_NODES * DIM;   // 10,240,000
    const size_t EE = (size_t)N_EDGES * DIM;   //  2,048,000
    u16* ws = (u16*)d_ws;
    u16* FVb  = ws;                          // bf16 feat_v (resid for node_attn)
    u16* QVb  = FVb + NE;                    // bf16 q_v [N][256]
    u16* B2   = QVb + NE;                    // bf16 x_v
    u16* QEb  = B2 + NE;                     // bf16 q_e
    u16* XE   = QEb + EE;                    // bf16 x_e
    u8*  KV8n = (u8*)(XE + EE);              // fp8 [N][512]B k_n|v_n
    u8*  KV8e = KV8n + (size_t)N_NODES * 512;// fp8 [E][512]B k_e|v_e
    u16* Wp   = (u16*)(KV8e + (size_t)N_EDGES * 512);  // 13 * 65536 u16
    u16* Wt_vtx = Wp +  0 * 65536;
    u16* Wt_pe  = Wp +  1 * 65536;
    u16* Wt_kvq = Wp +  2 * 65536;  // slots 2,3,4 = [768][256]
    u16* Wt_qe  = Wp +  5 * 65536;
    u16* Wt_kve = Wp +  6 * 65536;  // slots 6,7 = [512][256]
    u16* Wt_l1  = Wp +  8 * 65536;
    u16* Wt_l2  = Wp +  9 * 65536;
    u16* Wt_l3  = Wp + 10 * 65536;
    u16* Wt_l4  = Wp + 11 * 65536;
    u16* Wt_cls = Wp + 12 * 65536;

    const dim3 blk(256);
    const dim3 gW(8, 8, 13);
    const dim3 gQE(2, N_EDGES / 64);     // (2,125)

    prep_weights<<<gW, blk, 0, stream>>>(
        W_vtx, W_pe, W_kv, W_vv, W_qv, W_qe, W_ke, W_ve,
        W_l1, W_l2, W_l3, W_l4, W_cls, Wp);

    // fused assembly + KVQ (K/V -> fp8 via HW pair-pack, Q -> bf16)
    asm_kvq<<<N_NODES / 64, blk, 0, stream>>>(
        vfeat, eign, Wt_vtx, Wt_pe, b_vtx, b_pe,
        gcn, cs_emb, un_emb, cidx, uidx,
        Wt_kvq, b_kv, b_vv, b_qv, FVb, KV8n, QVb);

    // stage 1
    gemmN<0, 1, 4><<<gQE, blk, 0, stream>>>(efeat, Wt_qe,
        b_qe, b_qe, b_qe, QEb, 256);                                    // q_e
    edge_attn<<<N_EDGES / 4, blk, 0, stream>>>(KV8n, QEb, efeat, e2n, cent1,
        ln1_g, ln1_b, XE);
    ffn_fused<0><<<N_EDGES / 64, blk, 0, stream>>>(XE, Wt_l1, b_l1,
        Wt_l2, b_l2, ln1_g, ln1_b, Wt_kve, b_ke, b_ve, KV8e);           // FFN+LN+{k_e|v_e fp8}

    // stage 2
    node_attn<<<N_NODES / 8, blk, 0, stream>>>(KV8e, QVb, FVb, n2e, cent2,
        ln2_g, ln2_b, B2);                                              // x_v
    ffn_fused<1><<<N_NODES / 64, blk, 0, stream>>>(B2, Wt_l3, b_l3,
        Wt_l4, b_l4, ln2_g, ln2_b, Wt_cls, b_cls, nullptr, out);        // FFN+LN+cls
}